// Round 3
// baseline (2053.578 us; speedup 1.0000x reference)
//
#include <hip/hip_runtime.h>
#include <math.h>

#define BB 2
#define DD 128
#define HH 256
#define WW 256
#define KK 4
#define HWC (HH*WW)
#define SROW 272   // 16*17 floats per d-slice (pad 17 kills 4-way read conflicts)

// ---------------- Kernel 0: weight prep ----------------
// wtT[d][o] = projw[o][d];  wp[c][12][9] = interleaved offset/weight conv filters
__global__ __launch_bounds__(256) void k0_prep(
    const float* __restrict__ projw, const float* __restrict__ offw,
    const float* __restrict__ wtw, float* __restrict__ wtT, float* __restrict__ wp)
{
    int idx = blockIdx.x * 256 + threadIdx.x;
    if (idx < 16384) {
        int d = idx >> 7, o = idx & 127;
        wtT[d * 128 + o] = projw[o * 128 + d];
    }
    if (idx < 13824) {
        int c = idx / 108; int r = idx % 108; int o = r / 9; int t = r % 9;
        wp[idx] = (o < 8) ? offw[(o*128 + c)*9 + t] : wtw[((o-8)*128 + c)*9 + t];
    }
}

// ---------------- Kernel 1: 3x3 convs -> offsets(8) + softmaxed attn(4) ----------------
// block = one output row (b,i), thread j. Weights via uniform s_loads from wp.
// 3 input rows staged in LDS, double-buffered and pipelined across c.
__global__ __launch_bounds__(256) void k1_convs(
    const float* __restrict__ bev, const float* __restrict__ wp,
    const float* __restrict__ offb, const float* __restrict__ wtb,
    float* __restrict__ oa)
{
    __shared__ float rows[2][3][260];   // [buf][dy][1+j], pads at [0] and [257]
    int tid = threadIdx.x;
    int p = blockIdx.x;
    int b = p / HH; int i = p % HH; int j = tid;
    const float* bb = bev + (size_t)b * DD * HWC;

    // zero the x-pads once (never overwritten)
    if (tid < 12) { int bf = tid / 6, r = tid % 6; rows[bf][r >> 1][(r & 1) ? 257 : 0] = 0.f; }
    // stage c = 0
    #pragma unroll
    for (int l = 0; l < 3; l++) {
        int yy = i + l - 1;
        rows[0][l][1 + tid] = ((unsigned)yy < HH) ? bb[yy * WW + tid] : 0.f;
    }
    __syncthreads();

    float acc[12];
    #pragma unroll
    for (int o = 0; o < 12; o++) acc[o] = 0.f;

    for (int c = 0; c < 128; c++) {
        int cb = c & 1, nb = cb ^ 1;
        float rv[3];
        if (c < 127) {
            const float* pln = bb + (size_t)(c + 1) * HWC;
            #pragma unroll
            for (int l = 0; l < 3; l++) {
                int yy = i + l - 1;
                rv[l] = ((unsigned)yy < HH) ? pln[yy * WW + tid] : 0.f;
            }
        }
        float v[9];
        #pragma unroll
        for (int dy = 0; dy < 3; dy++)
            #pragma unroll
            for (int dx = 0; dx < 3; dx++)
                v[dy*3 + dx] = rows[cb][dy][tid + dx];
        const float* wc = wp + c * 108;   // uniform indices -> scalar loads
        #pragma unroll
        for (int o = 0; o < 12; o++) {
            float s = acc[o];
            #pragma unroll
            for (int t = 0; t < 9; t++) s = fmaf(wc[o*9 + t], v[t], s);
            acc[o] = s;
        }
        if (c < 127) {
            #pragma unroll
            for (int l = 0; l < 3; l++) rows[nb][l][1 + tid] = rv[l];
        }
        __syncthreads();
    }

    float outv[12];
    #pragma unroll
    for (int o = 0; o < 8; o++) outv[o] = acc[o] + offb[o];
    float l4[4];
    #pragma unroll
    for (int k = 0; k < 4; k++) l4[k] = acc[8+k] + wtb[k];
    float m = fmaxf(fmaxf(l4[0], l4[1]), fmaxf(l4[2], l4[3]));
    float e[4]; float se = 0.f;
    #pragma unroll
    for (int k = 0; k < 4; k++) { e[k] = expf(l4[k] - m); se += e[k]; }
    float inv = 1.f / se;
    #pragma unroll
    for (int k = 0; k < 4; k++) outv[8+k] = e[k] * inv;

    size_t basep = (size_t)b * 12 * HWC + (size_t)i * WW + j;
    #pragma unroll
    for (int o = 0; o < 12; o++) oa[basep + (size_t)o * HWC] = outv[o];
}

// ---------------- Kernel 2: deformable sample + K-aggregate + 1x1 proj ----------------
// 16x16 pixel tile, 512 threads. Software-pipelined: gathers for chunk c+1 are
// interleaved inside the GEMM dl-loop of chunk c (double-buffered S and WT).
// S layout [dl][p*17+q] -> <=2-way banks on both write (p-fast lanes) and read.
__global__ __launch_bounds__(512, 4) void k2_sample_proj(
    const float* __restrict__ bev, const float* __restrict__ oa,
    const float* __restrict__ wt, float* __restrict__ y)
{
    __shared__ float S[2][16 * SROW];   // 2 * 17408 B
    __shared__ float WT[2][16][128];    // 2 * 8192 B

    int tid = threadIdx.x;
    int bidx = blockIdx.x;
    int b  = bidx >> 8;
    int p0 = ((bidx >> 4) & 15) * 16;
    int q0 = (bidx & 15) * 16;

    // gather-phase identity (p-fast within 16-lane groups)
    int pix = tid & 255;
    int gq = pix >> 4;
    int gp = pix & 15;
    int dgrp = tid >> 8;                 // 0/1 -> which 8-d half of the chunk
    int swr = gp * 17 + gq;              // S column (add dl*SROW)

    // GEMM-phase identity
    int wv = tid >> 6;                   // wave -> o block [16wv,16wv+16)
    int lane = tid & 63;
    int m  = lane >> 4;                  // q block 0..3
    int lp = lane & 15;                  // p 0..15
    int q4 = m << 2;
    int soff = lp * 17 + q4;
    int wdl = tid >> 5, wo4 = tid & 31;  // WT staging identity

    // ---- offsets / attention for this thread's gather pixel ----
    const float* ob = oa + (size_t)b * 12 * HWC + (size_t)(p0 + gp) * WW + (q0 + gq);
    unsigned pa[8]; float cw[16];
    #pragma unroll
    for (int k = 0; k < 4; k++) {
        float dx = ob[(size_t)(2*k)   * HWC];
        float dy = ob[(size_t)(2*k+1) * HWC];
        float a  = ob[(size_t)(8+k)   * HWC];
        float x  = fminf(fmaxf((float)(p0 + gp) + dx, 0.f), (float)(WW-1));
        float yy = fminf(fmaxf((float)(q0 + gq) + dy, 0.f), (float)(HH-1));
        float x0f = floorf(x); float y0f = floorf(yy);
        int x0 = (int)x0f; int y0 = (int)y0f;
        int x1 = min(x0 + 1, WW - 1); int y1 = min(y0 + 1, HH - 1);
        float wx = x - x0f; float wy = yy - y0f;
        pa[k*2+0] = (unsigned)(y0*WW + x0) | ((unsigned)(y0*WW + x1) << 16);
        pa[k*2+1] = (unsigned)(y1*WW + x0) | ((unsigned)(y1*WW + x1) << 16);
        cw[k*4+0] = a * (1.f - wx) * (1.f - wy);
        cw[k*4+1] = a * wx * (1.f - wy);
        cw[k*4+2] = a * (1.f - wx) * wy;
        cw[k*4+3] = a * wx * wy;
    }

    const float* bb = bev + (size_t)b * DD * HWC;

    float acc[64];
    #pragma unroll
    for (int t = 0; t < 64; t++) acc[t] = 0.f;

    // ---- prologue: stage chunk 0 ----
    #pragma unroll 2
    for (int dd = 0; dd < 8; dd++) {
        const float* pl = bb + (size_t)(dgrp*8 + dd) * HWC;
        float s = 0.f;
        #pragma unroll
        for (int t = 0; t < 8; t++) {
            unsigned a01 = pa[t];
            s = fmaf(cw[2*t],   pl[a01 & 0xffffu], s);
            s = fmaf(cw[2*t+1], pl[a01 >> 16], s);
        }
        S[0][(dgrp*8 + dd) * SROW + swr] = s;
    }
    ((float4*)&WT[0][wdl][0])[wo4] = ((const float4*)(wt + (size_t)wdl * 128))[wo4];
    __syncthreads();

    // ---- pipelined main loop: GEMM chunk c, gather chunk c+1 ----
    for (int c = 0; c < 7; c++) {
        int cur = c & 1, nxt = cur ^ 1;
        int d0n = (c + 1) * 16;
        float smpn[8];
        float4 wv4n = ((const float4*)(wt + (size_t)(d0n + wdl) * 128))[wo4];
        const float* Sc = &S[cur][0];

        #pragma unroll
        for (int dl = 0; dl < 16; dl++) {
            if (dl < 8) {   // one gather interleaved per even slot
                const float* pl = bb + (size_t)(d0n + dgrp*8 + dl) * HWC;
                float s = 0.f;
                #pragma unroll
                for (int t = 0; t < 8; t++) {
                    unsigned a01 = pa[t];
                    s = fmaf(cw[2*t],   pl[a01 & 0xffffu], s);
                    s = fmaf(cw[2*t+1], pl[a01 >> 16], s);
                }
                smpn[dl] = s;
            }
            float sv0 = Sc[dl*SROW + soff + 0];
            float sv1 = Sc[dl*SROW + soff + 1];
            float sv2 = Sc[dl*SROW + soff + 2];
            float sv3 = Sc[dl*SROW + soff + 3];
            const float4* wrow = (const float4*)&WT[cur][dl][wv * 16];
            #pragma unroll
            for (int oi4 = 0; oi4 < 4; oi4++) {
                float4 w4 = wrow[oi4];
                int ob4 = oi4 * 16;
                acc[ob4+ 0] = fmaf(w4.x, sv0, acc[ob4+ 0]);
                acc[ob4+ 1] = fmaf(w4.x, sv1, acc[ob4+ 1]);
                acc[ob4+ 2] = fmaf(w4.x, sv2, acc[ob4+ 2]);
                acc[ob4+ 3] = fmaf(w4.x, sv3, acc[ob4+ 3]);
                acc[ob4+ 4] = fmaf(w4.y, sv0, acc[ob4+ 4]);
                acc[ob4+ 5] = fmaf(w4.y, sv1, acc[ob4+ 5]);
                acc[ob4+ 6] = fmaf(w4.y, sv2, acc[ob4+ 6]);
                acc[ob4+ 7] = fmaf(w4.y, sv3, acc[ob4+ 7]);
                acc[ob4+ 8] = fmaf(w4.z, sv0, acc[ob4+ 8]);
                acc[ob4+ 9] = fmaf(w4.z, sv1, acc[ob4+ 9]);
                acc[ob4+10] = fmaf(w4.z, sv2, acc[ob4+10]);
                acc[ob4+11] = fmaf(w4.z, sv3, acc[ob4+11]);
                acc[ob4+12] = fmaf(w4.w, sv0, acc[ob4+12]);
                acc[ob4+13] = fmaf(w4.w, sv1, acc[ob4+13]);
                acc[ob4+14] = fmaf(w4.w, sv2, acc[ob4+14]);
                acc[ob4+15] = fmaf(w4.w, sv3, acc[ob4+15]);
            }
        }
        #pragma unroll
        for (int dd = 0; dd < 8; dd++)
            S[nxt][(dgrp*8 + dd) * SROW + swr] = smpn[dd];
        ((float4*)&WT[nxt][wdl][0])[wo4] = wv4n;
        __syncthreads();
    }

    // ---- epilogue: GEMM chunk 7 ----
    {
        const float* Sc = &S[1][0];
        #pragma unroll
        for (int dl = 0; dl < 16; dl++) {
            float sv0 = Sc[dl*SROW + soff + 0];
            float sv1 = Sc[dl*SROW + soff + 1];
            float sv2 = Sc[dl*SROW + soff + 2];
            float sv3 = Sc[dl*SROW + soff + 3];
            const float4* wrow = (const float4*)&WT[1][dl][wv * 16];
            #pragma unroll
            for (int oi4 = 0; oi4 < 4; oi4++) {
                float4 w4 = wrow[oi4];
                int ob4 = oi4 * 16;
                acc[ob4+ 0] = fmaf(w4.x, sv0, acc[ob4+ 0]);
                acc[ob4+ 1] = fmaf(w4.x, sv1, acc[ob4+ 1]);
                acc[ob4+ 2] = fmaf(w4.x, sv2, acc[ob4+ 2]);
                acc[ob4+ 3] = fmaf(w4.x, sv3, acc[ob4+ 3]);
                acc[ob4+ 4] = fmaf(w4.y, sv0, acc[ob4+ 4]);
                acc[ob4+ 5] = fmaf(w4.y, sv1, acc[ob4+ 5]);
                acc[ob4+ 6] = fmaf(w4.y, sv2, acc[ob4+ 6]);
                acc[ob4+ 7] = fmaf(w4.y, sv3, acc[ob4+ 7]);
                acc[ob4+ 8] = fmaf(w4.z, sv0, acc[ob4+ 8]);
                acc[ob4+ 9] = fmaf(w4.z, sv1, acc[ob4+ 9]);
                acc[ob4+10] = fmaf(w4.z, sv2, acc[ob4+10]);
                acc[ob4+11] = fmaf(w4.z, sv3, acc[ob4+11]);
                acc[ob4+12] = fmaf(w4.w, sv0, acc[ob4+12]);
                acc[ob4+13] = fmaf(w4.w, sv1, acc[ob4+13]);
                acc[ob4+14] = fmaf(w4.w, sv2, acc[ob4+14]);
                acc[ob4+15] = fmaf(w4.w, sv3, acc[ob4+15]);
            }
        }
    }

    // coalesced float4 stores: a wave covers 16 full 64B lines per instruction
    size_t base = (size_t)b * DD * HWC + (size_t)(p0 + lp) * WW + (q0 + q4);
    #pragma unroll
    for (int oi = 0; oi < 16; oi++) {
        int o = wv * 16 + oi;
        float4 v = make_float4(acc[oi*4+0], acc[oi*4+1], acc[oi*4+2], acc[oi*4+3]);
        *(float4*)(y + base + (size_t)o * HWC) = v;
    }
}

// ---------------- Kernel 3a: per-channel partial sums (512 blocks, float4) ----------------
__global__ __launch_bounds__(256) void k3_partial(
    const float* __restrict__ y, double* __restrict__ part)
{
    int blk = blockIdx.x;            // o*4 + b*2 + half
    int o = blk >> 2; int sub = blk & 3; int b = sub >> 1; int half = sub & 1;
    const float4* pl = (const float4*)(y + ((size_t)b * DD + o) * HWC + half * (HWC/2));
    int tid = threadIdx.x;
    double s = 0.0, s2 = 0.0;
    for (int idx = tid; idx < HWC/8; idx += 256) {
        float4 v = pl[idx];
        s  += (double)v.x + (double)v.y + (double)v.z + (double)v.w;
        s2 += (double)v.x*v.x + (double)v.y*v.y + (double)v.z*v.z + (double)v.w*v.w;
    }
    __shared__ double ls[256], ls2[256];
    ls[tid] = s; ls2[tid] = s2;
    __syncthreads();
    for (int off = 128; off > 0; off >>= 1) {
        if (tid < off) { ls[tid] += ls[tid+off]; ls2[tid] += ls2[tid+off]; }
        __syncthreads();
    }
    if (tid == 0) { part[blk*2] = ls[0]; part[blk*2+1] = ls2[0]; }
}

// ---------------- Kernel 3b: finalize BN scale/shift ----------------
__global__ __launch_bounds__(128) void k3_finalize(
    const double* __restrict__ part, const float* __restrict__ gamma,
    const float* __restrict__ beta, float* __restrict__ stats)
{
    int o = threadIdx.x;
    double s = 0.0, s2 = 0.0;
    #pragma unroll
    for (int j = 0; j < 4; j++) { s += part[(o*4+j)*2]; s2 += part[(o*4+j)*2+1]; }
    double N = (double)(BB * HWC);
    double mean = s / N;
    double var = s2 / N - mean * mean;
    double invs = 1.0 / sqrt(var + 1e-5);
    double g = (double)gamma[o];
    stats[o*2]   = (float)(g * invs);
    stats[o*2+1] = (float)((double)beta[o] - mean * g * invs);
}

// ---------------- Kernel 4: BN + exact GELU, in-place on d_out ----------------
__global__ __launch_bounds__(256) void k4_bn_gelu(
    float* __restrict__ y, const float* __restrict__ stats)
{
    size_t idx4 = (size_t)blockIdx.x * 256 + threadIdx.x;  // float4 index
    float4* p = (float4*)y;
    float4 v = p[idx4];
    int o = (int)((idx4 * 4) / HWC) % DD;
    float sc = stats[o*2], sh = stats[o*2+1];
    const float inv_sqrt2 = 0.70710678118654752f;
    float g0 = fmaf(v.x, sc, sh);
    float g1 = fmaf(v.y, sc, sh);
    float g2 = fmaf(v.z, sc, sh);
    float g3 = fmaf(v.w, sc, sh);
    v.x = 0.5f * g0 * (1.f + erff(g0 * inv_sqrt2));
    v.y = 0.5f * g1 * (1.f + erff(g1 * inv_sqrt2));
    v.z = 0.5f * g2 * (1.f + erff(g2 * inv_sqrt2));
    v.w = 0.5f * g3 * (1.f + erff(g3 * inv_sqrt2));
    p[idx4] = v;
}

extern "C" void kernel_launch(void* const* d_in, const int* in_sizes, int n_in,
                              void* d_out, int out_size, void* d_ws, size_t ws_size,
                              hipStream_t stream) {
    const float* bev   = (const float*)d_in[0];
    const float* offw  = (const float*)d_in[1];
    const float* offb  = (const float*)d_in[2];
    const float* wtw   = (const float*)d_in[3];
    const float* wtb   = (const float*)d_in[4];
    const float* projw = (const float*)d_in[5];
    const float* gamma = (const float*)d_in[6];
    const float* beta  = (const float*)d_in[7];
    float* out = (float*)d_out;

    float* oa    = (float*)d_ws;                 // B*12*H*W = 1,572,864 floats
    float* wtT   = oa + (size_t)BB * 12 * HWC;   // 16384 floats
    float* wp    = wtT + 16384;                  // 13824 floats
    float* stats = wp + 13824;                   // 256 floats (+64 pad)
    double* part = (double*)(stats + 256 + 64);  // 1024 doubles (8B aligned)

    hipLaunchKernelGGL(k0_prep, dim3(64), dim3(256), 0, stream,
                       projw, offw, wtw, wtT, wp);
    hipLaunchKernelGGL(k1_convs, dim3(BB*HH), dim3(256), 0, stream,
                       bev, wp, offb, wtb, oa);
    hipLaunchKernelGGL(k2_sample_proj, dim3(BB*256), dim3(512), 0, stream,
                       bev, oa, wtT, out);
    hipLaunchKernelGGL(k3_partial, dim3(512), dim3(256), 0, stream,
                       out, part);
    hipLaunchKernelGGL(k3_finalize, dim3(1), dim3(128), 0, stream,
                       part, gamma, beta, stats);
    hipLaunchKernelGGL(k4_bn_gelu, dim3((BB*DD*HWC)/1024), dim3(256), 0, stream,
                       out, stats);
}

// Round 4
// 505.586 us; speedup vs baseline: 4.0618x; 4.0618x over previous
//
#include <hip/hip_runtime.h>
#include <math.h>

#define BB 2
#define DD 128
#define HH 256
#define WW 256
#define KK 4
#define HWC (HH*WW)
#define SROW2 320   // p-row stride 20 floats x 16 rows per d-slice: aligned b128 reads, conflict-free

// ---------------- Kernel 0: weight prep ----------------
// wtT[d][o] = projw[o][d];  wp[c][12][9] = interleaved offset/weight conv filters
__global__ __launch_bounds__(256) void k0_prep(
    const float* __restrict__ projw, const float* __restrict__ offw,
    const float* __restrict__ wtw, float* __restrict__ wtT, float* __restrict__ wp)
{
    int idx = blockIdx.x * 256 + threadIdx.x;
    if (idx < 16384) {
        int d = idx >> 7, o = idx & 127;
        wtT[d * 128 + o] = projw[o * 128 + d];
    }
    if (idx < 13824) {
        int c = idx / 108; int r = idx % 108; int o = r / 9; int t = r % 9;
        wp[idx] = (o < 8) ? offw[(o*128 + c)*9 + t] : wtw[((o-8)*128 + c)*9 + t];
    }
}

// ---------------- Kernel 1: 3x3 convs -> offsets(8) + softmaxed attn(4) ----------------
// block = one output row (b,i), thread j. Weights via uniform s_loads from wp.
// 3 input rows staged in LDS, double-buffered and pipelined across c.
__global__ __launch_bounds__(256) void k1_convs(
    const float* __restrict__ bev, const float* __restrict__ wp,
    const float* __restrict__ offb, const float* __restrict__ wtb,
    float* __restrict__ oa)
{
    __shared__ float rows[2][3][260];   // [buf][dy][1+j], pads at [0] and [257]
    int tid = threadIdx.x;
    int p = blockIdx.x;
    int b = p / HH; int i = p % HH; int j = tid;
    const float* bb = bev + (size_t)b * DD * HWC;

    // zero the x-pads once (never overwritten)
    if (tid < 12) { int bf = tid / 6, r = tid % 6; rows[bf][r >> 1][(r & 1) ? 257 : 0] = 0.f; }
    // stage c = 0
    #pragma unroll
    for (int l = 0; l < 3; l++) {
        int yy = i + l - 1;
        rows[0][l][1 + tid] = ((unsigned)yy < HH) ? bb[yy * WW + tid] : 0.f;
    }
    __syncthreads();

    float acc[12];
    #pragma unroll
    for (int o = 0; o < 12; o++) acc[o] = 0.f;

    for (int c = 0; c < 128; c++) {
        int cb = c & 1, nb = cb ^ 1;
        float rv[3];
        if (c < 127) {
            const float* pln = bb + (size_t)(c + 1) * HWC;
            #pragma unroll
            for (int l = 0; l < 3; l++) {
                int yy = i + l - 1;
                rv[l] = ((unsigned)yy < HH) ? pln[yy * WW + tid] : 0.f;
            }
        }
        float v[9];
        #pragma unroll
        for (int dy = 0; dy < 3; dy++)
            #pragma unroll
            for (int dx = 0; dx < 3; dx++)
                v[dy*3 + dx] = rows[cb][dy][tid + dx];
        const float* wc = wp + c * 108;   // uniform indices -> scalar loads
        #pragma unroll
        for (int o = 0; o < 12; o++) {
            float s = acc[o];
            #pragma unroll
            for (int t = 0; t < 9; t++) s = fmaf(wc[o*9 + t], v[t], s);
            acc[o] = s;
        }
        if (c < 127) {
            #pragma unroll
            for (int l = 0; l < 3; l++) rows[nb][l][1 + tid] = rv[l];
        }
        __syncthreads();
    }

    float outv[12];
    #pragma unroll
    for (int o = 0; o < 8; o++) outv[o] = acc[o] + offb[o];
    float l4[4];
    #pragma unroll
    for (int k = 0; k < 4; k++) l4[k] = acc[8+k] + wtb[k];
    float m = fmaxf(fmaxf(l4[0], l4[1]), fmaxf(l4[2], l4[3]));
    float e[4]; float se = 0.f;
    #pragma unroll
    for (int k = 0; k < 4; k++) { e[k] = expf(l4[k] - m); se += e[k]; }
    float inv = 1.f / se;
    #pragma unroll
    for (int k = 0; k < 4; k++) outv[8+k] = e[k] * inv;

    size_t basep = (size_t)b * 12 * HWC + (size_t)i * WW + j;
    #pragma unroll
    for (int o = 0; o < 12; o++) oa[basep + (size_t)o * HWC] = outv[o];
}

// ---------------- Kernel 2: deformable sample + K-aggregate + 1x1 proj ----------------
// 16x16 pixel tile, 512 threads. Software-pipelined: gather chains for chunk c+1
// write DIRECTLY into S[nxt] interleaved with the GEMM dl-loop over S[cur]
// (double-buffered S; one barrier per chunk). Proj weights are read via
// readfirstlane-forced scalar loads (wave-uniform address, L2-hot) - no WT LDS.
// S stride 20/row: GEMM reads are aligned ds_read_b128 with uniform bank spread;
// writes are exactly 2-way (free).
// launch_bounds(512,2): VGPR cap 256 - lesson from round 3: never cap below need.
__global__ __launch_bounds__(512, 2) void k2_sample_proj(
    const float* __restrict__ bev, const float* __restrict__ oa,
    const float* __restrict__ wt, float* __restrict__ y)
{
    __shared__ float S[2][16 * SROW2];   // 2 * 20480 B = 40 KB

    int tid = threadIdx.x;
    int bidx = blockIdx.x;
    int b  = bidx >> 8;
    int p0 = ((bidx >> 4) & 15) * 16;
    int q0 = (bidx & 15) * 16;

    // gather-phase identity (p-fast within 16-lane groups -> coalesced-ish gathers)
    int pix = tid & 255;
    int gq = pix >> 4;
    int gp = pix & 15;
    int dgrp = tid >> 8;                 // 0/1 -> which 8-d half of the chunk
    int swr = gp * 20 + gq;              // S column (add dl*SROW2)

    // GEMM-phase identity
    int wv = tid >> 6;                   // wave -> o block [16wv,16wv+16)
    int wvu = __builtin_amdgcn_readfirstlane(wv);   // force scalar for s_load of wt
    int lane = tid & 63;
    int lp = lane >> 2;                  // p 0..15
    int q4 = (lane & 3) << 2;            // q block base 0,4,8,12
    int soff = lp * 20 + q4;             // 16B-aligned

    // ---- offsets / attention for this thread's gather pixel ----
    const float* ob = oa + (size_t)b * 12 * HWC + (size_t)(p0 + gp) * WW + (q0 + gq);
    unsigned pa[8]; float cw[16];
    #pragma unroll
    for (int k = 0; k < 4; k++) {
        float dx = ob[(size_t)(2*k)   * HWC];
        float dy = ob[(size_t)(2*k+1) * HWC];
        float a  = ob[(size_t)(8+k)   * HWC];
        float x  = fminf(fmaxf((float)(p0 + gp) + dx, 0.f), (float)(WW-1));
        float yy = fminf(fmaxf((float)(q0 + gq) + dy, 0.f), (float)(HH-1));
        float x0f = floorf(x); float y0f = floorf(yy);
        int x0 = (int)x0f; int y0 = (int)y0f;
        int x1 = min(x0 + 1, WW - 1); int y1 = min(y0 + 1, HH - 1);
        float wx = x - x0f; float wy = yy - y0f;
        pa[k*2+0] = (unsigned)(y0*WW + x0) | ((unsigned)(y0*WW + x1) << 16);
        pa[k*2+1] = (unsigned)(y1*WW + x0) | ((unsigned)(y1*WW + x1) << 16);
        cw[k*4+0] = a * (1.f - wx) * (1.f - wy);
        cw[k*4+1] = a * wx * (1.f - wy);
        cw[k*4+2] = a * (1.f - wx) * wy;
        cw[k*4+3] = a * wx * wy;
    }

    const float* bb = bev + (size_t)b * DD * HWC;

    float acc[64];
    #pragma unroll
    for (int t = 0; t < 64; t++) acc[t] = 0.f;

    // ---- prologue: stage chunk 0 ----
    #pragma unroll
    for (int dd = 0; dd < 8; dd++) {
        const float* pl = bb + (size_t)(dgrp*8 + dd) * HWC;
        float s = 0.f;
        #pragma unroll
        for (int t = 0; t < 8; t++) {
            unsigned a01 = pa[t];
            s = fmaf(cw[2*t],   pl[a01 & 0xffffu], s);
            s = fmaf(cw[2*t+1], pl[a01 >> 16], s);
        }
        S[0][(dgrp*8 + dd) * SROW2 + swr] = s;
    }
    __syncthreads();

    // ---- pipelined main loop ----
    for (int c = 0; c < 8; c++) {
        int cur = c & 1;
        const float* Sc = &S[cur][0];
        float* Sn = &S[cur ^ 1][0];
        int d0 = c * 16;
        int d0n = d0 + 16;
        bool more = (c < 7);

        #pragma unroll
        for (int dl = 0; dl < 16; dl++) {
            if (dl < 8) {                 // one gather chain interleaved per slot
                if (more) {
                    const float* pl = bb + (size_t)(d0n + dgrp*8 + dl) * HWC;
                    float s = 0.f;
                    #pragma unroll
                    for (int t = 0; t < 8; t++) {
                        unsigned a01 = pa[t];
                        s = fmaf(cw[2*t],   pl[a01 & 0xffffu], s);
                        s = fmaf(cw[2*t+1], pl[a01 >> 16], s);
                    }
                    Sn[(dgrp*8 + dl) * SROW2 + swr] = s;
                }
            }
            float4 sv = *(const float4*)(Sc + dl * SROW2 + soff);
            const float4* wq = (const float4*)(wt + (size_t)(d0 + dl) * 128 + wvu * 16);
            #pragma unroll
            for (int oi4 = 0; oi4 < 4; oi4++) {
                float4 w4 = wq[oi4];
                int ob4 = oi4 * 16;
                acc[ob4+ 0] = fmaf(w4.x, sv.x, acc[ob4+ 0]);
                acc[ob4+ 1] = fmaf(w4.x, sv.y, acc[ob4+ 1]);
                acc[ob4+ 2] = fmaf(w4.x, sv.z, acc[ob4+ 2]);
                acc[ob4+ 3] = fmaf(w4.x, sv.w, acc[ob4+ 3]);
                acc[ob4+ 4] = fmaf(w4.y, sv.x, acc[ob4+ 4]);
                acc[ob4+ 5] = fmaf(w4.y, sv.y, acc[ob4+ 5]);
                acc[ob4+ 6] = fmaf(w4.y, sv.z, acc[ob4+ 6]);
                acc[ob4+ 7] = fmaf(w4.y, sv.w, acc[ob4+ 7]);
                acc[ob4+ 8] = fmaf(w4.z, sv.x, acc[ob4+ 8]);
                acc[ob4+ 9] = fmaf(w4.z, sv.y, acc[ob4+ 9]);
                acc[ob4+10] = fmaf(w4.z, sv.z, acc[ob4+10]);
                acc[ob4+11] = fmaf(w4.z, sv.w, acc[ob4+11]);
                acc[ob4+12] = fmaf(w4.w, sv.x, acc[ob4+12]);
                acc[ob4+13] = fmaf(w4.w, sv.y, acc[ob4+13]);
                acc[ob4+14] = fmaf(w4.w, sv.z, acc[ob4+14]);
                acc[ob4+15] = fmaf(w4.w, sv.w, acc[ob4+15]);
            }
        }
        __syncthreads();
    }

    // coalesced float4 stores: lanes 0-3 cover one full 64B line; wave = 16 full lines
    size_t base = (size_t)b * DD * HWC + (size_t)(p0 + lp) * WW + (q0 + q4);
    #pragma unroll
    for (int oi = 0; oi < 16; oi++) {
        int o = wv * 16 + oi;
        float4 v = make_float4(acc[oi*4+0], acc[oi*4+1], acc[oi*4+2], acc[oi*4+3]);
        *(float4*)(y + base + (size_t)o * HWC) = v;
    }
}

// ---------------- Kernel 3a: per-channel partial sums (512 blocks, float4) ----------------
__global__ __launch_bounds__(256) void k3_partial(
    const float* __restrict__ y, double* __restrict__ part)
{
    int blk = blockIdx.x;            // o*4 + b*2 + half
    int o = blk >> 2; int sub = blk & 3; int b = sub >> 1; int half = sub & 1;
    const float4* pl = (const float4*)(y + ((size_t)b * DD + o) * HWC + half * (HWC/2));
    int tid = threadIdx.x;
    double s = 0.0, s2 = 0.0;
    for (int idx = tid; idx < HWC/8; idx += 256) {
        float4 v = pl[idx];
        s  += (double)v.x + (double)v.y + (double)v.z + (double)v.w;
        s2 += (double)v.x*v.x + (double)v.y*v.y + (double)v.z*v.z + (double)v.w*v.w;
    }
    __shared__ double ls[256], ls2[256];
    ls[tid] = s; ls2[tid] = s2;
    __syncthreads();
    for (int off = 128; off > 0; off >>= 1) {
        if (tid < off) { ls[tid] += ls[tid+off]; ls2[tid] += ls2[tid+off]; }
        __syncthreads();
    }
    if (tid == 0) { part[blk*2] = ls[0]; part[blk*2+1] = ls2[0]; }
}

// ---------------- Kernel 3b: finalize BN scale/shift ----------------
__global__ __launch_bounds__(128) void k3_finalize(
    const double* __restrict__ part, const float* __restrict__ gamma,
    const float* __restrict__ beta, float* __restrict__ stats)
{
    int o = threadIdx.x;
    double s = 0.0, s2 = 0.0;
    #pragma unroll
    for (int j = 0; j < 4; j++) { s += part[(o*4+j)*2]; s2 += part[(o*4+j)*2+1]; }
    double N = (double)(BB * HWC);
    double mean = s / N;
    double var = s2 / N - mean * mean;
    double invs = 1.0 / sqrt(var + 1e-5);
    double g = (double)gamma[o];
    stats[o*2]   = (float)(g * invs);
    stats[o*2+1] = (float)((double)beta[o] - mean * g * invs);
}

// ---------------- Kernel 4: BN + exact GELU, in-place on d_out ----------------
__global__ __launch_bounds__(256) void k4_bn_gelu(
    float* __restrict__ y, const float* __restrict__ stats)
{
    size_t idx4 = (size_t)blockIdx.x * 256 + threadIdx.x;  // float4 index
    float4* p = (float4*)y;
    float4 v = p[idx4];
    int o = (int)((idx4 * 4) / HWC) % DD;
    float sc = stats[o*2], sh = stats[o*2+1];
    const float inv_sqrt2 = 0.70710678118654752f;
    float g0 = fmaf(v.x, sc, sh);
    float g1 = fmaf(v.y, sc, sh);
    float g2 = fmaf(v.z, sc, sh);
    float g3 = fmaf(v.w, sc, sh);
    v.x = 0.5f * g0 * (1.f + erff(g0 * inv_sqrt2));
    v.y = 0.5f * g1 * (1.f + erff(g1 * inv_sqrt2));
    v.z = 0.5f * g2 * (1.f + erff(g2 * inv_sqrt2));
    v.w = 0.5f * g3 * (1.f + erff(g3 * inv_sqrt2));
    p[idx4] = v;
}

extern "C" void kernel_launch(void* const* d_in, const int* in_sizes, int n_in,
                              void* d_out, int out_size, void* d_ws, size_t ws_size,
                              hipStream_t stream) {
    const float* bev   = (const float*)d_in[0];
    const float* offw  = (const float*)d_in[1];
    const float* offb  = (const float*)d_in[2];
    const float* wtw   = (const float*)d_in[3];
    const float* wtb   = (const float*)d_in[4];
    const float* projw = (const float*)d_in[5];
    const float* gamma = (const float*)d_in[6];
    const float* beta  = (const float*)d_in[7];
    float* out = (float*)d_out;

    float* oa    = (float*)d_ws;                 // B*12*H*W = 1,572,864 floats
    float* wtT   = oa + (size_t)BB * 12 * HWC;   // 16384 floats
    float* wp    = wtT + 16384;                  // 13824 floats
    float* stats = wp + 13824;                   // 256 floats (+64 pad)
    double* part = (double*)(stats + 256 + 64);  // 1024 doubles (8B aligned)

    hipLaunchKernelGGL(k0_prep, dim3(64), dim3(256), 0, stream,
                       projw, offw, wtw, wtT, wp);
    hipLaunchKernelGGL(k1_convs, dim3(BB*HH), dim3(256), 0, stream,
                       bev, wp, offb, wtb, oa);
    hipLaunchKernelGGL(k2_sample_proj, dim3(BB*256), dim3(512), 0, stream,
                       bev, oa, wtT, out);
    hipLaunchKernelGGL(k3_partial, dim3(512), dim3(256), 0, stream,
                       out, part);
    hipLaunchKernelGGL(k3_finalize, dim3(1), dim3(128), 0, stream,
                       part, gamma, beta, stats);
    hipLaunchKernelGGL(k4_bn_gelu, dim3((BB*DD*HWC)/1024), dim3(256), 0, stream,
                       out, stats);
}

// Round 5
// 495.092 us; speedup vs baseline: 4.1479x; 1.0212x over previous
//
#include <hip/hip_runtime.h>
#include <math.h>

#define BB 2
#define DD 128
#define HH 256
#define WW 256
#define KK 4
#define HWC (HH*WW)
#define SROW2 320   // d-slice stride in S: 16 rows x 20 floats (p*20+q)

// ws float layout
#define OA_OFF   0
#define WTT_OFF  1572864
#define WP_OFF   1589248
#define STATS_OFF 1603072
#define PART_OFF 1603392
#define BEVT_OFF 1605440
#define WS_NEED_BYTES ((size_t)(BEVT_OFF + 16777216) * 4)

// ---------------- Kernel 0: weight prep ----------------
__global__ __launch_bounds__(256) void k0_prep(
    const float* __restrict__ projw, const float* __restrict__ offw,
    const float* __restrict__ wtw, float* __restrict__ wtT, float* __restrict__ wp)
{
    int idx = blockIdx.x * 256 + threadIdx.x;
    if (idx < 16384) {
        int d = idx >> 7, o = idx & 127;
        wtT[d * 128 + o] = projw[o * 128 + d];
    }
    if (idx < 13824) {
        int c = idx / 108; int r = idx % 108; int o = r / 9; int t = r % 9;
        wp[idx] = (o < 8) ? offw[(o*128 + c)*9 + t] : wtw[((o-8)*128 + c)*9 + t];
    }
}

// ---------------- Kernel T: NCHW -> NHWC transpose (bevt[b][y][x][d]) ----------------
// block: (b, y, x-tile of 64). LDS tile [x][d] with 16B-granule XOR swizzle:
// writes 2-way, float4 reads uniform-bank.
__global__ __launch_bounds__(256) void k2t_transpose(
    const float* __restrict__ bev, float* __restrict__ bevt)
{
    __shared__ float T[64 * 128];   // 32 KB, swizzled
    int tid = threadIdx.x;
    int bidx = blockIdx.x;
    int b = bidx >> 10;
    int rem = bidx & 1023;
    int yrow = rem >> 2;
    int x0 = (rem & 3) << 6;

    const float* src = bev + ((size_t)b * DD) * HWC + (size_t)yrow * WW + x0;
    #pragma unroll 4
    for (int k = 0; k < 32; k++) {
        int flat = k * 256 + tid;
        int d = flat >> 6, xl = flat & 63;
        float v = src[(size_t)d * HWC + xl];
        T[xl * 128 + (((d >> 2) ^ (xl & 31)) << 2) + (d & 3)] = v;
    }
    __syncthreads();
    float* dst = bevt + (((size_t)b * HH + yrow) * WW + x0) * 128;
    #pragma unroll 4
    for (int k = 0; k < 8; k++) {
        int flat = k * 256 + tid;
        int d4 = flat & 31, xl = (flat >> 5) & 63;
        float4 v = *(const float4*)&T[xl * 128 + ((d4 ^ (xl & 31)) << 2)];
        *(float4*)(dst + (size_t)xl * 128 + (d4 << 2)) = v;
    }
}

// ---------------- Kernel 1: 3x3 convs -> offsets(8) + softmaxed attn(4) ----------------
// Groups of 4 channels per barrier (32 barriers), 12 loads in flight.
__global__ __launch_bounds__(256) void k1_convs(
    const float* __restrict__ bev, const float* __restrict__ wp,
    const float* __restrict__ offb, const float* __restrict__ wtb,
    float* __restrict__ oa)
{
    __shared__ float rows[2][12][260];
    int tid = threadIdx.x;
    int p = blockIdx.x;
    int b = p / HH; int i = p % HH; int j = tid;
    const float* bb = bev + (size_t)b * DD * HWC;

    if (tid < 48) { int bf = tid / 24; int r = (tid % 24) >> 1; rows[bf][r][(tid & 1) ? 257 : 0] = 0.f; }

    bool yok[3]; int yy[3];
    #pragma unroll
    for (int l = 0; l < 3; l++) { yy[l] = i + l - 1; yok[l] = ((unsigned)yy[l] < HH); }

    // stage group 0 (channels 0..3)
    #pragma unroll
    for (int cc = 0; cc < 4; cc++)
        #pragma unroll
        for (int l = 0; l < 3; l++)
            rows[0][cc*3 + l][1 + tid] = yok[l] ? bb[(size_t)cc * HWC + yy[l] * WW + tid] : 0.f;
    __syncthreads();

    float acc[12];
    #pragma unroll
    for (int o = 0; o < 12; o++) acc[o] = 0.f;

    for (int g = 0; g < 32; g++) {
        int cb = g & 1;
        float rv[12];
        if (g < 31) {
            #pragma unroll
            for (int cc = 0; cc < 4; cc++) {
                const float* pln = bb + (size_t)((g + 1) * 4 + cc) * HWC;
                #pragma unroll
                for (int l = 0; l < 3; l++)
                    rv[cc*3 + l] = yok[l] ? pln[yy[l] * WW + tid] : 0.f;
            }
        }
        #pragma unroll
        for (int cc = 0; cc < 4; cc++) {
            int c = g * 4 + cc;
            float v[9];
            #pragma unroll
            for (int dy = 0; dy < 3; dy++)
                #pragma unroll
                for (int dx = 0; dx < 3; dx++)
                    v[dy*3 + dx] = rows[cb][cc*3 + dy][tid + dx];
            const float* wc = wp + c * 108;
            #pragma unroll
            for (int o = 0; o < 12; o++) {
                float s = acc[o];
                #pragma unroll
                for (int t = 0; t < 9; t++) s = fmaf(wc[o*9 + t], v[t], s);
                acc[o] = s;
            }
        }
        if (g < 31) {
            #pragma unroll
            for (int l = 0; l < 12; l++) rows[cb ^ 1][l][1 + tid] = rv[l];
        }
        __syncthreads();
    }

    float outv[12];
    #pragma unroll
    for (int o = 0; o < 8; o++) outv[o] = acc[o] + offb[o];
    float l4[4];
    #pragma unroll
    for (int k = 0; k < 4; k++) l4[k] = acc[8+k] + wtb[k];
    float m = fmaxf(fmaxf(l4[0], l4[1]), fmaxf(l4[2], l4[3]));
    float e[4]; float se = 0.f;
    #pragma unroll
    for (int k = 0; k < 4; k++) { e[k] = expf(l4[k] - m); se += e[k]; }
    float inv = 1.f / se;
    #pragma unroll
    for (int k = 0; k < 4; k++) outv[8+k] = e[k] * inv;

    size_t basep = (size_t)b * 12 * HWC + (size_t)i * WW + j;
    #pragma unroll
    for (int o = 0; o < 12; o++) oa[basep + (size_t)o * HWC] = outv[o];
}

// ---------------- Kernel 2 (NHWC): deformable sample + K-aggregate + 1x1 proj ----------------
// 16x16 pixel tile, 512 threads = 256 pixels x 2 d-halves. Per tap: the thread pair
// reads one full 64B line of bevt (16 contiguous channels) as 2x dwordx4 each.
// Depth-1 register prefetch of the next tap; gathers for chunk c+1 interleaved
// into the GEMM dl-loop of chunk c; S double-buffered, one barrier per chunk.
__global__ __launch_bounds__(512, 2) void k2_sample_proj_t(
    const float* __restrict__ bevt, const float* __restrict__ oa,
    const float* __restrict__ wt, float* __restrict__ y)
{
    __shared__ float S[2][16 * SROW2];   // 40 KB

    int tid = threadIdx.x;
    int bidx = blockIdx.x;
    int b  = bidx >> 8;
    int p0 = ((bidx >> 4) & 15) * 16;
    int q0 = (bidx & 15) * 16;

    // gather identity: pixel = tid>>1 (p-fast), d-half = tid&1
    int gpix = tid >> 1;
    int gp = gpix & 15;
    int gq = gpix >> 4;
    int dgrp = tid & 1;
    int swr = gp * 20 + gq;

    // GEMM identity (same as r4)
    int wv = tid >> 6;
    int wvu = __builtin_amdgcn_readfirstlane(wv);
    int lane = tid & 63;
    int lp = lane >> 2;
    int q4 = (lane & 3) << 2;
    int soff = lp * 20 + q4;

    // offsets / attention for this thread's pixel
    const float* ob = oa + (size_t)b * 12 * HWC + (size_t)(p0 + gp) * WW + (q0 + gq);
    unsigned pa[8]; float cw[16];
    #pragma unroll
    for (int k = 0; k < 4; k++) {
        float dx = ob[(size_t)(2*k)   * HWC];
        float dy = ob[(size_t)(2*k+1) * HWC];
        float a  = ob[(size_t)(8+k)   * HWC];
        float x  = fminf(fmaxf((float)(p0 + gp) + dx, 0.f), (float)(WW-1));
        float yv = fminf(fmaxf((float)(q0 + gq) + dy, 0.f), (float)(HH-1));
        float x0f = floorf(x); float y0f = floorf(yv);
        int x0 = (int)x0f; int y0 = (int)y0f;
        int x1 = min(x0 + 1, WW - 1); int y1 = min(y0 + 1, HH - 1);
        float wx = x - x0f; float wy = yv - y0f;
        pa[k*2+0] = (unsigned)(y0*WW + x0) | ((unsigned)(y0*WW + x1) << 16);
        pa[k*2+1] = (unsigned)(y1*WW + x0) | ((unsigned)(y1*WW + x1) << 16);
        cw[k*4+0] = a * (1.f - wx) * (1.f - wy);
        cw[k*4+1] = a * wx * (1.f - wy);
        cw[k*4+2] = a * (1.f - wx) * wy;
        cw[k*4+3] = a * wx * wy;
    }

    // base pointer for this thread's d-half
    const float* bt = bevt + (size_t)b * HWC * 128 + dgrp * 8;

    float acc[64];
    #pragma unroll
    for (int t = 0; t < 64; t++) acc[t] = 0.f;

    // ---- prologue: gather chunk 0 ----
    {
        float4 s0 = make_float4(0,0,0,0), s1 = make_float4(0,0,0,0);
        #pragma unroll
        for (int t = 0; t < 16; t++) {
            unsigned pix = (t & 1) ? (pa[t >> 1] >> 16) : (pa[t >> 1] & 0xffffu);
            const float4* tp = (const float4*)(bt + ((size_t)pix << 7));
            float4 va = tp[0], vb = tp[1];
            float c = cw[t];
            s0.x = fmaf(c, va.x, s0.x); s0.y = fmaf(c, va.y, s0.y);
            s0.z = fmaf(c, va.z, s0.z); s0.w = fmaf(c, va.w, s0.w);
            s1.x = fmaf(c, vb.x, s1.x); s1.y = fmaf(c, vb.y, s1.y);
            s1.z = fmaf(c, vb.z, s1.z); s1.w = fmaf(c, vb.w, s1.w);
        }
        int r = dgrp * 8;
        S[0][(r+0)*SROW2 + swr] = s0.x; S[0][(r+1)*SROW2 + swr] = s0.y;
        S[0][(r+2)*SROW2 + swr] = s0.z; S[0][(r+3)*SROW2 + swr] = s0.w;
        S[0][(r+4)*SROW2 + swr] = s1.x; S[0][(r+5)*SROW2 + swr] = s1.y;
        S[0][(r+6)*SROW2 + swr] = s1.z; S[0][(r+7)*SROW2 + swr] = s1.w;
    }
    __syncthreads();

    // ---- main loop: GEMM chunk c from S[cur]; gather chunk c+1 (1 tap per dl slot) ----
    for (int c = 0; c < 8; c++) {
        int cur = c & 1;
        const float* Sc = &S[cur][0];
        float* Sn = &S[cur ^ 1][0];
        int d0 = c * 16;
        int dn = d0 + 16;
        bool more = (c < 7);

        float4 g0 = make_float4(0,0,0,0), g1 = make_float4(0,0,0,0);
        float4 pf0, pf1;
        if (more) {
            unsigned pix = pa[0] & 0xffffu;
            const float4* tp = (const float4*)(bt + ((size_t)pix << 7) + dn);
            pf0 = tp[0]; pf1 = tp[1];
        }

        #pragma unroll
        for (int dl = 0; dl < 16; dl++) {
            float4 cur0 = pf0, cur1 = pf1;
            if (more && dl < 15) {
                int t = dl + 1;
                unsigned pix = (t & 1) ? (pa[t >> 1] >> 16) : (pa[t >> 1] & 0xffffu);
                const float4* tp = (const float4*)(bt + ((size_t)pix << 7) + dn);
                pf0 = tp[0]; pf1 = tp[1];
            }

            float4 sv = *(const float4*)(Sc + dl * SROW2 + soff);
            const float4* wq = (const float4*)(wt + (size_t)(d0 + dl) * 128 + wvu * 16);
            #pragma unroll
            for (int oi4 = 0; oi4 < 4; oi4++) {
                float4 w4 = wq[oi4];
                int ob4 = oi4 * 16;
                acc[ob4+ 0] = fmaf(w4.x, sv.x, acc[ob4+ 0]);
                acc[ob4+ 1] = fmaf(w4.x, sv.y, acc[ob4+ 1]);
                acc[ob4+ 2] = fmaf(w4.x, sv.z, acc[ob4+ 2]);
                acc[ob4+ 3] = fmaf(w4.x, sv.w, acc[ob4+ 3]);
                acc[ob4+ 4] = fmaf(w4.y, sv.x, acc[ob4+ 4]);
                acc[ob4+ 5] = fmaf(w4.y, sv.y, acc[ob4+ 5]);
                acc[ob4+ 6] = fmaf(w4.y, sv.z, acc[ob4+ 6]);
                acc[ob4+ 7] = fmaf(w4.y, sv.w, acc[ob4+ 7]);
                acc[ob4+ 8] = fmaf(w4.z, sv.x, acc[ob4+ 8]);
                acc[ob4+ 9] = fmaf(w4.z, sv.y, acc[ob4+ 9]);
                acc[ob4+10] = fmaf(w4.z, sv.z, acc[ob4+10]);
                acc[ob4+11] = fmaf(w4.z, sv.w, acc[ob4+11]);
                acc[ob4+12] = fmaf(w4.w, sv.x, acc[ob4+12]);
                acc[ob4+13] = fmaf(w4.w, sv.y, acc[ob4+13]);
                acc[ob4+14] = fmaf(w4.w, sv.z, acc[ob4+14]);
                acc[ob4+15] = fmaf(w4.w, sv.w, acc[ob4+15]);
            }

            if (more) {
                float cwt = cw[dl];
                g0.x = fmaf(cwt, cur0.x, g0.x); g0.y = fmaf(cwt, cur0.y, g0.y);
                g0.z = fmaf(cwt, cur0.z, g0.z); g0.w = fmaf(cwt, cur0.w, g0.w);
                g1.x = fmaf(cwt, cur1.x, g1.x); g1.y = fmaf(cwt, cur1.y, g1.y);
                g1.z = fmaf(cwt, cur1.z, g1.z); g1.w = fmaf(cwt, cur1.w, g1.w);
            }
        }

        if (more) {
            int r = dgrp * 8;
            Sn[(r+0)*SROW2 + swr] = g0.x; Sn[(r+1)*SROW2 + swr] = g0.y;
            Sn[(r+2)*SROW2 + swr] = g0.z; Sn[(r+3)*SROW2 + swr] = g0.w;
            Sn[(r+4)*SROW2 + swr] = g1.x; Sn[(r+5)*SROW2 + swr] = g1.y;
            Sn[(r+6)*SROW2 + swr] = g1.z; Sn[(r+7)*SROW2 + swr] = g1.w;
        }
        __syncthreads();
    }

    size_t base = (size_t)b * DD * HWC + (size_t)(p0 + lp) * WW + (q0 + q4);
    #pragma unroll
    for (int oi = 0; oi < 16; oi++) {
        int o = wv * 16 + oi;
        float4 v = make_float4(acc[oi*4+0], acc[oi*4+1], acc[oi*4+2], acc[oi*4+3]);
        *(float4*)(y + base + (size_t)o * HWC) = v;
    }
}

// ---------------- Kernel 2 fallback (round-4 NCHW version, used if ws too small) ----------------
__global__ __launch_bounds__(512, 2) void k2_sample_proj(
    const float* __restrict__ bev, const float* __restrict__ oa,
    const float* __restrict__ wt, float* __restrict__ y)
{
    __shared__ float S[2][16 * SROW2];
    int tid = threadIdx.x;
    int bidx = blockIdx.x;
    int b  = bidx >> 8;
    int p0 = ((bidx >> 4) & 15) * 16;
    int q0 = (bidx & 15) * 16;
    int pix = tid & 255;
    int gq = pix >> 4;
    int gp = pix & 15;
    int dgrp = tid >> 8;
    int swr = gp * 20 + gq;
    int wv = tid >> 6;
    int wvu = __builtin_amdgcn_readfirstlane(wv);
    int lane = tid & 63;
    int lp = lane >> 2;
    int q4 = (lane & 3) << 2;
    int soff = lp * 20 + q4;

    const float* ob = oa + (size_t)b * 12 * HWC + (size_t)(p0 + gp) * WW + (q0 + gq);
    unsigned pa[8]; float cw[16];
    #pragma unroll
    for (int k = 0; k < 4; k++) {
        float dx = ob[(size_t)(2*k)   * HWC];
        float dy = ob[(size_t)(2*k+1) * HWC];
        float a  = ob[(size_t)(8+k)   * HWC];
        float x  = fminf(fmaxf((float)(p0 + gp) + dx, 0.f), (float)(WW-1));
        float yv = fminf(fmaxf((float)(q0 + gq) + dy, 0.f), (float)(HH-1));
        float x0f = floorf(x); float y0f = floorf(yv);
        int x0 = (int)x0f; int y0 = (int)y0f;
        int x1 = min(x0 + 1, WW - 1); int y1 = min(y0 + 1, HH - 1);
        float wx = x - x0f; float wy = yv - y0f;
        pa[k*2+0] = (unsigned)(y0*WW + x0) | ((unsigned)(y0*WW + x1) << 16);
        pa[k*2+1] = (unsigned)(y1*WW + x0) | ((unsigned)(y1*WW + x1) << 16);
        cw[k*4+0] = a * (1.f - wx) * (1.f - wy);
        cw[k*4+1] = a * wx * (1.f - wy);
        cw[k*4+2] = a * (1.f - wx) * wy;
        cw[k*4+3] = a * wx * wy;
    }
    const float* bb = bev + (size_t)b * DD * HWC;
    float acc[64];
    #pragma unroll
    for (int t = 0; t < 64; t++) acc[t] = 0.f;
    #pragma unroll
    for (int dd = 0; dd < 8; dd++) {
        const float* pl = bb + (size_t)(dgrp*8 + dd) * HWC;
        float s = 0.f;
        #pragma unroll
        for (int t = 0; t < 8; t++) {
            unsigned a01 = pa[t];
            s = fmaf(cw[2*t],   pl[a01 & 0xffffu], s);
            s = fmaf(cw[2*t+1], pl[a01 >> 16], s);
        }
        S[0][(dgrp*8 + dd) * SROW2 + swr] = s;
    }
    __syncthreads();
    for (int c = 0; c < 8; c++) {
        int cur = c & 1;
        const float* Sc = &S[cur][0];
        float* Sn = &S[cur ^ 1][0];
        int d0 = c * 16;
        int d0n = d0 + 16;
        bool more = (c < 7);
        #pragma unroll
        for (int dl = 0; dl < 16; dl++) {
            if (dl < 8) {
                if (more) {
                    const float* pl = bb + (size_t)(d0n + dgrp*8 + dl) * HWC;
                    float s = 0.f;
                    #pragma unroll
                    for (int t = 0; t < 8; t++) {
                        unsigned a01 = pa[t];
                        s = fmaf(cw[2*t],   pl[a01 & 0xffffu], s);
                        s = fmaf(cw[2*t+1], pl[a01 >> 16], s);
                    }
                    Sn[(dgrp*8 + dl) * SROW2 + swr] = s;
                }
            }
            float4 sv = *(const float4*)(Sc + dl * SROW2 + soff);
            const float4* wq = (const float4*)(wt + (size_t)(d0 + dl) * 128 + wvu * 16);
            #pragma unroll
            for (int oi4 = 0; oi4 < 4; oi4++) {
                float4 w4 = wq[oi4];
                int ob4 = oi4 * 16;
                acc[ob4+ 0] = fmaf(w4.x, sv.x, acc[ob4+ 0]);
                acc[ob4+ 1] = fmaf(w4.x, sv.y, acc[ob4+ 1]);
                acc[ob4+ 2] = fmaf(w4.x, sv.z, acc[ob4+ 2]);
                acc[ob4+ 3] = fmaf(w4.x, sv.w, acc[ob4+ 3]);
                acc[ob4+ 4] = fmaf(w4.y, sv.x, acc[ob4+ 4]);
                acc[ob4+ 5] = fmaf(w4.y, sv.y, acc[ob4+ 5]);
                acc[ob4+ 6] = fmaf(w4.y, sv.z, acc[ob4+ 6]);
                acc[ob4+ 7] = fmaf(w4.y, sv.w, acc[ob4+ 7]);
                acc[ob4+ 8] = fmaf(w4.z, sv.x, acc[ob4+ 8]);
                acc[ob4+ 9] = fmaf(w4.z, sv.y, acc[ob4+ 9]);
                acc[ob4+10] = fmaf(w4.z, sv.z, acc[ob4+10]);
                acc[ob4+11] = fmaf(w4.z, sv.w, acc[ob4+11]);
                acc[ob4+12] = fmaf(w4.w, sv.x, acc[ob4+12]);
                acc[ob4+13] = fmaf(w4.w, sv.y, acc[ob4+13]);
                acc[ob4+14] = fmaf(w4.w, sv.z, acc[ob4+14]);
                acc[ob4+15] = fmaf(w4.w, sv.w, acc[ob4+15]);
            }
        }
        __syncthreads();
    }
    size_t base = (size_t)b * DD * HWC + (size_t)(p0 + lp) * WW + (q0 + q4);
    #pragma unroll
    for (int oi = 0; oi < 16; oi++) {
        int o = wv * 16 + oi;
        float4 v = make_float4(acc[oi*4+0], acc[oi*4+1], acc[oi*4+2], acc[oi*4+3]);
        *(float4*)(y + base + (size_t)o * HWC) = v;
    }
}

// ---------------- Kernel 3a: per-channel partial sums ----------------
__global__ __launch_bounds__(256) void k3_partial(
    const float* __restrict__ y, double* __restrict__ part)
{
    int blk = blockIdx.x;
    int o = blk >> 2; int sub = blk & 3; int b = sub >> 1; int half = sub & 1;
    const float4* pl = (const float4*)(y + ((size_t)b * DD + o) * HWC + half * (HWC/2));
    int tid = threadIdx.x;
    double s = 0.0, s2 = 0.0;
    for (int idx = tid; idx < HWC/8; idx += 256) {
        float4 v = pl[idx];
        s  += (double)v.x + (double)v.y + (double)v.z + (double)v.w;
        s2 += (double)v.x*v.x + (double)v.y*v.y + (double)v.z*v.z + (double)v.w*v.w;
    }
    __shared__ double ls[256], ls2[256];
    ls[tid] = s; ls2[tid] = s2;
    __syncthreads();
    for (int off = 128; off > 0; off >>= 1) {
        if (tid < off) { ls[tid] += ls[tid+off]; ls2[tid] += ls2[tid+off]; }
        __syncthreads();
    }
    if (tid == 0) { part[blk*2] = ls[0]; part[blk*2+1] = ls2[0]; }
}

// ---------------- Kernel 3b: finalize BN scale/shift ----------------
__global__ __launch_bounds__(128) void k3_finalize(
    const double* __restrict__ part, const float* __restrict__ gamma,
    const float* __restrict__ beta, float* __restrict__ stats)
{
    int o = threadIdx.x;
    double s = 0.0, s2 = 0.0;
    #pragma unroll
    for (int j = 0; j < 4; j++) { s += part[(o*4+j)*2]; s2 += part[(o*4+j)*2+1]; }
    double N = (double)(BB * HWC);
    double mean = s / N;
    double var = s2 / N - mean * mean;
    double invs = 1.0 / sqrt(var + 1e-5);
    double g = (double)gamma[o];
    stats[o*2]   = (float)(g * invs);
    stats[o*2+1] = (float)((double)beta[o] - mean * g * invs);
}

// ---------------- Kernel 4: BN + exact GELU ----------------
__global__ __launch_bounds__(256) void k4_bn_gelu(
    float* __restrict__ y, const float* __restrict__ stats)
{
    size_t idx4 = (size_t)blockIdx.x * 256 + threadIdx.x;
    float4* p = (float4*)y;
    float4 v = p[idx4];
    int o = (int)((idx4 * 4) / HWC) % DD;
    float sc = stats[o*2], sh = stats[o*2+1];
    const float inv_sqrt2 = 0.70710678118654752f;
    float g0 = fmaf(v.x, sc, sh);
    float g1 = fmaf(v.y, sc, sh);
    float g2 = fmaf(v.z, sc, sh);
    float g3 = fmaf(v.w, sc, sh);
    v.x = 0.5f * g0 * (1.f + erff(g0 * inv_sqrt2));
    v.y = 0.5f * g1 * (1.f + erff(g1 * inv_sqrt2));
    v.z = 0.5f * g2 * (1.f + erff(g2 * inv_sqrt2));
    v.w = 0.5f * g3 * (1.f + erff(g3 * inv_sqrt2));
    p[idx4] = v;
}

extern "C" void kernel_launch(void* const* d_in, const int* in_sizes, int n_in,
                              void* d_out, int out_size, void* d_ws, size_t ws_size,
                              hipStream_t stream) {
    const float* bev   = (const float*)d_in[0];
    const float* offw  = (const float*)d_in[1];
    const float* offb  = (const float*)d_in[2];
    const float* wtw   = (const float*)d_in[3];
    const float* wtb   = (const float*)d_in[4];
    const float* projw = (const float*)d_in[5];
    const float* gamma = (const float*)d_in[6];
    const float* beta  = (const float*)d_in[7];
    float* out = (float*)d_out;
    float* wsf = (float*)d_ws;

    float* oa    = wsf + OA_OFF;
    float* wtT   = wsf + WTT_OFF;
    float* wp    = wsf + WP_OFF;
    float* stats = wsf + STATS_OFF;
    double* part = (double*)(wsf + PART_OFF);
    float* bevt  = wsf + BEVT_OFF;

    bool big = ws_size >= WS_NEED_BYTES;

    hipLaunchKernelGGL(k0_prep, dim3(64), dim3(256), 0, stream,
                       projw, offw, wtw, wtT, wp);
    if (big) {
        hipLaunchKernelGGL(k2t_transpose, dim3(2048), dim3(256), 0, stream,
                           bev, bevt);
    }
    hipLaunchKernelGGL(k1_convs, dim3(BB*HH), dim3(256), 0, stream,
                       bev, wp, offb, wtb, oa);
    if (big) {
        hipLaunchKernelGGL(k2_sample_proj_t, dim3(BB*256), dim3(512), 0, stream,
                           bevt, oa, wtT, out);
    } else {
        hipLaunchKernelGGL(k2_sample_proj, dim3(BB*256), dim3(512), 0, stream,
                           bev, oa, wtT, out);
    }
    hipLaunchKernelGGL(k3_partial, dim3(512), dim3(256), 0, stream,
                       out, part);
    hipLaunchKernelGGL(k3_finalize, dim3(1), dim3(128), 0, stream,
                       part, gamma, beta, stats);
    hipLaunchKernelGGL(k4_bn_gelu, dim3((BB*DD*HWC)/1024), dim3(256), 0, stream,
                       out, stats);
}

// Round 6
// 298.223 us; speedup vs baseline: 6.8860x; 1.6601x over previous
//
#include <hip/hip_runtime.h>
#include <math.h>

#define BB 2
#define DD 128
#define HH 256
#define WW 256
#define KK 4
#define HWC (HH*WW)
#define SROW2 320   // d-slice stride in S: 16 rows x 20 floats (p*20+q)

// ws float layout
#define OA_OFF    0
#define WTT_OFF   1572864
#define WP_OFF    1589248
#define STATS_OFF 1603072
#define PART_OFF  1603392
#define BEVT_OFF  1605440
#define PACC_OFF  18382656
#define WS_NEED_BEVT ((size_t)PACC_OFF * 4)
#define WS_NEED_FULL ((size_t)(PACC_OFF + 6291456) * 4)

// ---------------- Kernel 0: weight prep ----------------
__global__ __launch_bounds__(256) void k0_prep(
    const float* __restrict__ projw, const float* __restrict__ offw,
    const float* __restrict__ wtw, float* __restrict__ wtT, float* __restrict__ wp)
{
    int idx = blockIdx.x * 256 + threadIdx.x;
    if (idx < 16384) {
        int d = idx >> 7, o = idx & 127;
        wtT[d * 128 + o] = projw[o * 128 + d];
    }
    if (idx < 13824) {
        int c = idx / 108; int r = idx % 108; int o = r / 9; int t = r % 9;
        wp[idx] = (o < 8) ? offw[(o*128 + c)*9 + t] : wtw[((o-8)*128 + c)*9 + t];
    }
}

// ---------------- Kernel T: NCHW -> NHWC transpose (bevt[b][y][x][d]) ----------------
__global__ __launch_bounds__(256) void k2t_transpose(
    const float* __restrict__ bev, float* __restrict__ bevt)
{
    __shared__ float T[64 * 128];   // 32 KB, swizzled
    int tid = threadIdx.x;
    int bidx = blockIdx.x;
    int b = bidx >> 10;
    int rem = bidx & 1023;
    int yrow = rem >> 2;
    int x0 = (rem & 3) << 6;

    const float* src = bev + ((size_t)b * DD) * HWC + (size_t)yrow * WW + x0;
    #pragma unroll 4
    for (int k = 0; k < 32; k++) {
        int flat = k * 256 + tid;
        int d = flat >> 6, xl = flat & 63;
        float v = src[(size_t)d * HWC + xl];
        T[xl * 128 + (((d >> 2) ^ (xl & 31)) << 2) + (d & 3)] = v;
    }
    __syncthreads();
    float* dst = bevt + (((size_t)b * HH + yrow) * WW + x0) * 128;
    #pragma unroll 4
    for (int k = 0; k < 8; k++) {
        int flat = k * 256 + tid;
        int d4 = flat & 31, xl = (flat >> 5) & 63;
        float4 v = *(const float4*)&T[xl * 128 + ((d4 ^ (xl & 31)) << 2)];
        *(float4*)(dst + (size_t)xl * 128 + (d4 << 2)) = v;
    }
}

// ---------------- Kernel 1a: partial 3x3 convs over a 32-channel chunk ----------------
// block = (chunk, b, i), thread j. 4x the blocks of the old k1 -> 8 blocks/CU:
// latency hidden by TLP (r5 lesson: 2 blocks/CU left conv latency-bound at 8% VALU).
// r4 inner structure: 1 channel per barrier, 3-row LDS double buffer.
__global__ __launch_bounds__(256) void k1a_convs_partial(
    const float* __restrict__ bev, const float* __restrict__ wp,
    float* __restrict__ pacc)
{
    __shared__ float rows[2][3][260];
    int tid = threadIdx.x;
    int bidx = blockIdx.x;
    int chunk = bidx >> 9;          // 0..3
    int b = (bidx >> 8) & 1;
    int i = bidx & 255;
    int c0 = chunk * 32;
    const float* bb = bev + (size_t)b * DD * HWC;

    if (tid < 12) { int bf = tid / 6, r = tid % 6; rows[bf][r >> 1][(r & 1) ? 257 : 0] = 0.f; }

    int yy[3]; bool yok[3];
    #pragma unroll
    for (int l = 0; l < 3; l++) { yy[l] = i + l - 1; yok[l] = ((unsigned)yy[l] < HH); }

    #pragma unroll
    for (int l = 0; l < 3; l++)
        rows[0][l][1 + tid] = yok[l] ? bb[(size_t)c0 * HWC + yy[l] * WW + tid] : 0.f;
    __syncthreads();

    float acc[12];
    #pragma unroll
    for (int o = 0; o < 12; o++) acc[o] = 0.f;

    for (int cc = 0; cc < 32; cc++) {
        int cb = cc & 1, nb = cb ^ 1;
        float rv[3];
        if (cc < 31) {
            const float* pln = bb + (size_t)(c0 + cc + 1) * HWC;
            #pragma unroll
            for (int l = 0; l < 3; l++)
                rv[l] = yok[l] ? pln[yy[l] * WW + tid] : 0.f;
        }
        float v[9];
        #pragma unroll
        for (int dy = 0; dy < 3; dy++)
            #pragma unroll
            for (int dx = 0; dx < 3; dx++)
                v[dy*3 + dx] = rows[cb][dy][tid + dx];
        const float* wc = wp + (c0 + cc) * 108;   // uniform -> scalar loads
        #pragma unroll
        for (int o = 0; o < 12; o++) {
            float s = acc[o];
            #pragma unroll
            for (int t = 0; t < 9; t++) s = fmaf(wc[o*9 + t], v[t], s);
            acc[o] = s;
        }
        if (cc < 31) {
            #pragma unroll
            for (int l = 0; l < 3; l++) rows[nb][l][1 + tid] = rv[l];
        }
        __syncthreads();
    }

    size_t basep = (size_t)(chunk * 2 + b) * 12 * HWC + (size_t)i * WW + tid;
    #pragma unroll
    for (int o = 0; o < 12; o++) pacc[basep + (size_t)o * HWC] = acc[o];
}

// ---------------- Kernel 1b: reduce 4 chunk partials + bias + softmax ----------------
__global__ __launch_bounds__(256) void k1b_reduce(
    const float* __restrict__ pacc, const float* __restrict__ offb,
    const float* __restrict__ wtb, float* __restrict__ oa)
{
    int p = blockIdx.x;
    int b = p >> 8; int i = p & 255; int tid = threadIdx.x;
    size_t pbase = (size_t)i * WW + tid;

    float acc[12];
    #pragma unroll
    for (int o = 0; o < 12; o++) {
        float s = 0.f;
        #pragma unroll
        for (int ch = 0; ch < 4; ch++)
            s += pacc[(size_t)(ch * 2 + b) * 12 * HWC + (size_t)o * HWC + pbase];
        acc[o] = s;
    }

    float outv[12];
    #pragma unroll
    for (int o = 0; o < 8; o++) outv[o] = acc[o] + offb[o];
    float l4[4];
    #pragma unroll
    for (int k = 0; k < 4; k++) l4[k] = acc[8+k] + wtb[k];
    float m = fmaxf(fmaxf(l4[0], l4[1]), fmaxf(l4[2], l4[3]));
    float e[4]; float se = 0.f;
    #pragma unroll
    for (int k = 0; k < 4; k++) { e[k] = expf(l4[k] - m); se += e[k]; }
    float inv = 1.f / se;
    #pragma unroll
    for (int k = 0; k < 4; k++) outv[8+k] = e[k] * inv;

    size_t basep = (size_t)b * 12 * HWC + pbase;
    #pragma unroll
    for (int o = 0; o < 12; o++) oa[basep + (size_t)o * HWC] = outv[o];
}

// ---------------- Kernel 1 (fallback, r4 version): full 128-channel conv ----------------
__global__ __launch_bounds__(256) void k1_convs(
    const float* __restrict__ bev, const float* __restrict__ wp,
    const float* __restrict__ offb, const float* __restrict__ wtb,
    float* __restrict__ oa)
{
    __shared__ float rows[2][3][260];
    int tid = threadIdx.x;
    int p = blockIdx.x;
    int b = p / HH; int i = p % HH; int j = tid;
    const float* bb = bev + (size_t)b * DD * HWC;

    if (tid < 12) { int bf = tid / 6, r = tid % 6; rows[bf][r >> 1][(r & 1) ? 257 : 0] = 0.f; }
    #pragma unroll
    for (int l = 0; l < 3; l++) {
        int yy = i + l - 1;
        rows[0][l][1 + tid] = ((unsigned)yy < HH) ? bb[yy * WW + tid] : 0.f;
    }
    __syncthreads();

    float acc[12];
    #pragma unroll
    for (int o = 0; o < 12; o++) acc[o] = 0.f;

    for (int c = 0; c < 128; c++) {
        int cb = c & 1, nb = cb ^ 1;
        float rv[3];
        if (c < 127) {
            const float* pln = bb + (size_t)(c + 1) * HWC;
            #pragma unroll
            for (int l = 0; l < 3; l++) {
                int yy = i + l - 1;
                rv[l] = ((unsigned)yy < HH) ? pln[yy * WW + tid] : 0.f;
            }
        }
        float v[9];
        #pragma unroll
        for (int dy = 0; dy < 3; dy++)
            #pragma unroll
            for (int dx = 0; dx < 3; dx++)
                v[dy*3 + dx] = rows[cb][dy][tid + dx];
        const float* wc = wp + c * 108;
        #pragma unroll
        for (int o = 0; o < 12; o++) {
            float s = acc[o];
            #pragma unroll
            for (int t = 0; t < 9; t++) s = fmaf(wc[o*9 + t], v[t], s);
            acc[o] = s;
        }
        if (c < 127) {
            #pragma unroll
            for (int l = 0; l < 3; l++) rows[nb][l][1 + tid] = rv[l];
        }
        __syncthreads();
    }

    float outv[12];
    #pragma unroll
    for (int o = 0; o < 8; o++) outv[o] = acc[o] + offb[o];
    float l4[4];
    #pragma unroll
    for (int k = 0; k < 4; k++) l4[k] = acc[8+k] + wtb[k];
    float m = fmaxf(fmaxf(l4[0], l4[1]), fmaxf(l4[2], l4[3]));
    float e[4]; float se = 0.f;
    #pragma unroll
    for (int k = 0; k < 4; k++) { e[k] = expf(l4[k] - m); se += e[k]; }
    float inv = 1.f / se;
    #pragma unroll
    for (int k = 0; k < 4; k++) outv[8+k] = e[k] * inv;

    size_t basep = (size_t)b * 12 * HWC + (size_t)i * WW + j;
    #pragma unroll
    for (int o = 0; o < 12; o++) oa[basep + (size_t)o * HWC] = outv[o];
}

// ---------------- Kernel 2 (NHWC): deformable sample + K-aggregate + 1x1 proj ----------------
__global__ __launch_bounds__(512, 2) void k2_sample_proj_t(
    const float* __restrict__ bevt, const float* __restrict__ oa,
    const float* __restrict__ wt, float* __restrict__ y)
{
    __shared__ float S[2][16 * SROW2];   // 40 KB

    int tid = threadIdx.x;
    int bidx = blockIdx.x;
    int b  = bidx >> 8;
    int p0 = ((bidx >> 4) & 15) * 16;
    int q0 = (bidx & 15) * 16;

    int gpix = tid >> 1;
    int gp = gpix & 15;
    int gq = gpix >> 4;
    int dgrp = tid & 1;
    int swr = gp * 20 + gq;

    int wv = tid >> 6;
    int wvu = __builtin_amdgcn_readfirstlane(wv);
    int lane = tid & 63;
    int lp = lane >> 2;
    int q4 = (lane & 3) << 2;
    int soff = lp * 20 + q4;

    const float* ob = oa + (size_t)b * 12 * HWC + (size_t)(p0 + gp) * WW + (q0 + gq);
    unsigned pa[8]; float cw[16];
    #pragma unroll
    for (int k = 0; k < 4; k++) {
        float dx = ob[(size_t)(2*k)   * HWC];
        float dy = ob[(size_t)(2*k+1) * HWC];
        float a  = ob[(size_t)(8+k)   * HWC];
        float x  = fminf(fmaxf((float)(p0 + gp) + dx, 0.f), (float)(WW-1));
        float yv = fminf(fmaxf((float)(q0 + gq) + dy, 0.f), (float)(HH-1));
        float x0f = floorf(x); float y0f = floorf(yv);
        int x0 = (int)x0f; int y0 = (int)y0f;
        int x1 = min(x0 + 1, WW - 1); int y1 = min(y0 + 1, HH - 1);
        float wx = x - x0f; float wy = yv - y0f;
        pa[k*2+0] = (unsigned)(y0*WW + x0) | ((unsigned)(y0*WW + x1) << 16);
        pa[k*2+1] = (unsigned)(y1*WW + x0) | ((unsigned)(y1*WW + x1) << 16);
        cw[k*4+0] = a * (1.f - wx) * (1.f - wy);
        cw[k*4+1] = a * wx * (1.f - wy);
        cw[k*4+2] = a * (1.f - wx) * wy;
        cw[k*4+3] = a * wx * wy;
    }

    const float* bt = bevt + (size_t)b * HWC * 128 + dgrp * 8;

    float acc[64];
    #pragma unroll
    for (int t = 0; t < 64; t++) acc[t] = 0.f;

    {
        float4 s0 = make_float4(0,0,0,0), s1 = make_float4(0,0,0,0);
        #pragma unroll
        for (int t = 0; t < 16; t++) {
            unsigned pix = (t & 1) ? (pa[t >> 1] >> 16) : (pa[t >> 1] & 0xffffu);
            const float4* tp = (const float4*)(bt + ((size_t)pix << 7));
            float4 va = tp[0], vb = tp[1];
            float c = cw[t];
            s0.x = fmaf(c, va.x, s0.x); s0.y = fmaf(c, va.y, s0.y);
            s0.z = fmaf(c, va.z, s0.z); s0.w = fmaf(c, va.w, s0.w);
            s1.x = fmaf(c, vb.x, s1.x); s1.y = fmaf(c, vb.y, s1.y);
            s1.z = fmaf(c, vb.z, s1.z); s1.w = fmaf(c, vb.w, s1.w);
        }
        int r = dgrp * 8;
        S[0][(r+0)*SROW2 + swr] = s0.x; S[0][(r+1)*SROW2 + swr] = s0.y;
        S[0][(r+2)*SROW2 + swr] = s0.z; S[0][(r+3)*SROW2 + swr] = s0.w;
        S[0][(r+4)*SROW2 + swr] = s1.x; S[0][(r+5)*SROW2 + swr] = s1.y;
        S[0][(r+6)*SROW2 + swr] = s1.z; S[0][(r+7)*SROW2 + swr] = s1.w;
    }
    __syncthreads();

    for (int c = 0; c < 8; c++) {
        int cur = c & 1;
        const float* Sc = &S[cur][0];
        float* Sn = &S[cur ^ 1][0];
        int d0 = c * 16;
        int dn = d0 + 16;
        bool more = (c < 7);

        float4 g0 = make_float4(0,0,0,0), g1 = make_float4(0,0,0,0);
        float4 pf0, pf1;
        if (more) {
            unsigned pix = pa[0] & 0xffffu;
            const float4* tp = (const float4*)(bt + ((size_t)pix << 7) + dn);
            pf0 = tp[0]; pf1 = tp[1];
        }

        #pragma unroll
        for (int dl = 0; dl < 16; dl++) {
            float4 cur0 = pf0, cur1 = pf1;
            if (more && dl < 15) {
                int t = dl + 1;
                unsigned pix = (t & 1) ? (pa[t >> 1] >> 16) : (pa[t >> 1] & 0xffffu);
                const float4* tp = (const float4*)(bt + ((size_t)pix << 7) + dn);
                pf0 = tp[0]; pf1 = tp[1];
            }

            float4 sv = *(const float4*)(Sc + dl * SROW2 + soff);
            const float4* wq = (const float4*)(wt + (size_t)(d0 + dl) * 128 + wvu * 16);
            #pragma unroll
            for (int oi4 = 0; oi4 < 4; oi4++) {
                float4 w4 = wq[oi4];
                int ob4 = oi4 * 16;
                acc[ob4+ 0] = fmaf(w4.x, sv.x, acc[ob4+ 0]);
                acc[ob4+ 1] = fmaf(w4.x, sv.y, acc[ob4+ 1]);
                acc[ob4+ 2] = fmaf(w4.x, sv.z, acc[ob4+ 2]);
                acc[ob4+ 3] = fmaf(w4.x, sv.w, acc[ob4+ 3]);
                acc[ob4+ 4] = fmaf(w4.y, sv.x, acc[ob4+ 4]);
                acc[ob4+ 5] = fmaf(w4.y, sv.y, acc[ob4+ 5]);
                acc[ob4+ 6] = fmaf(w4.y, sv.z, acc[ob4+ 6]);
                acc[ob4+ 7] = fmaf(w4.y, sv.w, acc[ob4+ 7]);
                acc[ob4+ 8] = fmaf(w4.z, sv.x, acc[ob4+ 8]);
                acc[ob4+ 9] = fmaf(w4.z, sv.y, acc[ob4+ 9]);
                acc[ob4+10] = fmaf(w4.z, sv.z, acc[ob4+10]);
                acc[ob4+11] = fmaf(w4.z, sv.w, acc[ob4+11]);
                acc[ob4+12] = fmaf(w4.w, sv.x, acc[ob4+12]);
                acc[ob4+13] = fmaf(w4.w, sv.y, acc[ob4+13]);
                acc[ob4+14] = fmaf(w4.w, sv.z, acc[ob4+14]);
                acc[ob4+15] = fmaf(w4.w, sv.w, acc[ob4+15]);
            }

            if (more) {
                float cwt = cw[dl];
                g0.x = fmaf(cwt, cur0.x, g0.x); g0.y = fmaf(cwt, cur0.y, g0.y);
                g0.z = fmaf(cwt, cur0.z, g0.z); g0.w = fmaf(cwt, cur0.w, g0.w);
                g1.x = fmaf(cwt, cur1.x, g1.x); g1.y = fmaf(cwt, cur1.y, g1.y);
                g1.z = fmaf(cwt, cur1.z, g1.z); g1.w = fmaf(cwt, cur1.w, g1.w);
            }
        }

        if (more) {
            int r = dgrp * 8;
            Sn[(r+0)*SROW2 + swr] = g0.x; Sn[(r+1)*SROW2 + swr] = g0.y;
            Sn[(r+2)*SROW2 + swr] = g0.z; Sn[(r+3)*SROW2 + swr] = g0.w;
            Sn[(r+4)*SROW2 + swr] = g1.x; Sn[(r+5)*SROW2 + swr] = g1.y;
            Sn[(r+6)*SROW2 + swr] = g1.z; Sn[(r+7)*SROW2 + swr] = g1.w;
        }
        __syncthreads();
    }

    size_t base = (size_t)b * DD * HWC + (size_t)(p0 + lp) * WW + (q0 + q4);
    #pragma unroll
    for (int oi = 0; oi < 16; oi++) {
        int o = wv * 16 + oi;
        float4 v = make_float4(acc[oi*4+0], acc[oi*4+1], acc[oi*4+2], acc[oi*4+3]);
        *(float4*)(y + base + (size_t)o * HWC) = v;
    }
}

// ---------------- Kernel 2 fallback (NCHW) ----------------
__global__ __launch_bounds__(512, 2) void k2_sample_proj(
    const float* __restrict__ bev, const float* __restrict__ oa,
    const float* __restrict__ wt, float* __restrict__ y)
{
    __shared__ float S[2][16 * SROW2];
    int tid = threadIdx.x;
    int bidx = blockIdx.x;
    int b  = bidx >> 8;
    int p0 = ((bidx >> 4) & 15) * 16;
    int q0 = (bidx & 15) * 16;
    int pix = tid & 255;
    int gq = pix >> 4;
    int gp = pix & 15;
    int dgrp = tid >> 8;
    int swr = gp * 20 + gq;
    int wv = tid >> 6;
    int wvu = __builtin_amdgcn_readfirstlane(wv);
    int lane = tid & 63;
    int lp = lane >> 2;
    int q4 = (lane & 3) << 2;
    int soff = lp * 20 + q4;

    const float* ob = oa + (size_t)b * 12 * HWC + (size_t)(p0 + gp) * WW + (q0 + gq);
    unsigned pa[8]; float cw[16];
    #pragma unroll
    for (int k = 0; k < 4; k++) {
        float dx = ob[(size_t)(2*k)   * HWC];
        float dy = ob[(size_t)(2*k+1) * HWC];
        float a  = ob[(size_t)(8+k)   * HWC];
        float x  = fminf(fmaxf((float)(p0 + gp) + dx, 0.f), (float)(WW-1));
        float yv = fminf(fmaxf((float)(q0 + gq) + dy, 0.f), (float)(HH-1));
        float x0f = floorf(x); float y0f = floorf(yv);
        int x0 = (int)x0f; int y0 = (int)y0f;
        int x1 = min(x0 + 1, WW - 1); int y1 = min(y0 + 1, HH - 1);
        float wx = x - x0f; float wy = yv - y0f;
        pa[k*2+0] = (unsigned)(y0*WW + x0) | ((unsigned)(y0*WW + x1) << 16);
        pa[k*2+1] = (unsigned)(y1*WW + x0) | ((unsigned)(y1*WW + x1) << 16);
        cw[k*4+0] = a * (1.f - wx) * (1.f - wy);
        cw[k*4+1] = a * wx * (1.f - wy);
        cw[k*4+2] = a * (1.f - wx) * wy;
        cw[k*4+3] = a * wx * wy;
    }
    const float* bb = bev + (size_t)b * DD * HWC;
    float acc[64];
    #pragma unroll
    for (int t = 0; t < 64; t++) acc[t] = 0.f;
    #pragma unroll
    for (int dd = 0; dd < 8; dd++) {
        const float* pl = bb + (size_t)(dgrp*8 + dd) * HWC;
        float s = 0.f;
        #pragma unroll
        for (int t = 0; t < 8; t++) {
            unsigned a01 = pa[t];
            s = fmaf(cw[2*t],   pl[a01 & 0xffffu], s);
            s = fmaf(cw[2*t+1], pl[a01 >> 16], s);
        }
        S[0][(dgrp*8 + dd) * SROW2 + swr] = s;
    }
    __syncthreads();
    for (int c = 0; c < 8; c++) {
        int cur = c & 1;
        const float* Sc = &S[cur][0];
        float* Sn = &S[cur ^ 1][0];
        int d0 = c * 16;
        int d0n = d0 + 16;
        bool more = (c < 7);
        #pragma unroll
        for (int dl = 0; dl < 16; dl++) {
            if (dl < 8) {
                if (more) {
                    const float* pl = bb + (size_t)(d0n + dgrp*8 + dl) * HWC;
                    float s = 0.f;
                    #pragma unroll
                    for (int t = 0; t < 8; t++) {
                        unsigned a01 = pa[t];
                        s = fmaf(cw[2*t],   pl[a01 & 0xffffu], s);
                        s = fmaf(cw[2*t+1], pl[a01 >> 16], s);
                    }
                    Sn[(dgrp*8 + dl) * SROW2 + swr] = s;
                }
            }
            float4 sv = *(const float4*)(Sc + dl * SROW2 + soff);
            const float4* wq = (const float4*)(wt + (size_t)(d0 + dl) * 128 + wvu * 16);
            #pragma unroll
            for (int oi4 = 0; oi4 < 4; oi4++) {
                float4 w4 = wq[oi4];
                int ob4 = oi4 * 16;
                acc[ob4+ 0] = fmaf(w4.x, sv.x, acc[ob4+ 0]);
                acc[ob4+ 1] = fmaf(w4.x, sv.y, acc[ob4+ 1]);
                acc[ob4+ 2] = fmaf(w4.x, sv.z, acc[ob4+ 2]);
                acc[ob4+ 3] = fmaf(w4.x, sv.w, acc[ob4+ 3]);
                acc[ob4+ 4] = fmaf(w4.y, sv.x, acc[ob4+ 4]);
                acc[ob4+ 5] = fmaf(w4.y, sv.y, acc[ob4+ 5]);
                acc[ob4+ 6] = fmaf(w4.y, sv.z, acc[ob4+ 6]);
                acc[ob4+ 7] = fmaf(w4.y, sv.w, acc[ob4+ 7]);
                acc[ob4+ 8] = fmaf(w4.z, sv.x, acc[ob4+ 8]);
                acc[ob4+ 9] = fmaf(w4.z, sv.y, acc[ob4+ 9]);
                acc[ob4+10] = fmaf(w4.z, sv.z, acc[ob4+10]);
                acc[ob4+11] = fmaf(w4.z, sv.w, acc[ob4+11]);
                acc[ob4+12] = fmaf(w4.w, sv.x, acc[ob4+12]);
                acc[ob4+13] = fmaf(w4.w, sv.y, acc[ob4+13]);
                acc[ob4+14] = fmaf(w4.w, sv.z, acc[ob4+14]);
                acc[ob4+15] = fmaf(w4.w, sv.w, acc[ob4+15]);
            }
        }
        __syncthreads();
    }
    size_t base = (size_t)b * DD * HWC + (size_t)(p0 + lp) * WW + (q0 + q4);
    #pragma unroll
    for (int oi = 0; oi < 16; oi++) {
        int o = wv * 16 + oi;
        float4 v = make_float4(acc[oi*4+0], acc[oi*4+1], acc[oi*4+2], acc[oi*4+3]);
        *(float4*)(y + base + (size_t)o * HWC) = v;
    }
}

// ---------------- Kernel 3a: per-channel partial sums ----------------
__global__ __launch_bounds__(256) void k3_partial(
    const float* __restrict__ y, double* __restrict__ part)
{
    int blk = blockIdx.x;
    int o = blk >> 2; int sub = blk & 3; int b = sub >> 1; int half = sub & 1;
    const float4* pl = (const float4*)(y + ((size_t)b * DD + o) * HWC + half * (HWC/2));
    int tid = threadIdx.x;
    double s = 0.0, s2 = 0.0;
    for (int idx = tid; idx < HWC/8; idx += 256) {
        float4 v = pl[idx];
        s  += (double)v.x + (double)v.y + (double)v.z + (double)v.w;
        s2 += (double)v.x*v.x + (double)v.y*v.y + (double)v.z*v.z + (double)v.w*v.w;
    }
    __shared__ double ls[256], ls2[256];
    ls[tid] = s; ls2[tid] = s2;
    __syncthreads();
    for (int off = 128; off > 0; off >>= 1) {
        if (tid < off) { ls[tid] += ls[tid+off]; ls2[tid] += ls2[tid+off]; }
        __syncthreads();
    }
    if (tid == 0) { part[blk*2] = ls[0]; part[blk*2+1] = ls2[0]; }
}

// ---------------- Kernel 3b: finalize BN scale/shift ----------------
__global__ __launch_bounds__(128) void k3_finalize(
    const double* __restrict__ part, const float* __restrict__ gamma,
    const float* __restrict__ beta, float* __restrict__ stats)
{
    int o = threadIdx.x;
    double s = 0.0, s2 = 0.0;
    #pragma unroll
    for (int j = 0; j < 4; j++) { s += part[(o*4+j)*2]; s2 += part[(o*4+j)*2+1]; }
    double N = (double)(BB * HWC);
    double mean = s / N;
    double var = s2 / N - mean * mean;
    double invs = 1.0 / sqrt(var + 1e-5);
    double g = (double)gamma[o];
    stats[o*2]   = (float)(g * invs);
    stats[o*2+1] = (float)((double)beta[o] - mean * g * invs);
}

// ---------------- Kernel 4: BN + exact GELU ----------------
__global__ __launch_bounds__(256) void k4_bn_gelu(
    float* __restrict__ y, const float* __restrict__ stats)
{
    size_t idx4 = (size_t)blockIdx.x * 256 + threadIdx.x;
    float4* p = (float4*)y;
    float4 v = p[idx4];
    int o = (int)((idx4 * 4) / HWC) % DD;
    float sc = stats[o*2], sh = stats[o*2+1];
    const float inv_sqrt2 = 0.70710678118654752f;
    float g0 = fmaf(v.x, sc, sh);
    float g1 = fmaf(v.y, sc, sh);
    float g2 = fmaf(v.z, sc, sh);
    float g3 = fmaf(v.w, sc, sh);
    v.x = 0.5f * g0 * (1.f + erff(g0 * inv_sqrt2));
    v.y = 0.5f * g1 * (1.f + erff(g1 * inv_sqrt2));
    v.z = 0.5f * g2 * (1.f + erff(g2 * inv_sqrt2));
    v.w = 0.5f * g3 * (1.f + erff(g3 * inv_sqrt2));
    p[idx4] = v;
}

extern "C" void kernel_launch(void* const* d_in, const int* in_sizes, int n_in,
                              void* d_out, int out_size, void* d_ws, size_t ws_size,
                              hipStream_t stream) {
    const float* bev   = (const float*)d_in[0];
    const float* offw  = (const float*)d_in[1];
    const float* offb  = (const float*)d_in[2];
    const float* wtw   = (const float*)d_in[3];
    const float* wtb   = (const float*)d_in[4];
    const float* projw = (const float*)d_in[5];
    const float* gamma = (const float*)d_in[6];
    const float* beta  = (const float*)d_in[7];
    float* out = (float*)d_out;
    float* wsf = (float*)d_ws;

    float* oa    = wsf + OA_OFF;
    float* wtT   = wsf + WTT_OFF;
    float* wp    = wsf + WP_OFF;
    float* stats = wsf + STATS_OFF;
    double* part = (double*)(wsf + PART_OFF);
    float* bevt  = wsf + BEVT_OFF;
    float* pacc  = wsf + PACC_OFF;

    bool full = ws_size >= WS_NEED_FULL;
    bool big  = ws_size >= WS_NEED_BEVT;

    hipLaunchKernelGGL(k0_prep, dim3(64), dim3(256), 0, stream,
                       projw, offw, wtw, wtT, wp);
    if (big) {
        hipLaunchKernelGGL(k2t_transpose, dim3(2048), dim3(256), 0, stream,
                           bev, bevt);
    }
    if (full) {
        hipLaunchKernelGGL(k1a_convs_partial, dim3(2048), dim3(256), 0, stream,
                           bev, wp, pacc);
        hipLaunchKernelGGL(k1b_reduce, dim3(BB*HH), dim3(256), 0, stream,
                           pacc, offb, wtb, oa);
    } else {
        hipLaunchKernelGGL(k1_convs, dim3(BB*HH), dim3(256), 0, stream,
                           bev, wp, offb, wtb, oa);
    }
    if (big) {
        hipLaunchKernelGGL(k2_sample_proj_t, dim3(BB*256), dim3(512), 0, stream,
                           bevt, oa, wtT, out);
    } else {
        hipLaunchKernelGGL(k2_sample_proj, dim3(BB*256), dim3(512), 0, stream,
                           bev, oa, wtT, out);
    }
    hipLaunchKernelGGL(k3_partial, dim3(512), dim3(256), 0, stream,
                       out, part);
    hipLaunchKernelGGL(k3_finalize, dim3(1), dim3(128), 0, stream,
                       part, gamma, beta, stats);
    hipLaunchKernelGGL(k4_bn_gelu, dim3((BB*DD*HWC)/1024), dim3(256), 0, stream,
                       out, stats);
}

// Round 7
// 256.797 us; speedup vs baseline: 7.9969x; 1.1613x over previous
//
#include <hip/hip_runtime.h>
#include <math.h>

#define BB 2
#define DD 128
#define HH 256
#define WW 256
#define KK 4
#define HWC (HH*WW)
#define SROW2 320   // d-slice stride in S (fused fallback kernels)

typedef unsigned int u32;
typedef unsigned short ushort;
typedef __attribute__((ext_vector_type(8))) short bf16x8;
typedef __attribute__((ext_vector_type(4))) float f32x4;

// ws float layout
#define OA_OFF    0
#define WTT_OFF   1572864
#define WP_OFF    1589248
#define STATS_OFF 1603072
#define PART_OFF  1603392
#define BEVT_OFF  1605440
#define PACC_OFF  18382656
// AGG aliases PACC region (k1b consumes pacc before k2a writes agg)
#define AGG_OFF   PACC_OFF
#define WBF_OFF   26771264   // PACC_OFF + 8388608 (agg bf16 = 16.78M ushort)
#define WS_NEED_BEVT  ((size_t)PACC_OFF * 4)
#define WS_NEED_FULL  ((size_t)(PACC_OFF + 6291456) * 4)
#define WS_NEED_FULL2 ((size_t)(WBF_OFF + 8192) * 4)

__device__ __forceinline__ u32 f2bf(float x) {
    u32 u = __builtin_bit_cast(u32, x);
    return (u + 0x7fffu + ((u >> 16) & 1u)) >> 16;
}
__device__ __forceinline__ u32 pkbf(float a, float b) {
    return f2bf(a) | (f2bf(b) << 16);
}

// ---------------- Kernel 0: weight prep ----------------
__global__ __launch_bounds__(256) void k0_prep(
    const float* __restrict__ projw, const float* __restrict__ offw,
    const float* __restrict__ wtw, float* __restrict__ wtT, float* __restrict__ wp)
{
    int idx = blockIdx.x * 256 + threadIdx.x;
    if (idx < 16384) {
        int d = idx >> 7, o = idx & 127;
        wtT[d * 128 + o] = projw[o * 128 + d];
    }
    if (idx < 13824) {
        int c = idx / 108; int r = idx % 108; int o = r / 9; int t = r % 9;
        wp[idx] = (o < 8) ? offw[(o*128 + c)*9 + t] : wtw[((o-8)*128 + c)*9 + t];
    }
}

// ---------------- Kernel 0b: proj weights -> bf16 [o][d] (A-operand layout) ----------------
__global__ __launch_bounds__(256) void k0b_wbf(
    const float* __restrict__ projw, ushort* __restrict__ wbf)
{
    int idx = blockIdx.x * 256 + threadIdx.x;
    if (idx < 16384) wbf[idx] = (ushort)f2bf(projw[idx]);
}

// ---------------- Kernel T: NCHW -> NHWC transpose (bevt[b][y][x][d]) ----------------
__global__ __launch_bounds__(256) void k2t_transpose(
    const float* __restrict__ bev, float* __restrict__ bevt)
{
    __shared__ float T[64 * 128];   // 32 KB, swizzled
    int tid = threadIdx.x;
    int bidx = blockIdx.x;
    int b = bidx >> 10;
    int rem = bidx & 1023;
    int yrow = rem >> 2;
    int x0 = (rem & 3) << 6;

    const float* src = bev + ((size_t)b * DD) * HWC + (size_t)yrow * WW + x0;
    #pragma unroll 4
    for (int k = 0; k < 32; k++) {
        int flat = k * 256 + tid;
        int d = flat >> 6, xl = flat & 63;
        float v = src[(size_t)d * HWC + xl];
        T[xl * 128 + (((d >> 2) ^ (xl & 31)) << 2) + (d & 3)] = v;
    }
    __syncthreads();
    float* dst = bevt + (((size_t)b * HH + yrow) * WW + x0) * 128;
    #pragma unroll 4
    for (int k = 0; k < 8; k++) {
        int flat = k * 256 + tid;
        int d4 = flat & 31, xl = (flat >> 5) & 63;
        float4 v = *(const float4*)&T[xl * 128 + ((d4 ^ (xl & 31)) << 2)];
        *(float4*)(dst + (size_t)xl * 128 + (d4 << 2)) = v;
    }
}

// ---------------- Kernel 1a: partial 3x3 convs over a 32-channel chunk ----------------
__global__ __launch_bounds__(256) void k1a_convs_partial(
    const float* __restrict__ bev, const float* __restrict__ wp,
    float* __restrict__ pacc)
{
    __shared__ float rows[2][3][260];
    int tid = threadIdx.x;
    int bidx = blockIdx.x;
    int chunk = bidx >> 9;          // 0..3
    int b = (bidx >> 8) & 1;
    int i = bidx & 255;
    int c0 = chunk * 32;
    const float* bb = bev + (size_t)b * DD * HWC;

    if (tid < 12) { int bf = tid / 6, r = tid % 6; rows[bf][r >> 1][(r & 1) ? 257 : 0] = 0.f; }

    int yy[3]; bool yok[3];
    #pragma unroll
    for (int l = 0; l < 3; l++) { yy[l] = i + l - 1; yok[l] = ((unsigned)yy[l] < HH); }

    #pragma unroll
    for (int l = 0; l < 3; l++)
        rows[0][l][1 + tid] = yok[l] ? bb[(size_t)c0 * HWC + yy[l] * WW + tid] : 0.f;
    __syncthreads();

    float acc[12];
    #pragma unroll
    for (int o = 0; o < 12; o++) acc[o] = 0.f;

    for (int cc = 0; cc < 32; cc++) {
        int cb = cc & 1, nb = cb ^ 1;
        float rv[3];
        if (cc < 31) {
            const float* pln = bb + (size_t)(c0 + cc + 1) * HWC;
            #pragma unroll
            for (int l = 0; l < 3; l++)
                rv[l] = yok[l] ? pln[yy[l] * WW + tid] : 0.f;
        }
        float v[9];
        #pragma unroll
        for (int dy = 0; dy < 3; dy++)
            #pragma unroll
            for (int dx = 0; dx < 3; dx++)
                v[dy*3 + dx] = rows[cb][dy][tid + dx];
        const float* wc = wp + (c0 + cc) * 108;
        #pragma unroll
        for (int o = 0; o < 12; o++) {
            float s = acc[o];
            #pragma unroll
            for (int t = 0; t < 9; t++) s = fmaf(wc[o*9 + t], v[t], s);
            acc[o] = s;
        }
        if (cc < 31) {
            #pragma unroll
            for (int l = 0; l < 3; l++) rows[nb][l][1 + tid] = rv[l];
        }
        __syncthreads();
    }

    size_t basep = (size_t)(chunk * 2 + b) * 12 * HWC + (size_t)i * WW + tid;
    #pragma unroll
    for (int o = 0; o < 12; o++) pacc[basep + (size_t)o * HWC] = acc[o];
}

// ---------------- Kernel 1b: reduce 4 chunk partials + bias + softmax ----------------
__global__ __launch_bounds__(256) void k1b_reduce(
    const float* __restrict__ pacc, const float* __restrict__ offb,
    const float* __restrict__ wtb, float* __restrict__ oa)
{
    int p = blockIdx.x;
    int b = p >> 8; int i = p & 255; int tid = threadIdx.x;
    size_t pbase = (size_t)i * WW + tid;

    float acc[12];
    #pragma unroll
    for (int o = 0; o < 12; o++) {
        float s = 0.f;
        #pragma unroll
        for (int ch = 0; ch < 4; ch++)
            s += pacc[(size_t)(ch * 2 + b) * 12 * HWC + (size_t)o * HWC + pbase];
        acc[o] = s;
    }

    float outv[12];
    #pragma unroll
    for (int o = 0; o < 8; o++) outv[o] = acc[o] + offb[o];
    float l4[4];
    #pragma unroll
    for (int k = 0; k < 4; k++) l4[k] = acc[8+k] + wtb[k];
    float m = fmaxf(fmaxf(l4[0], l4[1]), fmaxf(l4[2], l4[3]));
    float e[4]; float se = 0.f;
    #pragma unroll
    for (int k = 0; k < 4; k++) { e[k] = expf(l4[k] - m); se += e[k]; }
    float inv = 1.f / se;
    #pragma unroll
    for (int k = 0; k < 4; k++) outv[8+k] = e[k] * inv;

    size_t basep = (size_t)b * 12 * HWC + pbase;
    #pragma unroll
    for (int o = 0; o < 12; o++) oa[basep + (size_t)o * HWC] = outv[o];
}

// ---------------- Kernel 1 (fallback): full 128-channel conv ----------------
__global__ __launch_bounds__(256) void k1_convs(
    const float* __restrict__ bev, const float* __restrict__ wp,
    const float* __restrict__ offb, const float* __restrict__ wtb,
    float* __restrict__ oa)
{
    __shared__ float rows[2][3][260];
    int tid = threadIdx.x;
    int p = blockIdx.x;
    int b = p / HH; int i = p % HH; int j = tid;
    const float* bb = bev + (size_t)b * DD * HWC;

    if (tid < 12) { int bf = tid / 6, r = tid % 6; rows[bf][r >> 1][(r & 1) ? 257 : 0] = 0.f; }
    #pragma unroll
    for (int l = 0; l < 3; l++) {
        int yy = i + l - 1;
        rows[0][l][1 + tid] = ((unsigned)yy < HH) ? bb[yy * WW + tid] : 0.f;
    }
    __syncthreads();

    float acc[12];
    #pragma unroll
    for (int o = 0; o < 12; o++) acc[o] = 0.f;

    for (int c = 0; c < 128; c++) {
        int cb = c & 1, nb = cb ^ 1;
        float rv[3];
        if (c < 127) {
            const float* pln = bb + (size_t)(c + 1) * HWC;
            #pragma unroll
            for (int l = 0; l < 3; l++) {
                int yy = i + l - 1;
                rv[l] = ((unsigned)yy < HH) ? pln[yy * WW + tid] : 0.f;
            }
        }
        float v[9];
        #pragma unroll
        for (int dy = 0; dy < 3; dy++)
            #pragma unroll
            for (int dx = 0; dx < 3; dx++)
                v[dy*3 + dx] = rows[cb][dy][tid + dx];
        const float* wc = wp + c * 108;
        #pragma unroll
        for (int o = 0; o < 12; o++) {
            float s = acc[o];
            #pragma unroll
            for (int t = 0; t < 9; t++) s = fmaf(wc[o*9 + t], v[t], s);
            acc[o] = s;
        }
        if (c < 127) {
            #pragma unroll
            for (int l = 0; l < 3; l++) rows[nb][l][1 + tid] = rv[l];
        }
        __syncthreads();
    }

    float outv[12];
    #pragma unroll
    for (int o = 0; o < 8; o++) outv[o] = acc[o] + offb[o];
    float l4[4];
    #pragma unroll
    for (int k = 0; k < 4; k++) l4[k] = acc[8+k] + wtb[k];
    float m = fmaxf(fmaxf(l4[0], l4[1]), fmaxf(l4[2], l4[3]));
    float e[4]; float se = 0.f;
    #pragma unroll
    for (int k = 0; k < 4; k++) { e[k] = expf(l4[k] - m); se += e[k]; }
    float inv = 1.f / se;
    #pragma unroll
    for (int k = 0; k < 4; k++) outv[8+k] = e[k] * inv;

    size_t basep = (size_t)b * 12 * HWC + (size_t)i * WW + j;
    #pragma unroll
    for (int o = 0; o < 12; o++) oa[basep + (size_t)o * HWC] = outv[o];
}

// ---------------- Kernel 2a: deformable sample + K-aggregate -> agg[pix][128] bf16 ----------------
// Barrier-free, LDS-free. Block 256 thr = 128 pixels (16p x 8q tile, p-fast) x 2 d-halves.
// Per (pixel,half) per 16-d chunk: 16 taps x 2 dwordx4 from NHWC bevt (pair covers the
// full 64B chunk-line), weighted-accumulate 8 floats, pack bf16, one 16B store.
__global__ __launch_bounds__(256) void k2a_sample(
    const float* __restrict__ bevt, const float* __restrict__ oa,
    ushort* __restrict__ aggb)
{
    int tid = threadIdx.x;
    int bidx = blockIdx.x;
    int b = bidx >> 9;
    int rem = bidx & 511;
    int pt = rem >> 5;           // 0..15
    int qt = rem & 31;           // 0..31
    int half = tid & 1;
    int pp = (tid >> 1) & 15;
    int qq = tid >> 5;           // 0..7
    int p = pt * 16 + pp;
    int q = qt * 8 + qq;

    // offsets / attention for this pixel (transpose quirk: x <- p+dx, row <- q+dy)
    const float* ob = oa + (size_t)b * 12 * HWC + (size_t)p * WW + q;
    unsigned pa[8]; float cw[16];
    #pragma unroll
    for (int k = 0; k < 4; k++) {
        float dx = ob[(size_t)(2*k)   * HWC];
        float dy = ob[(size_t)(2*k+1) * HWC];
        float a  = ob[(size_t)(8+k)   * HWC];
        float x  = fminf(fmaxf((float)p + dx, 0.f), (float)(WW-1));
        float yv = fminf(fmaxf((float)q + dy, 0.f), (float)(HH-1));
        float x0f = floorf(x); float y0f = floorf(yv);
        int x0 = (int)x0f; int y0 = (int)y0f;
        int x1 = min(x0 + 1, WW - 1); int y1 = min(y0 + 1, HH - 1);
        float wx = x - x0f; float wy = yv - y0f;
        pa[k*2+0] = (unsigned)(y0*WW + x0) | ((unsigned)(y0*WW + x1) << 16);
        pa[k*2+1] = (unsigned)(y1*WW + x0) | ((unsigned)(y1*WW + x1) << 16);
        cw[k*4+0] = a * (1.f - wx) * (1.f - wy);
        cw[k*4+1] = a * wx * (1.f - wy);
        cw[k*4+2] = a * (1.f - wx) * wy;
        cw[k*4+3] = a * wx * wy;
    }

    const float* bt = bevt + (size_t)b * HWC * 128 + half * 8;
    ushort* outp = aggb + ((size_t)b * HWC + (size_t)p * WW + q) * 128 + half * 8;

    #pragma unroll 2
    for (int c = 0; c < 8; c++) {
        float4 s0 = make_float4(0,0,0,0), s1 = make_float4(0,0,0,0);
        #pragma unroll
        for (int t = 0; t < 16; t++) {
            unsigned a01 = pa[t >> 1];
            unsigned pix = (t & 1) ? (a01 >> 16) : (a01 & 0xffffu);
            const float4* tp = (const float4*)(bt + ((size_t)pix << 7) + c * 16);
            float4 va = tp[0], vb = tp[1];
            float w = cw[t];
            s0.x = fmaf(w, va.x, s0.x); s0.y = fmaf(w, va.y, s0.y);
            s0.z = fmaf(w, va.z, s0.z); s0.w = fmaf(w, va.w, s0.w);
            s1.x = fmaf(w, vb.x, s1.x); s1.y = fmaf(w, vb.y, s1.y);
            s1.z = fmaf(w, vb.z, s1.z); s1.w = fmaf(w, vb.w, s1.w);
        }
        uint4 pk;
        pk.x = pkbf(s0.x, s0.y); pk.y = pkbf(s0.z, s0.w);
        pk.z = pkbf(s1.x, s1.y); pk.w = pkbf(s1.z, s1.w);
        *(uint4*)(outp + c * 16) = pk;
    }
}

// ---------------- Kernel 2b: 1x1 proj as bf16 MFMA GEMM ----------------
// y[b][o][pix] = sum_d W[o][d] * agg[pix][d].  mfma_f32_16x16x32_bf16:
// A lane: m=lane&15, k=(lane>>4)*8+i ; B lane: n=lane&15, same k ;
// C/D: col(n)=lane&15, row(m)=(lane>>4)*4+reg  [guide S3, m89-verified].
// Block 256 thr = 4 waves; wave w -> o in [32w,32w+32); block covers 64 pixels.
__global__ __launch_bounds__(256) void k2b_proj(
    const ushort* __restrict__ aggb, const ushort* __restrict__ wbf,
    float* __restrict__ y)
{
    int tid = threadIdx.x;
    int wv = tid >> 6;
    int l = tid & 63;
    int lm = l & 15, lk = l >> 4;
    int bidx = blockIdx.x;
    int b = bidx >> 10;
    int pix0 = (bidx & 1023) << 6;
    int o0 = wv << 5;

    // A fragments: 2 o-tiles x 4 k-slices, reused across all pixel tiles
    bf16x8 a[2][4];
    const ushort* wbase = wbf + (size_t)(o0 + lm) * 128 + lk * 8;
    #pragma unroll
    for (int ot = 0; ot < 2; ot++)
        #pragma unroll
        for (int kk = 0; kk < 4; kk++)
            a[ot][kk] = *(const bf16x8*)(wbase + ot * 16 * 128 + kk * 32);

    f32x4 acc[2][4];
    #pragma unroll
    for (int ot = 0; ot < 2; ot++)
        #pragma unroll
        for (int nt = 0; nt < 4; nt++)
            acc[ot][nt] = (f32x4)(0.f);

    const ushort* bbase = aggb + ((size_t)b * HWC + pix0 + lm) * 128 + lk * 8;
    #pragma unroll
    for (int nt = 0; nt < 4; nt++) {
        bf16x8 bfr[4];
        #pragma unroll
        for (int kk = 0; kk < 4; kk++)
            bfr[kk] = *(const bf16x8*)(bbase + nt * 16 * 128 + kk * 32);
        #pragma unroll
        for (int ot = 0; ot < 2; ot++)
            #pragma unroll
            for (int kk = 0; kk < 4; kk++)
                acc[ot][nt] = __builtin_amdgcn_mfma_f32_16x16x32_bf16(
                    a[ot][kk], bfr[kk], acc[ot][nt], 0, 0, 0);
    }

    #pragma unroll
    for (int ot = 0; ot < 2; ot++)
        #pragma unroll
        for (int nt = 0; nt < 4; nt++)
            #pragma unroll
            for (int r = 0; r < 4; r++)
                y[((size_t)b * DD + o0 + ot * 16 + lk * 4 + r) * HWC + pix0 + nt * 16 + lm]
                    = acc[ot][nt][r];
}

// ---------------- Kernel 2 fused fallback (NHWC, round-6 version) ----------------
__global__ __launch_bounds__(512, 2) void k2_sample_proj_t(
    const float* __restrict__ bevt, const float* __restrict__ oa,
    const float* __restrict__ wt, float* __restrict__ y)
{
    __shared__ float S[2][16 * SROW2];   // 40 KB

    int tid = threadIdx.x;
    int bidx = blockIdx.x;
    int b  = bidx >> 8;
    int p0 = ((bidx >> 4) & 15) * 16;
    int q0 = (bidx & 15) * 16;

    int gpix = tid >> 1;
    int gp = gpix & 15;
    int gq = gpix >> 4;
    int dgrp = tid & 1;
    int swr = gp * 20 + gq;

    int wv = tid >> 6;
    int wvu = __builtin_amdgcn_readfirstlane(wv);
    int lane = tid & 63;
    int lp = lane >> 2;
    int q4 = (lane & 3) << 2;
    int soff = lp * 20 + q4;

    const float* ob = oa + (size_t)b * 12 * HWC + (size_t)(p0 + gp) * WW + (q0 + gq);
    unsigned pa[8]; float cw[16];
    #pragma unroll
    for (int k = 0; k < 4; k++) {
        float dx = ob[(size_t)(2*k)   * HWC];
        float dy = ob[(size_t)(2*k+1) * HWC];
        float a  = ob[(size_t)(8+k)   * HWC];
        float x  = fminf(fmaxf((float)(p0 + gp) + dx, 0.f), (float)(WW-1));
        float yv = fminf(fmaxf((float)(q0 + gq) + dy, 0.f), (float)(HH-1));
        float x0f = floorf(x); float y0f = floorf(yv);
        int x0 = (int)x0f; int y0 = (int)y0f;
        int x1 = min(x0 + 1, WW - 1); int y1 = min(y0 + 1, HH - 1);
        float wx = x - x0f; float wy = yv - y0f;
        pa[k*2+0] = (unsigned)(y0*WW + x0) | ((unsigned)(y0*WW + x1) << 16);
        pa[k*2+1] = (unsigned)(y1*WW + x0) | ((unsigned)(y1*WW + x1) << 16);
        cw[k*4+0] = a * (1.f - wx) * (1.f - wy);
        cw[k*4+1] = a * wx * (1.f - wy);
        cw[k*4+2] = a * (1.f - wx) * wy;
        cw[k*4+3] = a * wx * wy;
    }

    const float* bt = bevt + (size_t)b * HWC * 128 + dgrp * 8;

    float acc[64];
    #pragma unroll
    for (int t = 0; t < 64; t++) acc[t] = 0.f;

    {
        float4 s0 = make_float4(0,0,0,0), s1 = make_float4(0,0,0,0);
        #pragma unroll
        for (int t = 0; t < 16; t++) {
            unsigned pix = (t & 1) ? (pa[t >> 1] >> 16) : (pa[t >> 1] & 0xffffu);
            const float4* tp = (const float4*)(bt + ((size_t)pix << 7));
            float4 va = tp[0], vb = tp[1];
            float c = cw[t];
            s0.x = fmaf(c, va.x, s0.x); s0.y = fmaf(c, va.y, s0.y);
            s0.z = fmaf(c, va.z, s0.z); s0.w = fmaf(c, va.w, s0.w);
            s1.x = fmaf(c, vb.x, s1.x); s1.y = fmaf(c, vb.y, s1.y);
            s1.z = fmaf(c, vb.z, s1.z); s1.w = fmaf(c, vb.w, s1.w);
        }
        int r = dgrp * 8;
        S[0][(r+0)*SROW2 + swr] = s0.x; S[0][(r+1)*SROW2 + swr] = s0.y;
        S[0][(r+2)*SROW2 + swr] = s0.z; S[0][(r+3)*SROW2 + swr] = s0.w;
        S[0][(r+4)*SROW2 + swr] = s1.x; S[0][(r+5)*SROW2 + swr] = s1.y;
        S[0][(r+6)*SROW2 + swr] = s1.z; S[0][(r+7)*SROW2 + swr] = s1.w;
    }
    __syncthreads();

    for (int c = 0; c < 8; c++) {
        int cur = c & 1;
        const float* Sc = &S[cur][0];
        float* Sn = &S[cur ^ 1][0];
        int d0 = c * 16;
        int dn = d0 + 16;
        bool more = (c < 7);

        float4 g0 = make_float4(0,0,0,0), g1 = make_float4(0,0,0,0);
        float4 pf0, pf1;
        if (more) {
            unsigned pix = pa[0] & 0xffffu;
            const float4* tp = (const float4*)(bt + ((size_t)pix << 7) + dn);
            pf0 = tp[0]; pf1 = tp[1];
        }

        #pragma unroll
        for (int dl = 0; dl < 16; dl++) {
            float4 cur0 = pf0, cur1 = pf1;
            if (more && dl < 15) {
                int t = dl + 1;
                unsigned pix = (t & 1) ? (pa[t >> 1] >> 16) : (pa[t >> 1] & 0xffffu);
                const float4* tp = (const float4*)(bt + ((size_t)pix << 7) + dn);
                pf0 = tp[0]; pf1 = tp[1];
            }

            float4 sv = *(const float4*)(Sc + dl * SROW2 + soff);
            const float4* wq = (const float4*)(wt + (size_t)(d0 + dl) * 128 + wvu * 16);
            #pragma unroll
            for (int oi4 = 0; oi4 < 4; oi4++) {
                float4 w4 = wq[oi4];
                int ob4 = oi4 * 16;
                acc[ob4+ 0] = fmaf(w4.x, sv.x, acc[ob4+ 0]);
                acc[ob4+ 1] = fmaf(w4.x, sv.y, acc[ob4+ 1]);
                acc[ob4+ 2] = fmaf(w4.x, sv.z, acc[ob4+ 2]);
                acc[ob4+ 3] = fmaf(w4.x, sv.w, acc[ob4+ 3]);
                acc[ob4+ 4] = fmaf(w4.y, sv.x, acc[ob4+ 4]);
                acc[ob4+ 5] = fmaf(w4.y, sv.y, acc[ob4+ 5]);
                acc[ob4+ 6] = fmaf(w4.y, sv.z, acc[ob4+ 6]);
                acc[ob4+ 7] = fmaf(w4.y, sv.w, acc[ob4+ 7]);
                acc[ob4+ 8] = fmaf(w4.z, sv.x, acc[ob4+ 8]);
                acc[ob4+ 9] = fmaf(w4.z, sv.y, acc[ob4+ 9]);
                acc[ob4+10] = fmaf(w4.z, sv.z, acc[ob4+10]);
                acc[ob4+11] = fmaf(w4.z, sv.w, acc[ob4+11]);
                acc[ob4+12] = fmaf(w4.w, sv.x, acc[ob4+12]);
                acc[ob4+13] = fmaf(w4.w, sv.y, acc[ob4+13]);
                acc[ob4+14] = fmaf(w4.w, sv.z, acc[ob4+14]);
                acc[ob4+15] = fmaf(w4.w, sv.w, acc[ob4+15]);
            }

            if (more) {
                float cwt = cw[dl];
                g0.x = fmaf(cwt, cur0.x, g0.x); g0.y = fmaf(cwt, cur0.y, g0.y);
                g0.z = fmaf(cwt, cur0.z, g0.z); g0.w = fmaf(cwt, cur0.w, g0.w);
                g1.x = fmaf(cwt, cur1.x, g1.x); g1.y = fmaf(cwt, cur1.y, g1.y);
                g1.z = fmaf(cwt, cur1.z, g1.z); g1.w = fmaf(cwt, cur1.w, g1.w);
            }
        }

        if (more) {
            int r = dgrp * 8;
            Sn[(r+0)*SROW2 + swr] = g0.x; Sn[(r+1)*SROW2 + swr] = g0.y;
            Sn[(r+2)*SROW2 + swr] = g0.z; Sn[(r+3)*SROW2 + swr] = g0.w;
            Sn[(r+4)*SROW2 + swr] = g1.x; Sn[(r+5)*SROW2 + swr] = g1.y;
            Sn[(r+6)*SROW2 + swr] = g1.z; Sn[(r+7)*SROW2 + swr] = g1.w;
        }
        __syncthreads();
    }

    size_t base = (size_t)b * DD * HWC + (size_t)(p0 + lp) * WW + (q0 + q4);
    #pragma unroll
    for (int oi = 0; oi < 16; oi++) {
        int o = wv * 16 + oi;
        float4 v = make_float4(acc[oi*4+0], acc[oi*4+1], acc[oi*4+2], acc[oi*4+3]);
        *(float4*)(y + base + (size_t)o * HWC) = v;
    }
}

// ---------------- Kernel 2 fallback (NCHW) ----------------
__global__ __launch_bounds__(512, 2) void k2_sample_proj(
    const float* __restrict__ bev, const float* __restrict__ oa,
    const float* __restrict__ wt, float* __restrict__ y)
{
    __shared__ float S[2][16 * SROW2];
    int tid = threadIdx.x;
    int bidx = blockIdx.x;
    int b  = bidx >> 8;
    int p0 = ((bidx >> 4) & 15) * 16;
    int q0 = (bidx & 15) * 16;
    int pix = tid & 255;
    int gq = pix >> 4;
    int gp = pix & 15;
    int dgrp = tid >> 8;
    int swr = gp * 20 + gq;
    int wv = tid >> 6;
    int wvu = __builtin_amdgcn_readfirstlane(wv);
    int lane = tid & 63;
    int lp = lane >> 2;
    int q4 = (lane & 3) << 2;
    int soff = lp * 20 + q4;

    const float* ob = oa + (size_t)b * 12 * HWC + (size_t)(p0 + gp) * WW + (q0 + gq);
    unsigned pa[8]; float cw[16];
    #pragma unroll
    for (int k = 0; k < 4; k++) {
        float dx = ob[(size_t)(2*k)   * HWC];
        float dy = ob[(size_t)(2*k+1) * HWC];
        float a  = ob[(size_t)(8+k)   * HWC];
        float x  = fminf(fmaxf((float)(p0 + gp) + dx, 0.f), (float)(WW-1));
        float yv = fminf(fmaxf((float)(q0 + gq) + dy, 0.f), (float)(HH-1));
        float x0f = floorf(x); float y0f = floorf(yv);
        int x0 = (int)x0f; int y0 = (int)y0f;
        int x1 = min(x0 + 1, WW - 1); int y1 = min(y0 + 1, HH - 1);
        float wx = x - x0f; float wy = yv - y0f;
        pa[k*2+0] = (unsigned)(y0*WW + x0) | ((unsigned)(y0*WW + x1) << 16);
        pa[k*2+1] = (unsigned)(y1*WW + x0) | ((unsigned)(y1*WW + x1) << 16);
        cw[k*4+0] = a * (1.f - wx) * (1.f - wy);
        cw[k*4+1] = a * wx * (1.f - wy);
        cw[k*4+2] = a * (1.f - wx) * wy;
        cw[k*4+3] = a * wx * wy;
    }
    const float* bb = bev + (size_t)b * DD * HWC;
    float acc[64];
    #pragma unroll
    for (int t = 0; t < 64; t++) acc[t] = 0.f;
    #pragma unroll
    for (int dd = 0; dd < 8; dd++) {
        const float* pl = bb + (size_t)(dgrp*8 + dd) * HWC;
        float s = 0.f;
        #pragma unroll
        for (int t = 0; t < 8; t++) {
            unsigned a01 = pa[t];
            s = fmaf(cw[2*t],   pl[a01 & 0xffffu], s);
            s = fmaf(cw[2*t+1], pl[a01 >> 16], s);
        }
        S[0][(dgrp*8 + dd) * SROW2 + swr] = s;
    }
    __syncthreads();
    for (int c = 0; c < 8; c++) {
        int cur = c & 1;
        const float* Sc = &S[cur][0];
        float* Sn = &S[cur ^ 1][0];
        int d0 = c * 16;
        int d0n = d0 + 16;
        bool more = (c < 7);
        #pragma unroll
        for (int dl = 0; dl < 16; dl++) {
            if (dl < 8) {
                if (more) {
                    const float* pl = bb + (size_t)(d0n + dgrp*8 + dl) * HWC;
                    float s = 0.f;
                    #pragma unroll
                    for (int t = 0; t < 8; t++) {
                        unsigned a01 = pa[t];
                        s = fmaf(cw[2*t],   pl[a01 & 0xffffu], s);
                        s = fmaf(cw[2*t+1], pl[a01 >> 16], s);
                    }
                    Sn[(dgrp*8 + dl) * SROW2 + swr] = s;
                }
            }
            float4 sv = *(const float4*)(Sc + dl * SROW2 + soff);
            const float4* wq = (const float4*)(wt + (size_t)(d0 + dl) * 128 + wvu * 16);
            #pragma unroll
            for (int oi4 = 0; oi4 < 4; oi4++) {
                float4 w4 = wq[oi4];
                int ob4 = oi4 * 16;
                acc[ob4+ 0] = fmaf(w4.x, sv.x, acc[ob4+ 0]);
                acc[ob4+ 1] = fmaf(w4.x, sv.y, acc[ob4+ 1]);
                acc[ob4+ 2] = fmaf(w4.x, sv.z, acc[ob4+ 2]);
                acc[ob4+ 3] = fmaf(w4.x, sv.w, acc[ob4+ 3]);
                acc[ob4+ 4] = fmaf(w4.y, sv.x, acc[ob4+ 4]);
                acc[ob4+ 5] = fmaf(w4.y, sv.y, acc[ob4+ 5]);
                acc[ob4+ 6] = fmaf(w4.y, sv.z, acc[ob4+ 6]);
                acc[ob4+ 7] = fmaf(w4.y, sv.w, acc[ob4+ 7]);
                acc[ob4+ 8] = fmaf(w4.z, sv.x, acc[ob4+ 8]);
                acc[ob4+ 9] = fmaf(w4.z, sv.y, acc[ob4+ 9]);
                acc[ob4+10] = fmaf(w4.z, sv.z, acc[ob4+10]);
                acc[ob4+11] = fmaf(w4.z, sv.w, acc[ob4+11]);
                acc[ob4+12] = fmaf(w4.w, sv.x, acc[ob4+12]);
                acc[ob4+13] = fmaf(w4.w, sv.y, acc[ob4+13]);
                acc[ob4+14] = fmaf(w4.w, sv.z, acc[ob4+14]);
                acc[ob4+15] = fmaf(w4.w, sv.w, acc[ob4+15]);
            }
        }
        __syncthreads();
    }
    size_t base = (size_t)b * DD * HWC + (size_t)(p0 + lp) * WW + (q0 + q4);
    #pragma unroll
    for (int oi = 0; oi < 16; oi++) {
        int o = wv * 16 + oi;
        float4 v = make_float4(acc[oi*4+0], acc[oi*4+1], acc[oi*4+2], acc[oi*4+3]);
        *(float4*)(y + base + (size_t)o * HWC) = v;
    }
}

// ---------------- Kernel 3a: per-channel partial sums ----------------
__global__ __launch_bounds__(256) void k3_partial(
    const float* __restrict__ y, double* __restrict__ part)
{
    int blk = blockIdx.x;
    int o = blk >> 2; int sub = blk & 3; int b = sub >> 1; int half = sub & 1;
    const float4* pl = (const float4*)(y + ((size_t)b * DD + o) * HWC + half * (HWC/2));
    int tid = threadIdx.x;
    double s = 0.0, s2 = 0.0;
    for (int idx = tid; idx < HWC/8; idx += 256) {
        float4 v = pl[idx];
        s  += (double)v.x + (double)v.y + (double)v.z + (double)v.w;
        s2 += (double)v.x*v.x + (double)v.y*v.y + (double)v.z*v.z + (double)v.w*v.w;
    }
    __shared__ double ls[256], ls2[256];
    ls[tid] = s; ls2[tid] = s2;
    __syncthreads();
    for (int off = 128; off > 0; off >>= 1) {
        if (tid < off) { ls[tid] += ls[tid+off]; ls2[tid] += ls2[tid+off]; }
        __syncthreads();
    }
    if (tid == 0) { part[blk*2] = ls[0]; part[blk*2+1] = ls2[0]; }
}

// ---------------- Kernel 3b: finalize BN scale/shift ----------------
__global__ __launch_bounds__(128) void k3_finalize(
    const double* __restrict__ part, const float* __restrict__ gamma,
    const float* __restrict__ beta, float* __restrict__ stats)
{
    int o = threadIdx.x;
    double s = 0.0, s2 = 0.0;
    #pragma unroll
    for (int j = 0; j < 4; j++) { s += part[(o*4+j)*2]; s2 += part[(o*4+j)*2+1]; }
    double N = (double)(BB * HWC);
    double mean = s / N;
    double var = s2 / N - mean * mean;
    double invs = 1.0 / sqrt(var + 1e-5);
    double g = (double)gamma[o];
    stats[o*2]   = (float)(g * invs);
    stats[o*2+1] = (float)((double)beta[o] - mean * g * invs);
}

// ---------------- Kernel 4: BN + exact GELU ----------------
__global__ __launch_bounds__(256) void k4_bn_gelu(
    float* __restrict__ y, const float* __restrict__ stats)
{
    size_t idx4 = (size_t)blockIdx.x * 256 + threadIdx.x;
    float4* p = (float4*)y;
    float4 v = p[idx4];
    int o = (int)((idx4 * 4) / HWC) % DD;
    float sc = stats[o*2], sh = stats[o*2+1];
    const float inv_sqrt2 = 0.70710678118654752f;
    float g0 = fmaf(v.x, sc, sh);
    float g1 = fmaf(v.y, sc, sh);
    float g2 = fmaf(v.z, sc, sh);
    float g3 = fmaf(v.w, sc, sh);
    v.x = 0.5f * g0 * (1.f + erff(g0 * inv_sqrt2));
    v.y = 0.5f * g1 * (1.f + erff(g1 * inv_sqrt2));
    v.z = 0.5f * g2 * (1.f + erff(g2 * inv_sqrt2));
    v.w = 0.5f * g3 * (1.f + erff(g3 * inv_sqrt2));
    p[idx4] = v;
}

extern "C" void kernel_launch(void* const* d_in, const int* in_sizes, int n_in,
                              void* d_out, int out_size, void* d_ws, size_t ws_size,
                              hipStream_t stream) {
    const float* bev   = (const float*)d_in[0];
    const float* offw  = (const float*)d_in[1];
    const float* offb  = (const float*)d_in[2];
    const float* wtw   = (const float*)d_in[3];
    const float* wtb   = (const float*)d_in[4];
    const float* projw = (const float*)d_in[5];
    const float* gamma = (const float*)d_in[6];
    const float* beta  = (const float*)d_in[7];
    float* out = (float*)d_out;
    float* wsf = (float*)d_ws;

    float* oa    = wsf + OA_OFF;
    float* wtT   = wsf + WTT_OFF;
    float* wp    = wsf + WP_OFF;
    float* stats = wsf + STATS_OFF;
    double* part = (double*)(wsf + PART_OFF);
    float* bevt  = wsf + BEVT_OFF;
    float* pacc  = wsf + PACC_OFF;
    ushort* aggb = (ushort*)(wsf + AGG_OFF);
    ushort* wbf  = (ushort*)(wsf + WBF_OFF);

    bool full2 = ws_size >= WS_NEED_FULL2;
    bool full  = ws_size >= WS_NEED_FULL;
    bool big   = ws_size >= WS_NEED_BEVT;

    hipLaunchKernelGGL(k0_prep, dim3(64), dim3(256), 0, stream,
                       projw, offw, wtw, wtT, wp);
    if (full2) {
        hipLaunchKernelGGL(k0b_wbf, dim3(64), dim3(256), 0, stream, projw, wbf);
    }
    if (big) {
        hipLaunchKernelGGL(k2t_transpose, dim3(2048), dim3(256), 0, stream,
                           bev, bevt);
    }
    if (full) {
        hipLaunchKernelGGL(k1a_convs_partial, dim3(2048), dim3(256), 0, stream,
                           bev, wp, pacc);
        hipLaunchKernelGGL(k1b_reduce, dim3(BB*HH), dim3(256), 0, stream,
                           pacc, offb, wtb, oa);
    } else {
        hipLaunchKernelGGL(k1_convs, dim3(BB*HH), dim3(256), 0, stream,
                           bev, wp, offb, wtb, oa);
    }
    if (full2) {
        // agg overwrites the pacc region - k1b has already consumed it
        hipLaunchKernelGGL(k2a_sample, dim3(1024), dim3(256), 0, stream,
                           bevt, oa, aggb);
        hipLaunchKernelGGL(k2b_proj, dim3(2048), dim3(256), 0, stream,
                           aggb, wbf, out);
    } else if (big) {
        hipLaunchKernelGGL(k2_sample_proj_t, dim3(BB*256), dim3(512), 0, stream,
                           bevt, oa, wtT, out);
    } else {
        hipLaunchKernelGGL(k2_sample_proj, dim3(BB*256), dim3(512), 0, stream,
                           bev, oa, wtT, out);
    }
    hipLaunchKernelGGL(k3_partial, dim3(512), dim3(256), 0, stream,
                       out, part);
    hipLaunchKernelGGL(k3_finalize, dim3(1), dim3(128), 0, stream,
                       part, gamma, beta, stats);
    hipLaunchKernelGGL(k4_bn_gelu, dim3((BB*DD*HWC)/1024), dim3(256), 0, stream,
                       out, stats);
}

// Round 8
// 214.282 us; speedup vs baseline: 9.5835x; 1.1984x over previous
//
#include <hip/hip_runtime.h>
#include <math.h>

#define BB 2
#define DD 128
#define HH 256
#define WW 256
#define KK 4
#define HWC (HH*WW)
#define SROW2 320   // d-slice stride in S (fused fallback kernels)

typedef unsigned int u32;
typedef unsigned short ushort;
typedef __attribute__((ext_vector_type(8))) short bf16x8;
typedef __attribute__((ext_vector_type(4))) float f32x4;

// ws float layout
#define OA_OFF    0
#define WTT_OFF   1572864
#define WP_OFF    1589248
#define STATS_OFF 1603072
#define PART_OFF  1603392
#define BEVT_OFF  1605440
#define PACC_OFF  18382656
// AGG aliases PACC region (k1b consumes pacc before k2a writes agg)
#define AGG_OFF   PACC_OFF
#define WBF_OFF   26771264   // PACC_OFF + 8388608 (agg bf16 = 16.78M ushort)
// PART2 aliases BEVT region: k2b (which writes part2) runs strictly after
// k2a's last bevt read; next launch's k2t rewrites bevt before k2a reads it.
#define PART2_OFF BEVT_OFF
#define WS_NEED_BEVT  ((size_t)PACC_OFF * 4)
#define WS_NEED_FULL  ((size_t)(PACC_OFF + 6291456) * 4)
#define WS_NEED_FULL2 ((size_t)(WBF_OFF + 8192) * 4)

__device__ __forceinline__ u32 f2bf(float x) {
    u32 u = __builtin_bit_cast(u32, x);
    return (u + 0x7fffu + ((u >> 16) & 1u)) >> 16;
}
__device__ __forceinline__ u32 pkbf(float a, float b) {
    return f2bf(a) | (f2bf(b) << 16);
}

// ---------------- Kernel 0: weight prep ----------------
__global__ __launch_bounds__(256) void k0_prep(
    const float* __restrict__ projw, const float* __restrict__ offw,
    const float* __restrict__ wtw, float* __restrict__ wtT, float* __restrict__ wp)
{
    int idx = blockIdx.x * 256 + threadIdx.x;
    if (idx < 16384) {
        int d = idx >> 7, o = idx & 127;
        wtT[d * 128 + o] = projw[o * 128 + d];
    }
    if (idx < 13824) {
        int c = idx / 108; int r = idx % 108; int o = r / 9; int t = r % 9;
        wp[idx] = (o < 8) ? offw[(o*128 + c)*9 + t] : wtw[((o-8)*128 + c)*9 + t];
    }
}

// ---------------- Kernel 0b: proj weights -> bf16 [o][d] ----------------
__global__ __launch_bounds__(256) void k0b_wbf(
    const float* __restrict__ projw, ushort* __restrict__ wbf)
{
    int idx = blockIdx.x * 256 + threadIdx.x;
    if (idx < 16384) wbf[idx] = (ushort)f2bf(projw[idx]);
}

// ---------------- Kernel T: NCHW -> NHWC transpose (bevt[b][y][x][d]) ----------------
__global__ __launch_bounds__(256) void k2t_transpose(
    const float* __restrict__ bev, float* __restrict__ bevt)
{
    __shared__ float T[64 * 128];   // 32 KB, swizzled
    int tid = threadIdx.x;
    int bidx = blockIdx.x;
    int b = bidx >> 10;
    int rem = bidx & 1023;
    int yrow = rem >> 2;
    int x0 = (rem & 3) << 6;

    const float* src = bev + ((size_t)b * DD) * HWC + (size_t)yrow * WW + x0;
    #pragma unroll 4
    for (int k = 0; k < 32; k++) {
        int flat = k * 256 + tid;
        int d = flat >> 6, xl = flat & 63;
        float v = src[(size_t)d * HWC + xl];
        T[xl * 128 + (((d >> 2) ^ (xl & 31)) << 2) + (d & 3)] = v;
    }
    __syncthreads();
    float* dst = bevt + (((size_t)b * HH + yrow) * WW + x0) * 128;
    #pragma unroll 4
    for (int k = 0; k < 8; k++) {
        int flat = k * 256 + tid;
        int d4 = flat & 31, xl = (flat >> 5) & 63;
        float4 v = *(const float4*)&T[xl * 128 + ((d4 ^ (xl & 31)) << 2)];
        *(float4*)(dst + (size_t)xl * 128 + (d4 << 2)) = v;
    }
}

// ---------------- Kernel 1a: partial 3x3 convs over a 32-channel chunk ----------------
__global__ __launch_bounds__(256) void k1a_convs_partial(
    const float* __restrict__ bev, const float* __restrict__ wp,
    float* __restrict__ pacc)
{
    __shared__ float rows[2][3][260];
    int tid = threadIdx.x;
    int bidx = blockIdx.x;
    int chunk = bidx >> 9;          // 0..3
    int b = (bidx >> 8) & 1;
    int i = bidx & 255;
    int c0 = chunk * 32;
    const float* bb = bev + (size_t)b * DD * HWC;

    if (tid < 12) { int bf = tid / 6, r = tid % 6; rows[bf][r >> 1][(r & 1) ? 257 : 0] = 0.f; }

    int yy[3]; bool yok[3];
    #pragma unroll
    for (int l = 0; l < 3; l++) { yy[l] = i + l - 1; yok[l] = ((unsigned)yy[l] < HH); }

    #pragma unroll
    for (int l = 0; l < 3; l++)
        rows[0][l][1 + tid] = yok[l] ? bb[(size_t)c0 * HWC + yy[l] * WW + tid] : 0.f;
    __syncthreads();

    float acc[12];
    #pragma unroll
    for (int o = 0; o < 12; o++) acc[o] = 0.f;

    for (int cc = 0; cc < 32; cc++) {
        int cb = cc & 1, nb = cb ^ 1;
        float rv[3];
        if (cc < 31) {
            const float* pln = bb + (size_t)(c0 + cc + 1) * HWC;
            #pragma unroll
            for (int l = 0; l < 3; l++)
                rv[l] = yok[l] ? pln[yy[l] * WW + tid] : 0.f;
        }
        float v[9];
        #pragma unroll
        for (int dy = 0; dy < 3; dy++)
            #pragma unroll
            for (int dx = 0; dx < 3; dx++)
                v[dy*3 + dx] = rows[cb][dy][tid + dx];
        const float* wc = wp + (c0 + cc) * 108;
        #pragma unroll
        for (int o = 0; o < 12; o++) {
            float s = acc[o];
            #pragma unroll
            for (int t = 0; t < 9; t++) s = fmaf(wc[o*9 + t], v[t], s);
            acc[o] = s;
        }
        if (cc < 31) {
            #pragma unroll
            for (int l = 0; l < 3; l++) rows[nb][l][1 + tid] = rv[l];
        }
        __syncthreads();
    }

    size_t basep = (size_t)(chunk * 2 + b) * 12 * HWC + (size_t)i * WW + tid;
    #pragma unroll
    for (int o = 0; o < 12; o++) pacc[basep + (size_t)o * HWC] = acc[o];
}

// ---------------- Kernel 1b: reduce 4 chunk partials + bias + softmax ----------------
__global__ __launch_bounds__(256) void k1b_reduce(
    const float* __restrict__ pacc, const float* __restrict__ offb,
    const float* __restrict__ wtb, float* __restrict__ oa)
{
    int p = blockIdx.x;
    int b = p >> 8; int i = p & 255; int tid = threadIdx.x;
    size_t pbase = (size_t)i * WW + tid;

    float acc[12];
    #pragma unroll
    for (int o = 0; o < 12; o++) {
        float s = 0.f;
        #pragma unroll
        for (int ch = 0; ch < 4; ch++)
            s += pacc[(size_t)(ch * 2 + b) * 12 * HWC + (size_t)o * HWC + pbase];
        acc[o] = s;
    }

    float outv[12];
    #pragma unroll
    for (int o = 0; o < 8; o++) outv[o] = acc[o] + offb[o];
    float l4[4];
    #pragma unroll
    for (int k = 0; k < 4; k++) l4[k] = acc[8+k] + wtb[k];
    float m = fmaxf(fmaxf(l4[0], l4[1]), fmaxf(l4[2], l4[3]));
    float e[4]; float se = 0.f;
    #pragma unroll
    for (int k = 0; k < 4; k++) { e[k] = expf(l4[k] - m); se += e[k]; }
    float inv = 1.f / se;
    #pragma unroll
    for (int k = 0; k < 4; k++) outv[8+k] = e[k] * inv;

    size_t basep = (size_t)b * 12 * HWC + pbase;
    #pragma unroll
    for (int o = 0; o < 12; o++) oa[basep + (size_t)o * HWC] = outv[o];
}

// ---------------- Kernel 1 (fallback): full 128-channel conv ----------------
__global__ __launch_bounds__(256) void k1_convs(
    const float* __restrict__ bev, const float* __restrict__ wp,
    const float* __restrict__ offb, const float* __restrict__ wtb,
    float* __restrict__ oa)
{
    __shared__ float rows[2][3][260];
    int tid = threadIdx.x;
    int p = blockIdx.x;
    int b = p / HH; int i = p % HH; int j = tid;
    const float* bb = bev + (size_t)b * DD * HWC;

    if (tid < 12) { int bf = tid / 6, r = tid % 6; rows[bf][r >> 1][(r & 1) ? 257 : 0] = 0.f; }
    #pragma unroll
    for (int l = 0; l < 3; l++) {
        int yy = i + l - 1;
        rows[0][l][1 + tid] = ((unsigned)yy < HH) ? bb[yy * WW + tid] : 0.f;
    }
    __syncthreads();

    float acc[12];
    #pragma unroll
    for (int o = 0; o < 12; o++) acc[o] = 0.f;

    for (int c = 0; c < 128; c++) {
        int cb = c & 1, nb = cb ^ 1;
        float rv[3];
        if (c < 127) {
            const float* pln = bb + (size_t)(c + 1) * HWC;
            #pragma unroll
            for (int l = 0; l < 3; l++) {
                int yy = i + l - 1;
                rv[l] = ((unsigned)yy < HH) ? pln[yy * WW + tid] : 0.f;
            }
        }
        float v[9];
        #pragma unroll
        for (int dy = 0; dy < 3; dy++)
            #pragma unroll
            for (int dx = 0; dx < 3; dx++)
                v[dy*3 + dx] = rows[cb][dy][tid + dx];
        const float* wc = wp + c * 108;
        #pragma unroll
        for (int o = 0; o < 12; o++) {
            float s = acc[o];
            #pragma unroll
            for (int t = 0; t < 9; t++) s = fmaf(wc[o*9 + t], v[t], s);
            acc[o] = s;
        }
        if (c < 127) {
            #pragma unroll
            for (int l = 0; l < 3; l++) rows[nb][l][1 + tid] = rv[l];
        }
        __syncthreads();
    }

    float outv[12];
    #pragma unroll
    for (int o = 0; o < 8; o++) outv[o] = acc[o] + offb[o];
    float l4[4];
    #pragma unroll
    for (int k = 0; k < 4; k++) l4[k] = acc[8+k] + wtb[k];
    float m = fmaxf(fmaxf(l4[0], l4[1]), fmaxf(l4[2], l4[3]));
    float e[4]; float se = 0.f;
    #pragma unroll
    for (int k = 0; k < 4; k++) { e[k] = expf(l4[k] - m); se += e[k]; }
    float inv = 1.f / se;
    #pragma unroll
    for (int k = 0; k < 4; k++) outv[8+k] = e[k] * inv;

    size_t basep = (size_t)b * 12 * HWC + (size_t)i * WW + j;
    #pragma unroll
    for (int o = 0; o < 12; o++) oa[basep + (size_t)o * HWC] = outv[o];
}

// ---------------- Kernel 2a: deformable sample + K-aggregate -> agg[pix][128] bf16 ----------------
// Barrier-free, LDS-free. Thread = (pixel, d-quarter); quarter in lane bits 0-1,
// 16 consecutive-p pixels in bits 2-5 -> per tap the 4 q4-lanes read 4x16B
// CONTIGUOUS, so each 64B bevt line is fully consumed by one instruction
// (16 lines/instr vs round-7's 32 at 32B each: line-touch count halves).
// Per thread: 16 taps x 8 loads (shared base + offset:c*64), acc 32 channels.
__global__ __launch_bounds__(256) void k2a_sample(
    const float* __restrict__ bevt, const float* __restrict__ oa,
    ushort* __restrict__ aggb)
{
    int tid = threadIdx.x;
    int q4 = tid & 3;              // d-quarter slice within each 64B line
    int pl = (tid >> 2) & 15;      // p within wave: 16 consecutive
    int ql = tid >> 6;             // wave -> q
    int bidx = blockIdx.x;
    int b = bidx >> 10;
    int rem = bidx & 1023;
    int pt = rem >> 6;             // 0..15
    int qt = rem & 63;             // 0..63
    int p = pt * 16 + pl;
    int q = qt * 4 + ql;

    // offsets / attention (transpose quirk: x <- p+dx, y <- q+dy)
    const float* ob = oa + (size_t)b * 12 * HWC + (size_t)p * WW + q;
    unsigned pa[8]; float cw[16];
    #pragma unroll
    for (int k = 0; k < 4; k++) {
        float dx = ob[(size_t)(2*k)   * HWC];
        float dy = ob[(size_t)(2*k+1) * HWC];
        float a  = ob[(size_t)(8+k)   * HWC];
        float x  = fminf(fmaxf((float)p + dx, 0.f), (float)(WW-1));
        float yv = fminf(fmaxf((float)q + dy, 0.f), (float)(HH-1));
        float x0f = floorf(x); float y0f = floorf(yv);
        int x0 = (int)x0f; int y0 = (int)y0f;
        int x1 = min(x0 + 1, WW - 1); int y1 = min(y0 + 1, HH - 1);
        float wx = x - x0f; float wy = yv - y0f;
        pa[k*2+0] = (unsigned)(y0*WW + x0) | ((unsigned)(y0*WW + x1) << 16);
        pa[k*2+1] = (unsigned)(y1*WW + x0) | ((unsigned)(y1*WW + x1) << 16);
        cw[k*4+0] = a * (1.f - wx) * (1.f - wy);
        cw[k*4+1] = a * wx * (1.f - wy);
        cw[k*4+2] = a * (1.f - wx) * wy;
        cw[k*4+3] = a * wx * wy;
    }

    const float* bt = bevt + (size_t)b * HWC * 128 + q4 * 4;

    float4 s[8];
    #pragma unroll
    for (int c = 0; c < 8; c++) s[c] = make_float4(0.f, 0.f, 0.f, 0.f);

    #pragma unroll
    for (int t = 0; t < 16; t++) {
        unsigned a01 = pa[t >> 1];
        unsigned pix = (t & 1) ? (a01 >> 16) : (a01 & 0xffffu);
        const float* tp = bt + ((size_t)pix << 7);
        float w = cw[t];
        #pragma unroll
        for (int c = 0; c < 8; c++) {
            float4 v = *(const float4*)(tp + c * 16);
            s[c].x = fmaf(w, v.x, s[c].x);
            s[c].y = fmaf(w, v.y, s[c].y);
            s[c].z = fmaf(w, v.z, s[c].z);
            s[c].w = fmaf(w, v.w, s[c].w);
        }
    }

    // thread owns channels {16c+4*q4 .. +4} for c=0..7 -> 8B store per c
    ushort* outp = aggb + ((size_t)b * HWC + (size_t)p * WW + q) * 128 + q4 * 4;
    #pragma unroll
    for (int c = 0; c < 8; c++) {
        uint2 pk;
        pk.x = pkbf(s[c].x, s[c].y);
        pk.y = pkbf(s[c].z, s[c].w);
        *(uint2*)(outp + c * 16) = pk;
    }
}

// ---------------- Kernel 2b: 1x1 proj as bf16 MFMA GEMM + fused BN partial stats ----------------
// y[b][o][pix] = sum_d W[o][d] * agg[pix][d].  mfma_f32_16x16x32_bf16 layouts per guide S3.
// Each block also reduces its 64-pixel tile's sum/sumsq per o -> part2[o][2048] (f32),
// replacing k3_partial's 67MB re-read of y.
__global__ __launch_bounds__(256) void k2b_proj(
    const ushort* __restrict__ aggb, const ushort* __restrict__ wbf,
    float* __restrict__ y, float* __restrict__ part2)
{
    int tid = threadIdx.x;
    int wv = tid >> 6;
    int l = tid & 63;
    int lm = l & 15, lk = l >> 4;
    int bidx = blockIdx.x;
    int b = bidx >> 10;
    int pix0 = (bidx & 1023) << 6;
    int o0 = wv << 5;

    bf16x8 a[2][4];
    const ushort* wbase = wbf + (size_t)(o0 + lm) * 128 + lk * 8;
    #pragma unroll
    for (int ot = 0; ot < 2; ot++)
        #pragma unroll
        for (int kk = 0; kk < 4; kk++)
            a[ot][kk] = *(const bf16x8*)(wbase + ot * 16 * 128 + kk * 32);

    f32x4 acc[2][4];
    #pragma unroll
    for (int ot = 0; ot < 2; ot++)
        #pragma unroll
        for (int nt = 0; nt < 4; nt++)
            acc[ot][nt] = (f32x4)(0.f);

    const ushort* bbase = aggb + ((size_t)b * HWC + pix0 + lm) * 128 + lk * 8;
    #pragma unroll
    for (int nt = 0; nt < 4; nt++) {
        bf16x8 bfr[4];
        #pragma unroll
        for (int kk = 0; kk < 4; kk++)
            bfr[kk] = *(const bf16x8*)(bbase + nt * 16 * 128 + kk * 32);
        #pragma unroll
        for (int ot = 0; ot < 2; ot++)
            #pragma unroll
            for (int kk = 0; kk < 4; kk++)
                acc[ot][nt] = __builtin_amdgcn_mfma_f32_16x16x32_bf16(
                    a[ot][kk], bfr[kk], acc[ot][nt], 0, 0, 0);
    }

    #pragma unroll
    for (int ot = 0; ot < 2; ot++)
        #pragma unroll
        for (int nt = 0; nt < 4; nt++)
            #pragma unroll
            for (int r = 0; r < 4; r++)
                y[((size_t)b * DD + o0 + ot * 16 + lk * 4 + r) * HWC + pix0 + nt * 16 + lm]
                    = acc[ot][nt][r];

    // ---- fused BN partial stats over this block's 64 pixels ----
    float sm[2][4], sq[2][4];
    #pragma unroll
    for (int ot = 0; ot < 2; ot++)
        #pragma unroll
        for (int r = 0; r < 4; r++) { sm[ot][r] = 0.f; sq[ot][r] = 0.f; }
    #pragma unroll
    for (int ot = 0; ot < 2; ot++)
        #pragma unroll
        for (int nt = 0; nt < 4; nt++)
            #pragma unroll
            for (int r = 0; r < 4; r++) {
                float v = acc[ot][nt][r];
                sm[ot][r] += v;
                sq[ot][r] = fmaf(v, v, sq[ot][r]);
            }
    #pragma unroll
    for (int m = 1; m < 16; m <<= 1) {
        #pragma unroll
        for (int ot = 0; ot < 2; ot++)
            #pragma unroll
            for (int r = 0; r < 4; r++) {
                sm[ot][r] += __shfl_xor(sm[ot][r], m);
                sq[ot][r] += __shfl_xor(sq[ot][r], m);
            }
    }
    if (lm == 0) {
        #pragma unroll
        for (int ot = 0; ot < 2; ot++)
            #pragma unroll
            for (int r = 0; r < 4; r++) {
                int o = o0 + ot * 16 + lk * 4 + r;
                part2[(size_t)o * 2048 + bidx] = sm[ot][r];
                part2[(size_t)128 * 2048 + (size_t)o * 2048 + bidx] = sq[ot][r];
            }
    }
}

// ---------------- Kernel 3b': finalize BN from k2b block partials ----------------
__global__ __launch_bounds__(256) void k3b_finalize2(
    const float* __restrict__ part2, const float* __restrict__ gamma,
    const float* __restrict__ beta, float* __restrict__ stats)
{
    int o = blockIdx.x; int tid = threadIdx.x;
    const float* ps = part2 + (size_t)o * 2048;
    const float* pq = part2 + (size_t)128 * 2048 + (size_t)o * 2048;
    double s = 0.0, s2 = 0.0;
    for (int i = tid; i < 2048; i += 256) { s += (double)ps[i]; s2 += (double)pq[i]; }
    __shared__ double ls[256], ls2[256];
    ls[tid] = s; ls2[tid] = s2;
    __syncthreads();
    for (int off = 128; off > 0; off >>= 1) {
        if (tid < off) { ls[tid] += ls[tid+off]; ls2[tid] += ls2[tid+off]; }
        __syncthreads();
    }
    if (tid == 0) {
        double N = (double)(BB * HWC);
        double mean = ls[0] / N;
        double var = ls2[0] / N - mean * mean;
        double invs = 1.0 / sqrt(var + 1e-5);
        double g = (double)gamma[o];
        stats[o*2]   = (float)(g * invs);
        stats[o*2+1] = (float)((double)beta[o] - mean * g * invs);
    }
}

// ---------------- Kernel 2 fused fallback (NHWC) ----------------
__global__ __launch_bounds__(512, 2) void k2_sample_proj_t(
    const float* __restrict__ bevt, const float* __restrict__ oa,
    const float* __restrict__ wt, float* __restrict__ y)
{
    __shared__ float S[2][16 * SROW2];   // 40 KB

    int tid = threadIdx.x;
    int bidx = blockIdx.x;
    int b  = bidx >> 8;
    int p0 = ((bidx >> 4) & 15) * 16;
    int q0 = (bidx & 15) * 16;

    int gpix = tid >> 1;
    int gp = gpix & 15;
    int gq = gpix >> 4;
    int dgrp = tid & 1;
    int swr = gp * 20 + gq;

    int wv = tid >> 6;
    int wvu = __builtin_amdgcn_readfirstlane(wv);
    int lane = tid & 63;
    int lp = lane >> 2;
    int q4 = (lane & 3) << 2;
    int soff = lp * 20 + q4;

    const float* ob = oa + (size_t)b * 12 * HWC + (size_t)(p0 + gp) * WW + (q0 + gq);
    unsigned pa[8]; float cw[16];
    #pragma unroll
    for (int k = 0; k < 4; k++) {
        float dx = ob[(size_t)(2*k)   * HWC];
        float dy = ob[(size_t)(2*k+1) * HWC];
        float a  = ob[(size_t)(8+k)   * HWC];
        float x  = fminf(fmaxf((float)(p0 + gp) + dx, 0.f), (float)(WW-1));
        float yv = fminf(fmaxf((float)(q0 + gq) + dy, 0.f), (float)(HH-1));
        float x0f = floorf(x); float y0f = floorf(yv);
        int x0 = (int)x0f; int y0 = (int)y0f;
        int x1 = min(x0 + 1, WW - 1); int y1 = min(y0 + 1, HH - 1);
        float wx = x - x0f; float wy = yv - y0f;
        pa[k*2+0] = (unsigned)(y0*WW + x0) | ((unsigned)(y0*WW + x1) << 16);
        pa[k*2+1] = (unsigned)(y1*WW + x0) | ((unsigned)(y1*WW + x1) << 16);
        cw[k*4+0] = a * (1.f - wx) * (1.f - wy);
        cw[k*4+1] = a * wx * (1.f - wy);
        cw[k*4+2] = a * (1.f - wx) * wy;
        cw[k*4+3] = a * wx * wy;
    }

    const float* bt = bevt + (size_t)b * HWC * 128 + dgrp * 8;

    float acc[64];
    #pragma unroll
    for (int t = 0; t < 64; t++) acc[t] = 0.f;

    {
        float4 s0 = make_float4(0,0,0,0), s1 = make_float4(0,0,0,0);
        #pragma unroll
        for (int t = 0; t < 16; t++) {
            unsigned pix = (t & 1) ? (pa[t >> 1] >> 16) : (pa[t >> 1] & 0xffffu);
            const float4* tp = (const float4*)(bt + ((size_t)pix << 7));
            float4 va = tp[0], vb = tp[1];
            float c = cw[t];
            s0.x = fmaf(c, va.x, s0.x); s0.y = fmaf(c, va.y, s0.y);
            s0.z = fmaf(c, va.z, s0.z); s0.w = fmaf(c, va.w, s0.w);
            s1.x = fmaf(c, vb.x, s1.x); s1.y = fmaf(c, vb.y, s1.y);
            s1.z = fmaf(c, vb.z, s1.z); s1.w = fmaf(c, vb.w, s1.w);
        }
        int r = dgrp * 8;
        S[0][(r+0)*SROW2 + swr] = s0.x; S[0][(r+1)*SROW2 + swr] = s0.y;
        S[0][(r+2)*SROW2 + swr] = s0.z; S[0][(r+3)*SROW2 + swr] = s0.w;
        S[0][(r+4)*SROW2 + swr] = s1.x; S[0][(r+5)*SROW2 + swr] = s1.y;
        S[0][(r+6)*SROW2 + swr] = s1.z; S[0][(r+7)*SROW2 + swr] = s1.w;
    }
    __syncthreads();

    for (int c = 0; c < 8; c++) {
        int cur = c & 1;
        const float* Sc = &S[cur][0];
        float* Sn = &S[cur ^ 1][0];
        int d0 = c * 16;
        int dn = d0 + 16;
        bool more = (c < 7);

        float4 g0 = make_float4(0,0,0,0), g1 = make_float4(0,0,0,0);
        float4 pf0, pf1;
        if (more) {
            unsigned pix = pa[0] & 0xffffu;
            const float4* tp = (const float4*)(bt + ((size_t)pix << 7) + dn);
            pf0 = tp[0]; pf1 = tp[1];
        }

        #pragma unroll
        for (int dl = 0; dl < 16; dl++) {
            float4 cur0 = pf0, cur1 = pf1;
            if (more && dl < 15) {
                int t = dl + 1;
                unsigned pix = (t & 1) ? (pa[t >> 1] >> 16) : (pa[t >> 1] & 0xffffu);
                const float4* tp = (const float4*)(bt + ((size_t)pix << 7) + dn);
                pf0 = tp[0]; pf1 = tp[1];
            }

            float4 sv = *(const float4*)(Sc + dl * SROW2 + soff);
            const float4* wq = (const float4*)(wt + (size_t)(d0 + dl) * 128 + wvu * 16);
            #pragma unroll
            for (int oi4 = 0; oi4 < 4; oi4++) {
                float4 w4 = wq[oi4];
                int ob4 = oi4 * 16;
                acc[ob4+ 0] = fmaf(w4.x, sv.x, acc[ob4+ 0]);
                acc[ob4+ 1] = fmaf(w4.x, sv.y, acc[ob4+ 1]);
                acc[ob4+ 2] = fmaf(w4.x, sv.z, acc[ob4+ 2]);
                acc[ob4+ 3] = fmaf(w4.x, sv.w, acc[ob4+ 3]);
                acc[ob4+ 4] = fmaf(w4.y, sv.x, acc[ob4+ 4]);
                acc[ob4+ 5] = fmaf(w4.y, sv.y, acc[ob4+ 5]);
                acc[ob4+ 6] = fmaf(w4.y, sv.z, acc[ob4+ 6]);
                acc[ob4+ 7] = fmaf(w4.y, sv.w, acc[ob4+ 7]);
                acc[ob4+ 8] = fmaf(w4.z, sv.x, acc[ob4+ 8]);
                acc[ob4+ 9] = fmaf(w4.z, sv.y, acc[ob4+ 9]);
                acc[ob4+10] = fmaf(w4.z, sv.z, acc[ob4+10]);
                acc[ob4+11] = fmaf(w4.z, sv.w, acc[ob4+11]);
                acc[ob4+12] = fmaf(w4.w, sv.x, acc[ob4+12]);
                acc[ob4+13] = fmaf(w4.w, sv.y, acc[ob4+13]);
                acc[ob4+14] = fmaf(w4.w, sv.z, acc[ob4+14]);
                acc[ob4+15] = fmaf(w4.w, sv.w, acc[ob4+15]);
            }

            if (more) {
                float cwt = cw[dl];
                g0.x = fmaf(cwt, cur0.x, g0.x); g0.y = fmaf(cwt, cur0.y, g0.y);
                g0.z = fmaf(cwt, cur0.z, g0.z); g0.w = fmaf(cwt, cur0.w, g0.w);
                g1.x = fmaf(cwt, cur1.x, g1.x); g1.y = fmaf(cwt, cur1.y, g1.y);
                g1.z = fmaf(cwt, cur1.z, g1.z); g1.w = fmaf(cwt, cur1.w, g1.w);
            }
        }

        if (more) {
            int r = dgrp * 8;
            Sn[(r+0)*SROW2 + swr] = g0.x; Sn[(r+1)*SROW2 + swr] = g0.y;
            Sn[(r+2)*SROW2 + swr] = g0.z; Sn[(r+3)*SROW2 + swr] = g0.w;
            Sn[(r+4)*SROW2 + swr] = g1.x; Sn[(r+5)*SROW2 + swr] = g1.y;
            Sn[(r+6)*SROW2 + swr] = g1.z; Sn[(r+7)*SROW2 + swr] = g1.w;
        }
        __syncthreads();
    }

    size_t base = (size_t)b * DD * HWC + (size_t)(p0 + lp) * WW + (q0 + q4);
    #pragma unroll
    for (int oi = 0; oi < 16; oi++) {
        int o = wv * 16 + oi;
        float4 v = make_float4(acc[oi*4+0], acc[oi*4+1], acc[oi*4+2], acc[oi*4+3]);
        *(float4*)(y + base + (size_t)o * HWC) = v;
    }
}

// ---------------- Kernel 2 fallback (NCHW) ----------------
__global__ __launch_bounds__(512, 2) void k2_sample_proj(
    const float* __restrict__ bev, const float* __restrict__ oa,
    const float* __restrict__ wt, float* __restrict__ y)
{
    __shared__ float S[2][16 * SROW2];
    int tid = threadIdx.x;
    int bidx = blockIdx.x;
    int b  = bidx >> 8;
    int p0 = ((bidx >> 4) & 15) * 16;
    int q0 = (bidx & 15) * 16;
    int pix = tid & 255;
    int gq = pix >> 4;
    int gp = pix & 15;
    int dgrp = tid >> 8;
    int swr = gp * 20 + gq;
    int wv = tid >> 6;
    int wvu = __builtin_amdgcn_readfirstlane(wv);
    int lane = tid & 63;
    int lp = lane >> 2;
    int q4 = (lane & 3) << 2;
    int soff = lp * 20 + q4;

    const float* ob = oa + (size_t)b * 12 * HWC + (size_t)(p0 + gp) * WW + (q0 + gq);
    unsigned pa[8]; float cw[16];
    #pragma unroll
    for (int k = 0; k < 4; k++) {
        float dx = ob[(size_t)(2*k)   * HWC];
        float dy = ob[(size_t)(2*k+1) * HWC];
        float a  = ob[(size_t)(8+k)   * HWC];
        float x  = fminf(fmaxf((float)(p0 + gp) + dx, 0.f), (float)(WW-1));
        float yv = fminf(fmaxf((float)(q0 + gq) + dy, 0.f), (float)(HH-1));
        float x0f = floorf(x); float y0f = floorf(yv);
        int x0 = (int)x0f; int y0 = (int)y0f;
        int x1 = min(x0 + 1, WW - 1); int y1 = min(y0 + 1, HH - 1);
        float wx = x - x0f; float wy = yv - y0f;
        pa[k*2+0] = (unsigned)(y0*WW + x0) | ((unsigned)(y0*WW + x1) << 16);
        pa[k*2+1] = (unsigned)(y1*WW + x0) | ((unsigned)(y1*WW + x1) << 16);
        cw[k*4+0] = a * (1.f - wx) * (1.f - wy);
        cw[k*4+1] = a * wx * (1.f - wy);
        cw[k*4+2] = a * (1.f - wx) * wy;
        cw[k*4+3] = a * wx * wy;
    }
    const float* bb = bev + (size_t)b * DD * HWC;
    float acc[64];
    #pragma unroll
    for (int t = 0; t < 64; t++) acc[t] = 0.f;
    #pragma unroll
    for (int dd = 0; dd < 8; dd++) {
        const float* pl = bb + (size_t)(dgrp*8 + dd) * HWC;
        float s = 0.f;
        #pragma unroll
        for (int t = 0; t < 8; t++) {
            unsigned a01 = pa[t];
            s = fmaf(cw[2*t],   pl[a01 & 0xffffu], s);
            s = fmaf(cw[2*t+1], pl[a01 >> 16], s);
        }
        S[0][(dgrp*8 + dd) * SROW2 + swr] = s;
    }
    __syncthreads();
    for (int c = 0; c < 8; c++) {
        int cur = c & 1;
        const float* Sc = &S[cur][0];
        float* Sn = &S[cur ^ 1][0];
        int d0 = c * 16;
        int d0n = d0 + 16;
        bool more = (c < 7);
        #pragma unroll
        for (int dl = 0; dl < 16; dl++) {
            if (dl < 8) {
                if (more) {
                    const float* pl = bb + (size_t)(d0n + dgrp*8 + dl) * HWC;
                    float s = 0.f;
                    #pragma unroll
                    for (int t = 0; t < 8; t++) {
                        unsigned a01 = pa[t];
                        s = fmaf(cw[2*t],   pl[a01 & 0xffffu], s);
                        s = fmaf(cw[2*t+1], pl[a01 >> 16], s);
                    }
                    Sn[(dgrp*8 + dl) * SROW2 + swr] = s;
                }
            }
            float4 sv = *(const float4*)(Sc + dl * SROW2 + soff);
            const float4* wq = (const float4*)(wt + (size_t)(d0 + dl) * 128 + wvu * 16);
            #pragma unroll
            for (int oi4 = 0; oi4 < 4; oi4++) {
                float4 w4 = wq[oi4];
                int ob4 = oi4 * 16;
                acc[ob4+ 0] = fmaf(w4.x, sv.x, acc[ob4+ 0]);
                acc[ob4+ 1] = fmaf(w4.x, sv.y, acc[ob4+ 1]);
                acc[ob4+ 2] = fmaf(w4.x, sv.z, acc[ob4+ 2]);
                acc[ob4+ 3] = fmaf(w4.x, sv.w, acc[ob4+ 3]);
                acc[ob4+ 4] = fmaf(w4.y, sv.x, acc[ob4+ 4]);
                acc[ob4+ 5] = fmaf(w4.y, sv.y, acc[ob4+ 5]);
                acc[ob4+ 6] = fmaf(w4.y, sv.z, acc[ob4+ 6]);
                acc[ob4+ 7] = fmaf(w4.y, sv.w, acc[ob4+ 7]);
                acc[ob4+ 8] = fmaf(w4.z, sv.x, acc[ob4+ 8]);
                acc[ob4+ 9] = fmaf(w4.z, sv.y, acc[ob4+ 9]);
                acc[ob4+10] = fmaf(w4.z, sv.z, acc[ob4+10]);
                acc[ob4+11] = fmaf(w4.z, sv.w, acc[ob4+11]);
                acc[ob4+12] = fmaf(w4.w, sv.x, acc[ob4+12]);
                acc[ob4+13] = fmaf(w4.w, sv.y, acc[ob4+13]);
                acc[ob4+14] = fmaf(w4.w, sv.z, acc[ob4+14]);
                acc[ob4+15] = fmaf(w4.w, sv.w, acc[ob4+15]);
            }
        }
        __syncthreads();
    }
    size_t base = (size_t)b * DD * HWC + (size_t)(p0 + lp) * WW + (q0 + q4);
    #pragma unroll
    for (int oi = 0; oi < 16; oi++) {
        int o = wv * 16 + oi;
        float4 v = make_float4(acc[oi*4+0], acc[oi*4+1], acc[oi*4+2], acc[oi*4+3]);
        *(float4*)(y + base + (size_t)o * HWC) = v;
    }
}

// ---------------- Kernel 3a: per-channel partial sums (fallback tiers only) ----------------
__global__ __launch_bounds__(256) void k3_partial(
    const float* __restrict__ y, double* __restrict__ part)
{
    int blk = blockIdx.x;
    int o = blk >> 2; int sub = blk & 3; int b = sub >> 1; int half = sub & 1;
    const float4* pl = (const float4*)(y + ((size_t)b * DD + o) * HWC + half * (HWC/2));
    int tid = threadIdx.x;
    double s = 0.0, s2 = 0.0;
    for (int idx = tid; idx < HWC/8; idx += 256) {
        float4 v = pl[idx];
        s  += (double)v.x + (double)v.y + (double)v.z + (double)v.w;
        s2 += (double)v.x*v.x + (double)v.y*v.y + (double)v.z*v.z + (double)v.w*v.w;
    }
    __shared__ double ls[256], ls2[256];
    ls[tid] = s; ls2[tid] = s2;
    __syncthreads();
    for (int off = 128; off > 0; off >>= 1) {
        if (tid < off) { ls[tid] += ls[tid+off]; ls2[tid] += ls2[tid+off]; }
        __syncthreads();
    }
    if (tid == 0) { part[blk*2] = ls[0]; part[blk*2+1] = ls2[0]; }
}

// ---------------- Kernel 3b: finalize BN scale/shift (fallback tiers) ----------------
__global__ __launch_bounds__(128) void k3_finalize(
    const double* __restrict__ part, const float* __restrict__ gamma,
    const float* __restrict__ beta, float* __restrict__ stats)
{
    int o = threadIdx.x;
    double s = 0.0, s2 = 0.0;
    #pragma unroll
    for (int j = 0; j < 4; j++) { s += part[(o*4+j)*2]; s2 += part[(o*4+j)*2+1]; }
    double N = (double)(BB * HWC);
    double mean = s / N;
    double var = s2 / N - mean * mean;
    double invs = 1.0 / sqrt(var + 1e-5);
    double g = (double)gamma[o];
    stats[o*2]   = (float)(g * invs);
    stats[o*2+1] = (float)((double)beta[o] - mean * g * invs);
}

// ---------------- Kernel 4: BN + exact GELU ----------------
__global__ __launch_bounds__(256) void k4_bn_gelu(
    float* __restrict__ y, const float* __restrict__ stats)
{
    size_t idx4 = (size_t)blockIdx.x * 256 + threadIdx.x;
    float4* p = (float4*)y;
    float4 v = p[idx4];
    int o = (int)((idx4 * 4) / HWC) % DD;
    float sc = stats[o*2], sh = stats[o*2+1];
    const float inv_sqrt2 = 0.70710678118654752f;
    float g0 = fmaf(v.x, sc, sh);
    float g1 = fmaf(v.y, sc, sh);
    float g2 = fmaf(v.z, sc, sh);
    float g3 = fmaf(v.w, sc, sh);
    v.x = 0.5f * g0 * (1.f + erff(g0 * inv_sqrt2));
    v.y = 0.5f * g1 * (1.f + erff(g1 * inv_sqrt2));
    v.z = 0.5f * g2 * (1.f + erff(g2 * inv_sqrt2));
    v.w = 0.5f * g3 * (1.f + erff(g3 * inv_sqrt2));
    p[idx4] = v;
}

extern "C" void kernel_launch(void* const* d_in, const int* in_sizes, int n_in,
                              void* d_out, int out_size, void* d_ws, size_t ws_size,
                              hipStream_t stream) {
    const float* bev   = (const float*)d_in[0];
    const float* offw  = (const float*)d_in[1];
    const float* offb  = (const float*)d_in[2];
    const float* wtw   = (const float*)d_in[3];
    const float* wtb   = (const float*)d_in[4];
    const float* projw = (const float*)d_in[5];
    const float* gamma = (const float*)d_in[6];
    const float* beta  = (const float*)d_in[7];
    float* out = (float*)d_out;
    float* wsf = (float*)d_ws;

    float* oa    = wsf + OA_OFF;
    float* wtT   = wsf + WTT_OFF;
    float* wp    = wsf + WP_OFF;
    float* stats = wsf + STATS_OFF;
    double* part = (double*)(wsf + PART_OFF);
    float* bevt  = wsf + BEVT_OFF;
    float* pacc  = wsf + PACC_OFF;
    ushort* aggb = (ushort*)(wsf + AGG_OFF);
    ushort* wbf  = (ushort*)(wsf + WBF_OFF);
    float* part2 = wsf + PART2_OFF;   // aliases bevt (safe: written after last bevt read)

    bool full2 = ws_size >= WS_NEED_FULL2;
    bool full  = ws_size >= WS_NEED_FULL;
    bool big   = ws_size >= WS_NEED_BEVT;

    hipLaunchKernelGGL(k0_prep, dim3(64), dim3(256), 0, stream,
                       projw, offw, wtw, wtT, wp);
    if (full2) {
        hipLaunchKernelGGL(k0b_wbf, dim3(64), dim3(256), 0, stream, projw, wbf);
    }
    if (big) {
        hipLaunchKernelGGL(k2t_transpose, dim3(2048), dim3(256), 0, stream,
                           bev, bevt);
    }
    if (full) {
        hipLaunchKernelGGL(k1a_convs_partial, dim3(2048), dim3(256), 0, stream,
                           bev, wp, pacc);
        hipLaunchKernelGGL(k1b_reduce, dim3(BB*HH), dim3(256), 0, stream,
                           pacc, offb, wtb, oa);
    } else {
        hipLaunchKernelGGL(k1_convs, dim3(BB*HH), dim3(256), 0, stream,
                           bev, wp, offb, wtb, oa);
    }
    if (full2) {
        hipLaunchKernelGGL(k2a_sample, dim3(2048), dim3(256), 0, stream,
                           bevt, oa, aggb);
        hipLaunchKernelGGL(k2b_proj, dim3(2048), dim3(256), 0, stream,
                           aggb, wbf, out, part2);
        hipLaunchKernelGGL(k3b_finalize2, dim3(128), dim3(256), 0, stream,
                           part2, gamma, beta, stats);
    } else if (big) {
        hipLaunchKernelGGL(k2_sample_proj_t, dim3(BB*256), dim3(512), 0, stream,
                           bevt, oa, wtT, out);
        hipLaunchKernelGGL(k3_partial, dim3(512), dim3(256), 0, stream,
                           out, part);
        hipLaunchKernelGGL(k3_finalize, dim3(1), dim3(128), 0, stream,
                           part, gamma, beta, stats);
    } else {
        hipLaunchKernelGGL(k2_sample_proj, dim3(BB*256), dim3(512), 0, stream,
                           bev, oa, wtT, out);
        hipLaunchKernelGGL(k3_partial, dim3(512), dim3(256), 0, stream,
                           out, part);
        hipLaunchKernelGGL(k3_finalize, dim3(1), dim3(128), 0, stream,
                           part, gamma, beta, stats);
    }
    hipLaunchKernelGGL(k4_bn_gelu, dim3((BB*DD*HWC)/1024), dim3(256), 0, stream,
                       out, stats);
}

// Round 9
// 204.321 us; speedup vs baseline: 10.0507x; 1.0488x over previous
//
#include <hip/hip_runtime.h>
#include <math.h>

#define BB 2
#define DD 128
#define HH 256
#define WW 256
#define KK 4
#define HWC (HH*WW)
#define SROW2 320   // d-slice stride in S (fused fallback kernels)

typedef unsigned int u32;
typedef unsigned short ushort;
typedef __attribute__((ext_vector_type(8))) short bf16x8;
typedef __attribute__((ext_vector_type(4))) float f32x4;

// ws float layout
#define OA_OFF    0
#define WTT_OFF   1572864
#define WP_OFF    1589248
#define STATS_OFF 1603072
#define PART_OFF  1603392
#define BEVT_OFF  1605440       // full3: bevtb bf16 (16.8M ushort = 8.4M floats); tier2: f32 bevt
#define PACC_OFF  18382656
#define AGG_OFF   PACC_OFF      // agg bf16: 16.8M ushort
#define WBF_OFF   26771264      // proj W bf16: 16384 ushort = 8192 floats
#define WCB_OFF   26779456      // conv W bf16 padded: 9*16*128 ushort = 9216 float-slots
// PART2 aliases BEVT region: k2b (writes part2) runs strictly after k2a's last bevtb read.
#define PART2_OFF BEVT_OFF
#define WS_NEED_BEVT  ((size_t)PACC_OFF * 4)
#define WS_NEED_FULL3 ((size_t)(WCB_OFF + 9216) * 4)

__device__ __forceinline__ u32 f2bf(float x) {
    u32 u = __builtin_bit_cast(u32, x);
    return (u + 0x7fffu + ((u >> 16) & 1u)) >> 16;
}
__device__ __forceinline__ u32 pkbf(float a, float b) {
    return f2bf(a) | (f2bf(b) << 16);
}
__device__ __forceinline__ float bflo(u32 d) { return __builtin_bit_cast(float, d << 16); }
__device__ __forceinline__ float bfhi(u32 d) { return __builtin_bit_cast(float, d & 0xffff0000u); }

// ---------------- Kernel 0: weight prep (wtT/wp for fallback tiers) ----------------
__global__ __launch_bounds__(256) void k0_prep(
    const float* __restrict__ projw, const float* __restrict__ offw,
    const float* __restrict__ wtw, float* __restrict__ wtT, float* __restrict__ wp)
{
    int idx = blockIdx.x * 256 + threadIdx.x;
    if (idx < 16384) {
        int d = idx >> 7, o = idx & 127;
        wtT[d * 128 + o] = projw[o * 128 + d];
    }
    if (idx < 13824) {
        int c = idx / 108; int r = idx % 108; int o = r / 9; int t = r % 9;
        wp[idx] = (o < 8) ? offw[(o*128 + c)*9 + t] : wtw[((o-8)*128 + c)*9 + t];
    }
}

// ---------------- Kernel 0b: proj weights -> bf16 [o][d] ----------------
__global__ __launch_bounds__(256) void k0b_wbf(
    const float* __restrict__ projw, ushort* __restrict__ wbf)
{
    int idx = blockIdx.x * 256 + threadIdx.x;
    if (idx < 16384) wbf[idx] = (ushort)f2bf(projw[idx]);
}

// ---------------- Kernel 0c: conv weights -> bf16 wcb[tap][16(o pad)][128(c)] ----------------
__global__ __launch_bounds__(256) void k0c_wcb(
    const float* __restrict__ offw, const float* __restrict__ wtw,
    ushort* __restrict__ wcb)
{
    int idx = blockIdx.x * 256 + threadIdx.x;
    if (idx < 18432) {
        int tap = idx >> 11;          // /2048
        int rem = idx & 2047;
        int oo = rem >> 7, c = rem & 127;
        float v = 0.f;
        if (oo < 8)       v = offw[(oo*128 + c)*9 + tap];
        else if (oo < 12) v = wtw[((oo-8)*128 + c)*9 + tap];
        wcb[idx] = (ushort)f2bf(v);
    }
}

// ---------------- Kernel Tb: NCHW f32 -> NHWC bf16 (bevtb[b][y][x][128]) ----------------
__global__ __launch_bounds__(256) void k2t_bf(
    const float* __restrict__ bev, ushort* __restrict__ bevtb)
{
    __shared__ float T[64 * 128];   // 32 KB, XOR-swizzled (same scheme as verified k2t)
    int tid = threadIdx.x;
    int bidx = blockIdx.x;
    int b = bidx >> 10;
    int rem = bidx & 1023;
    int yrow = rem >> 2;
    int x0 = (rem & 3) << 6;

    const float* src = bev + ((size_t)b * DD) * HWC + (size_t)yrow * WW + x0;
    #pragma unroll 4
    for (int k = 0; k < 32; k++) {
        int flat = k * 256 + tid;
        int d = flat >> 6, xl = flat & 63;
        float v = src[(size_t)d * HWC + xl];
        T[xl * 128 + (((d >> 2) ^ (xl & 31)) << 2) + (d & 3)] = v;
    }
    __syncthreads();
    ushort* dst = bevtb + (((size_t)b * HH + yrow) * WW + x0) * 128;
    #pragma unroll 4
    for (int k = 0; k < 8; k++) {
        int flat = k * 256 + tid;
        int d4 = flat & 31, xl = (flat >> 5) & 63;
        float4 v = *(const float4*)&T[xl * 128 + ((d4 ^ (xl & 31)) << 2)];
        uint2 pk;
        pk.x = pkbf(v.x, v.y);
        pk.y = pkbf(v.z, v.w);
        *(uint2*)(dst + (size_t)xl * 128 + (d4 << 2)) = pk;
    }
}

// ---------------- Kernel 1m: 3x3 convs as implicit-GEMM MFMA ----------------
// y12[o][pix] = sum_tap Wtap[16(12)][128] x[128][16px].  mfma_f32_16x16x32_bf16,
// fragment mapping identical to the verified k2b: A lane o=lm, B lane px=lm,
// C/D row(o)=lk*4+r, col(px)=lm.  Attn logits o=8..11 land whole in lk==2 lanes
// -> softmax fully in-register.  Block = 4 waves x 16 px of one row (b,i).
__global__ __launch_bounds__(256) void k1m_conv_mfma(
    const ushort* __restrict__ bevtb, const ushort* __restrict__ wcb,
    const float* __restrict__ offb, const float* __restrict__ wtb,
    float* __restrict__ oa)
{
    int tid = threadIdx.x;
    int wv = tid >> 6;
    int l = tid & 63;
    int lm = l & 15, lk = l >> 4;
    int bidx = blockIdx.x;
    int b = bidx >> 10;
    int i = (bidx >> 2) & 255;
    int jt = bidx & 3;
    int j = jt * 64 + wv * 16 + lm;

    const ushort* bb = bevtb + (size_t)b * HWC * 128;
    f32x4 acc = (f32x4)(0.f);

    #pragma unroll
    for (int dy = 0; dy < 3; dy++) {
        int yy = i + dy - 1;
        bool yok = ((unsigned)yy < HH);
        #pragma unroll
        for (int dx = 0; dx < 3; dx++) {
            int xx = j + dx - 1;
            bool ok = yok && ((unsigned)xx < WW);
            int pix = ok ? (yy * WW + xx) : 0;
            const ushort* bp = bb + (size_t)pix * 128 + lk * 8;
            const ushort* ap = wcb + (size_t)((dy*3 + dx) * 16 + lm) * 128 + lk * 8;
            #pragma unroll
            for (int kk = 0; kk < 4; kk++) {
                bf16x8 bfr = (bf16x8)0;
                if (ok) bfr = *(const bf16x8*)(bp + kk * 32);
                bf16x8 afr = *(const bf16x8*)(ap + kk * 32);
                acc = __builtin_amdgcn_mfma_f32_16x16x32_bf16(afr, bfr, acc, 0, 0, 0);
            }
        }
    }

    float v[4];
    #pragma unroll
    for (int r = 0; r < 4; r++) v[r] = acc[r];

    if (lk < 2) {
        #pragma unroll
        for (int r = 0; r < 4; r++) v[r] += offb[lk*4 + r];   // OFFSET_SCALE = 1.0
    } else if (lk == 2) {
        float l4[4];
        #pragma unroll
        for (int r = 0; r < 4; r++) l4[r] = v[r] + wtb[r];
        float m = fmaxf(fmaxf(l4[0], l4[1]), fmaxf(l4[2], l4[3]));
        float e[4]; float se = 0.f;
        #pragma unroll
        for (int r = 0; r < 4; r++) { e[r] = expf(l4[r] - m); se += e[r]; }
        float inv = 1.f / se;
        #pragma unroll
        for (int r = 0; r < 4; r++) v[r] = e[r] * inv;
    }
    if (lk < 3) {
        size_t basep = (size_t)b * 12 * HWC + (size_t)i * WW + j;
        #pragma unroll
        for (int r = 0; r < 4; r++)
            oa[basep + (size_t)(lk*4 + r) * HWC] = v[r];
    }
}

// ---------------- Kernel 1 (tier2 fallback): full 128-channel conv ----------------
__global__ __launch_bounds__(256) void k1_convs(
    const float* __restrict__ bev, const float* __restrict__ wp,
    const float* __restrict__ offb, const float* __restrict__ wtb,
    float* __restrict__ oa)
{
    __shared__ float rows[2][3][260];
    int tid = threadIdx.x;
    int p = blockIdx.x;
    int b = p / HH; int i = p % HH; int j = tid;
    const float* bb = bev + (size_t)b * DD * HWC;

    if (tid < 12) { int bf = tid / 6, r = tid % 6; rows[bf][r >> 1][(r & 1) ? 257 : 0] = 0.f; }
    #pragma unroll
    for (int l = 0; l < 3; l++) {
        int yy = i + l - 1;
        rows[0][l][1 + tid] = ((unsigned)yy < HH) ? bb[yy * WW + tid] : 0.f;
    }
    __syncthreads();

    float acc[12];
    #pragma unroll
    for (int o = 0; o < 12; o++) acc[o] = 0.f;

    for (int c = 0; c < 128; c++) {
        int cb = c & 1, nb = cb ^ 1;
        float rv[3];
        if (c < 127) {
            const float* pln = bb + (size_t)(c + 1) * HWC;
            #pragma unroll
            for (int l = 0; l < 3; l++) {
                int yy = i + l - 1;
                rv[l] = ((unsigned)yy < HH) ? pln[yy * WW + tid] : 0.f;
            }
        }
        float v[9];
        #pragma unroll
        for (int dy = 0; dy < 3; dy++)
            #pragma unroll
            for (int dx = 0; dx < 3; dx++)
                v[dy*3 + dx] = rows[cb][dy][tid + dx];
        const float* wc = wp + c * 108;
        #pragma unroll
        for (int o = 0; o < 12; o++) {
            float s = acc[o];
            #pragma unroll
            for (int t = 0; t < 9; t++) s = fmaf(wc[o*9 + t], v[t], s);
            acc[o] = s;
        }
        if (c < 127) {
            #pragma unroll
            for (int l = 0; l < 3; l++) rows[nb][l][1 + tid] = rv[l];
        }
        __syncthreads();
    }

    float outv[12];
    #pragma unroll
    for (int o = 0; o < 8; o++) outv[o] = acc[o] + offb[o];
    float l4[4];
    #pragma unroll
    for (int k = 0; k < 4; k++) l4[k] = acc[8+k] + wtb[k];
    float m = fmaxf(fmaxf(l4[0], l4[1]), fmaxf(l4[2], l4[3]));
    float e[4]; float se = 0.f;
    #pragma unroll
    for (int k = 0; k < 4; k++) { e[k] = expf(l4[k] - m); se += e[k]; }
    float inv = 1.f / se;
    #pragma unroll
    for (int k = 0; k < 4; k++) outv[8+k] = e[k] * inv;

    size_t basep = (size_t)b * 12 * HWC + (size_t)i * WW + j;
    #pragma unroll
    for (int o = 0; o < 12; o++) oa[basep + (size_t)o * HWC] = outv[o];
}

// ---------------- Kernel T (tier2): NCHW -> NHWC f32 transpose ----------------
__global__ __launch_bounds__(256) void k2t_transpose(
    const float* __restrict__ bev, float* __restrict__ bevt)
{
    __shared__ float T[64 * 128];
    int tid = threadIdx.x;
    int bidx = blockIdx.x;
    int b = bidx >> 10;
    int rem = bidx & 1023;
    int yrow = rem >> 2;
    int x0 = (rem & 3) << 6;

    const float* src = bev + ((size_t)b * DD) * HWC + (size_t)yrow * WW + x0;
    #pragma unroll 4
    for (int k = 0; k < 32; k++) {
        int flat = k * 256 + tid;
        int d = flat >> 6, xl = flat & 63;
        float v = src[(size_t)d * HWC + xl];
        T[xl * 128 + (((d >> 2) ^ (xl & 31)) << 2) + (d & 3)] = v;
    }
    __syncthreads();
    float* dst = bevt + (((size_t)b * HH + yrow) * WW + x0) * 128;
    #pragma unroll 4
    for (int k = 0; k < 8; k++) {
        int flat = k * 256 + tid;
        int d4 = flat & 31, xl = (flat >> 5) & 63;
        float4 v = *(const float4*)&T[xl * 128 + ((d4 ^ (xl & 31)) << 2)];
        *(float4*)(dst + (size_t)xl * 128 + (d4 << 2)) = v;
    }
}

// ---------------- Kernel 2a (bf16): deformable sample + K-aggregate ----------------
// Thread = (pixel, d-quarter).  bf16 bevtb: per tap, lane q4 reads 16B at
// byte pix*256 + q4*16 + c*64 -> 4 q4-lanes fully consume each 64B line, 4 instr/tap
// (line-touches halved vs R8's f32: 16.8M -> 8.4M).
__global__ __launch_bounds__(256) void k2a_sample_bf(
    const ushort* __restrict__ bevtb, const float* __restrict__ oa,
    ushort* __restrict__ aggb)
{
    int tid = threadIdx.x;
    int q4 = tid & 3;
    int pl = (tid >> 2) & 15;
    int ql = tid >> 6;
    int bidx = blockIdx.x;
    int b = bidx >> 10;
    int rem = bidx & 1023;
    int pt = rem >> 6;
    int qt = rem & 63;
    int p = pt * 16 + pl;
    int q = qt * 4 + ql;

    // offsets / attention (transpose quirk: x <- p+dx, y <- q+dy)
    const float* ob = oa + (size_t)b * 12 * HWC + (size_t)p * WW + q;
    unsigned pa[8]; float cw[16];
    #pragma unroll
    for (int k = 0; k < 4; k++) {
        float dx = ob[(size_t)(2*k)   * HWC];
        float dy = ob[(size_t)(2*k+1) * HWC];
        float a  = ob[(size_t)(8+k)   * HWC];
        float x  = fminf(fmaxf((float)p + dx, 0.f), (float)(WW-1));
        float yv = fminf(fmaxf((float)q + dy, 0.f), (float)(HH-1));
        float x0f = floorf(x); float y0f = floorf(yv);
        int x0 = (int)x0f; int y0 = (int)y0f;
        int x1 = min(x0 + 1, WW - 1); int y1 = min(y0 + 1, HH - 1);
        float wx = x - x0f; float wy = yv - y0f;
        pa[k*2+0] = (unsigned)(y0*WW + x0) | ((unsigned)(y0*WW + x1) << 16);
        pa[k*2+1] = (unsigned)(y1*WW + x0) | ((unsigned)(y1*WW + x1) << 16);
        cw[k*4+0] = a * (1.f - wx) * (1.f - wy);
        cw[k*4+1] = a * wx * (1.f - wy);
        cw[k*4+2] = a * (1.f - wx) * wy;
        cw[k*4+3] = a * wx * wy;
    }

    const ushort* bt = bevtb + (size_t)b * HWC * 128 + q4 * 8;

    float s[4][8];
    #pragma unroll
    for (int c = 0; c < 4; c++)
        #pragma unroll
        for (int e = 0; e < 8; e++) s[c][e] = 0.f;

    #pragma unroll
    for (int t = 0; t < 16; t++) {
        unsigned a01 = pa[t >> 1];
        unsigned pix = (t & 1) ? (a01 >> 16) : (a01 & 0xffffu);
        const ushort* tp = bt + ((size_t)pix << 7);
        float w = cw[t];
        #pragma unroll
        for (int c = 0; c < 4; c++) {
            uint4 v = *(const uint4*)(tp + c * 32);
            s[c][0] = fmaf(w, bflo(v.x), s[c][0]);
            s[c][1] = fmaf(w, bfhi(v.x), s[c][1]);
            s[c][2] = fmaf(w, bflo(v.y), s[c][2]);
            s[c][3] = fmaf(w, bfhi(v.y), s[c][3]);
            s[c][4] = fmaf(w, bflo(v.z), s[c][4]);
            s[c][5] = fmaf(w, bfhi(v.z), s[c][5]);
            s[c][6] = fmaf(w, bflo(v.w), s[c][6]);
            s[c][7] = fmaf(w, bfhi(v.w), s[c][7]);
        }
    }

    // thread owns channels q4*8 + c*32 .. +8  (ch-linear agg preserved for k2b)
    ushort* outp = aggb + ((size_t)b * HWC + (size_t)p * WW + q) * 128 + q4 * 8;
    #pragma unroll
    for (int c = 0; c < 4; c++) {
        uint4 pk;
        pk.x = pkbf(s[c][0], s[c][1]);
        pk.y = pkbf(s[c][2], s[c][3]);
        pk.z = pkbf(s[c][4], s[c][5]);
        pk.w = pkbf(s[c][6], s[c][7]);
        *(uint4*)(outp + c * 32) = pk;
    }
}

// ---------------- Kernel 2b: 1x1 proj as bf16 MFMA GEMM + fused BN partial stats ----------------
__global__ __launch_bounds__(256) void k2b_proj(
    const ushort* __restrict__ aggb, const ushort* __restrict__ wbf,
    float* __restrict__ y, float* __restrict__ part2)
{
    int tid = threadIdx.x;
    int wv = tid >> 6;
    int l = tid & 63;
    int lm = l & 15, lk = l >> 4;
    int bidx = blockIdx.x;
    int b = bidx >> 10;
    int pix0 = (bidx & 1023) << 6;
    int o0 = wv << 5;

    bf16x8 a[2][4];
    const ushort* wbase = wbf + (size_t)(o0 + lm) * 128 + lk * 8;
    #pragma unroll
    for (int ot = 0; ot < 2; ot++)
        #pragma unroll
        for (int kk = 0; kk < 4; kk++)
            a[ot][kk] = *(const bf16x8*)(wbase + ot * 16 * 128 + kk * 32);

    f32x4 acc[2][4];
    #pragma unroll
    for (int ot = 0; ot < 2; ot++)
        #pragma unroll
        for (int nt = 0; nt < 4; nt++)
            acc[ot][nt] = (f32x4)(0.f);

    const ushort* bbase = aggb + ((size_t)b * HWC + pix0 + lm) * 128 + lk * 8;
    #pragma unroll
    for (int nt = 0; nt < 4; nt++) {
        bf16x8 bfr[4];
        #pragma unroll
        for (int kk = 0; kk < 4; kk++)
            bfr[kk] = *(const bf16x8*)(bbase + nt * 16 * 128 + kk * 32);
        #pragma unroll
        for (int ot = 0; ot < 2; ot++)
            #pragma unroll
            for (int kk = 0; kk < 4; kk++)
                acc[ot][nt] = __builtin_amdgcn_mfma_f32_16x16x32_bf16(
                    a[ot][kk], bfr[kk], acc[ot][nt], 0, 0, 0);
    }

    #pragma unroll
    for (int ot = 0; ot < 2; ot++)
        #pragma unroll
        for (int nt = 0; nt < 4; nt++)
            #pragma unroll
            for (int r = 0; r < 4; r++)
                y[((size_t)b * DD + o0 + ot * 16 + lk * 4 + r) * HWC + pix0 + nt * 16 + lm]
                    = acc[ot][nt][r];

    float sm[2][4], sq[2][4];
    #pragma unroll
    for (int ot = 0; ot < 2; ot++)
        #pragma unroll
        for (int r = 0; r < 4; r++) { sm[ot][r] = 0.f; sq[ot][r] = 0.f; }
    #pragma unroll
    for (int ot = 0; ot < 2; ot++)
        #pragma unroll
        for (int nt = 0; nt < 4; nt++)
            #pragma unroll
            for (int r = 0; r < 4; r++) {
                float v = acc[ot][nt][r];
                sm[ot][r] += v;
                sq[ot][r] = fmaf(v, v, sq[ot][r]);
            }
    #pragma unroll
    for (int m = 1; m < 16; m <<= 1) {
        #pragma unroll
        for (int ot = 0; ot < 2; ot++)
            #pragma unroll
            for (int r = 0; r < 4; r++) {
                sm[ot][r] += __shfl_xor(sm[ot][r], m);
                sq[ot][r] += __shfl_xor(sq[ot][r], m);
            }
    }
    if (lm == 0) {
        #pragma unroll
        for (int ot = 0; ot < 2; ot++)
            #pragma unroll
            for (int r = 0; r < 4; r++) {
                int o = o0 + ot * 16 + lk * 4 + r;
                part2[(size_t)o * 2048 + bidx] = sm[ot][r];
                part2[(size_t)128 * 2048 + (size_t)o * 2048 + bidx] = sq[ot][r];
            }
    }
}

// ---------------- Kernel 3b': finalize BN from k2b block partials ----------------
__global__ __launch_bounds__(256) void k3b_finalize2(
    const float* __restrict__ part2, const float* __restrict__ gamma,
    const float* __restrict__ beta, float* __restrict__ stats)
{
    int o = blockIdx.x; int tid = threadIdx.x;
    const float* ps = part2 + (size_t)o * 2048;
    const float* pq = part2 + (size_t)128 * 2048 + (size_t)o * 2048;
    double s = 0.0, s2 = 0.0;
    for (int i = tid; i < 2048; i += 256) { s += (double)ps[i]; s2 += (double)pq[i]; }
    __shared__ double ls[256], ls2[256];
    ls[tid] = s; ls2[tid] = s2;
    __syncthreads();
    for (int off = 128; off > 0; off >>= 1) {
        if (tid < off) { ls[tid] += ls[tid+off]; ls2[tid] += ls2[tid+off]; }
        __syncthreads();
    }
    if (tid == 0) {
        double N = (double)(BB * HWC);
        double mean = ls[0] / N;
        double var = ls2[0] / N - mean * mean;
        double invs = 1.0 / sqrt(var + 1e-5);
        double g = (double)gamma[o];
        stats[o*2]   = (float)(g * invs);
        stats[o*2+1] = (float)((double)beta[o] - mean * g * invs);
    }
}

// ---------------- Kernel 2 fused fallback (tier2, NHWC f32) ----------------
__global__ __launch_bounds__(512, 2) void k2_sample_proj_t(
    const float* __restrict__ bevt, const float* __restrict__ oa,
    const float* __restrict__ wt, float* __restrict__ y)
{
    __shared__ float S[2][16 * SROW2];

    int tid = threadIdx.x;
    int bidx = blockIdx.x;
    int b  = bidx >> 8;
    int p0 = ((bidx >> 4) & 15) * 16;
    int q0 = (bidx & 15) * 16;

    int gpix = tid >> 1;
    int gp = gpix & 15;
    int gq = gpix >> 4;
    int dgrp = tid & 1;
    int swr = gp * 20 + gq;

    int wv = tid >> 6;
    int wvu = __builtin_amdgcn_readfirstlane(wv);
    int lane = tid & 63;
    int lp = lane >> 2;
    int q4 = (lane & 3) << 2;
    int soff = lp * 20 + q4;

    const float* ob = oa + (size_t)b * 12 * HWC + (size_t)(p0 + gp) * WW + (q0 + gq);
    unsigned pa[8]; float cw[16];
    #pragma unroll
    for (int k = 0; k < 4; k++) {
        float dx = ob[(size_t)(2*k)   * HWC];
        float dy = ob[(size_t)(2*k+1) * HWC];
        float a  = ob[(size_t)(8+k)   * HWC];
        float x  = fminf(fmaxf((float)(p0 + gp) + dx, 0.f), (float)(WW-1));
        float yv = fminf(fmaxf((float)(q0 + gq) + dy, 0.f), (float)(HH-1));
        float x0f = floorf(x); float y0f = floorf(yv);
        int x0 = (int)x0f; int y0 = (int)y0f;
        int x1 = min(x0 + 1, WW - 1); int y1 = min(y0 + 1, HH - 1);
        float wx = x - x0f; float wy = yv - y0f;
        pa[k*2+0] = (unsigned)(y0*WW + x0) | ((unsigned)(y0*WW + x1) << 16);
        pa[k*2+1] = (unsigned)(y1*WW + x0) | ((unsigned)(y1*WW + x1) << 16);
        cw[k*4+0] = a * (1.f - wx) * (1.f - wy);
        cw[k*4+1] = a * wx * (1.f - wy);
        cw[k*4+2] = a * (1.f - wx) * wy;
        cw[k*4+3] = a * wx * wy;
    }

    const float* bt = bevt + (size_t)b * HWC * 128 + dgrp * 8;

    float acc[64];
    #pragma unroll
    for (int t = 0; t < 64; t++) acc[t] = 0.f;

    {
        float4 s0 = make_float4(0,0,0,0), s1 = make_float4(0,0,0,0);
        #pragma unroll
        for (int t = 0; t < 16; t++) {
            unsigned pix = (t & 1) ? (pa[t >> 1] >> 16) : (pa[t >> 1] & 0xffffu);
            const float4* tp = (const float4*)(bt + ((size_t)pix << 7));
            float4 va = tp[0], vb = tp[1];
            float c = cw[t];
            s0.x = fmaf(c, va.x, s0.x); s0.y = fmaf(c, va.y, s0.y);
            s0.z = fmaf(c, va.z, s0.z); s0.w = fmaf(c, va.w, s0.w);
            s1.x = fmaf(c, vb.x, s1.x); s1.y = fmaf(c, vb.y, s1.y);
            s1.z = fmaf(c, vb.z, s1.z); s1.w = fmaf(c, vb.w, s1.w);
        }
        int r = dgrp * 8;
        S[0][(r+0)*SROW2 + swr] = s0.x; S[0][(r+1)*SROW2 + swr] = s0.y;
        S[0][(r+2)*SROW2 + swr] = s0.z; S[0][(r+3)*SROW2 + swr] = s0.w;
        S[0][(r+4)*SROW2 + swr] = s1.x; S[0][(r+5)*SROW2 + swr] = s1.y;
        S[0][(r+6)*SROW2 + swr] = s1.z; S[0][(r+7)*SROW2 + swr] = s1.w;
    }
    __syncthreads();

    for (int c = 0; c < 8; c++) {
        int cur = c & 1;
        const float* Sc = &S[cur][0];
        float* Sn = &S[cur ^ 1][0];
        int d0 = c * 16;
        int dn = d0 + 16;
        bool more = (c < 7);

        float4 g0 = make_float4(0,0,0,0), g1 = make_float4(0,0,0,0);
        float4 pf0, pf1;
        if (more) {
            unsigned pix = pa[0] & 0xffffu;
            const float4* tp = (const float4*)(bt + ((size_t)pix << 7) + dn);
            pf0 = tp[0]; pf1 = tp[1];
        }

        #pragma unroll
        for (int dl = 0; dl < 16; dl++) {
            float4 cur0 = pf0, cur1 = pf1;
            if (more && dl < 15) {
                int t = dl + 1;
                unsigned pix = (t & 1) ? (pa[t >> 1] >> 16) : (pa[t >> 1] & 0xffffu);
                const float4* tp = (const float4*)(bt + ((size_t)pix << 7) + dn);
                pf0 = tp[0]; pf1 = tp[1];
            }

            float4 sv = *(const float4*)(Sc + dl * SROW2 + soff);
            const float4* wq = (const float4*)(wt + (size_t)(d0 + dl) * 128 + wvu * 16);
            #pragma unroll
            for (int oi4 = 0; oi4 < 4; oi4++) {
                float4 w4 = wq[oi4];
                int ob4 = oi4 * 16;
                acc[ob4+ 0] = fmaf(w4.x, sv.x, acc[ob4+ 0]);
                acc[ob4+ 1] = fmaf(w4.x, sv.y, acc[ob4+ 1]);
                acc[ob4+ 2] = fmaf(w4.x, sv.z, acc[ob4+ 2]);
                acc[ob4+ 3] = fmaf(w4.x, sv.w, acc[ob4+ 3]);
                acc[ob4+ 4] = fmaf(w4.y, sv.x, acc[ob4+ 4]);
                acc[ob4+ 5] = fmaf(w4.y, sv.y, acc[ob4+ 5]);
                acc[ob4+ 6] = fmaf(w4.y, sv.z, acc[ob4+ 6]);
                acc[ob4+ 7] = fmaf(w4.y, sv.w, acc[ob4+ 7]);
                acc[ob4+ 8] = fmaf(w4.z, sv.x, acc[ob4+ 8]);
                acc[ob4+ 9] = fmaf(w4.z, sv.y, acc[ob4+ 9]);
                acc[ob4+10] = fmaf(w4.z, sv.z, acc[ob4+10]);
                acc[ob4+11] = fmaf(w4.z, sv.w, acc[ob4+11]);
                acc[ob4+12] = fmaf(w4.w, sv.x, acc[ob4+12]);
                acc[ob4+13] = fmaf(w4.w, sv.y, acc[ob4+13]);
                acc[ob4+14] = fmaf(w4.w, sv.z, acc[ob4+14]);
                acc[ob4+15] = fmaf(w4.w, sv.w, acc[ob4+15]);
            }

            if (more) {
                float cwt = cw[dl];
                g0.x = fmaf(cwt, cur0.x, g0.x); g0.y = fmaf(cwt, cur0.y, g0.y);
                g0.z = fmaf(cwt, cur0.z, g0.z); g0.w = fmaf(cwt, cur0.w, g0.w);
                g1.x = fmaf(cwt, cur1.x, g1.x); g1.y = fmaf(cwt, cur1.y, g1.y);
                g1.z = fmaf(cwt, cur1.z, g1.z); g1.w = fmaf(cwt, cur1.w, g1.w);
            }
        }

        if (more) {
            int r = dgrp * 8;
            Sn[(r+0)*SROW2 + swr] = g0.x; Sn[(r+1)*SROW2 + swr] = g0.y;
            Sn[(r+2)*SROW2 + swr] = g0.z; Sn[(r+3)*SROW2 + swr] = g0.w;
            Sn[(r+4)*SROW2 + swr] = g1.x; Sn[(r+5)*SROW2 + swr] = g1.y;
            Sn[(r+6)*SROW2 + swr] = g1.z; Sn[(r+7)*SROW2 + swr] = g1.w;
        }
        __syncthreads();
    }

    size_t base = (size_t)b * DD * HWC + (size_t)(p0 + lp) * WW + (q0 + q4);
    #pragma unroll
    for (int oi = 0; oi < 16; oi++) {
        int o = wv * 16 + oi;
        float4 v = make_float4(acc[oi*4+0], acc[oi*4+1], acc[oi*4+2], acc[oi*4+3]);
        *(float4*)(y + base + (size_t)o * HWC) = v;
    }
}

// ---------------- Kernel 2 fallback (tier3, NCHW) ----------------
__global__ __launch_bounds__(512, 2) void k2_sample_proj(
    const float* __restrict__ bev, const float* __restrict__ oa,
    const float* __restrict__ wt, float* __restrict__ y)
{
    __shared__ float S[2][16 * SROW2];
    int tid = threadIdx.x;
    int bidx = blockIdx.x;
    int b  = bidx >> 8;
    int p0 = ((bidx >> 4) & 15) * 16;
    int q0 = (bidx & 15) * 16;
    int pix = tid & 255;
    int gq = pix >> 4;
    int gp = pix & 15;
    int dgrp = tid >> 8;
    int swr = gp * 20 + gq;
    int wv = tid >> 6;
    int wvu = __builtin_amdgcn_readfirstlane(wv);
    int lane = tid & 63;
    int lp = lane >> 2;
    int q4 = (lane & 3) << 2;
    int soff = lp * 20 + q4;

    const float* ob = oa + (size_t)b * 12 * HWC + (size_t)(p0 + gp) * WW + (q0 + gq);
    unsigned pa[8]; float cw[16];
    #pragma unroll
    for (int k = 0; k < 4; k++) {
        float dx = ob[(size_t)(2*k)   * HWC];
        float dy = ob[(size_t)(2*k+1) * HWC];
        float a  = ob[(size_t)(8+k)   * HWC];
        float x  = fminf(fmaxf((float)(p0 + gp) + dx, 0.f), (float)(WW-1));
        float yv = fminf(fmaxf((float)(q0 + gq) + dy, 0.f), (float)(HH-1));
        float x0f = floorf(x); float y0f = floorf(yv);
        int x0 = (int)x0f; int y0 = (int)y0f;
        int x1 = min(x0 + 1, WW - 1); int y1 = min(y0 + 1, HH - 1);
        float wx = x - x0f; float wy = yv - y0f;
        pa[k*2+0] = (unsigned)(y0*WW + x0) | ((unsigned)(y0*WW + x1) << 16);
        pa[k*2+1] = (unsigned)(y1*WW + x0) | ((unsigned)(y1*WW + x1) << 16);
        cw[k*4+0] = a * (1.f - wx) * (1.f - wy);
        cw[k*4+1] = a * wx * (1.f - wy);
        cw[k*4+2] = a * (1.f - wx) * wy;
        cw[k*4+3] = a * wx * wy;
    }
    const float* bb = bev + (size_t)b * DD * HWC;
    float acc[64];
    #pragma unroll
    for (int t = 0; t < 64; t++) acc[t] = 0.f;
    #pragma unroll
    for (int dd = 0; dd < 8; dd++) {
        const float* pl = bb + (size_t)(dgrp*8 + dd) * HWC;
        float s = 0.f;
        #pragma unroll
        for (int t = 0; t < 8; t++) {
            unsigned a01 = pa[t];
            s = fmaf(cw[2*t],   pl[a01 & 0xffffu], s);
            s = fmaf(cw[2*t+1], pl[a01 >> 16], s);
        }
        S[0][(dgrp*8 + dd) * SROW2 + swr] = s;
    }
    __syncthreads();
    for (int c = 0; c < 8; c++) {
        int cur = c & 1;
        const float* Sc = &S[cur][0];
        float* Sn = &S[cur ^ 1][0];
        int d0 = c * 16;
        int d0n = d0 + 16;
        bool more = (c < 7);
        #pragma unroll
        for (int dl = 0; dl < 16; dl++) {
            if (dl < 8) {
                if (more) {
                    const float* pl = bb + (size_t)(d0n + dgrp*8 + dl) * HWC;
                    float s = 0.f;
                    #pragma unroll
                    for (int t = 0; t < 8; t++) {
                        unsigned a01 = pa[t];
                        s = fmaf(cw[2*t],   pl[a01 & 0xffffu], s);
                        s = fmaf(cw[2*t+1], pl[a01 >> 16], s);
                    }
                    Sn[(dgrp*8 + dl) * SROW2 + swr] = s;
                }
            }
            float4 sv = *(const float4*)(Sc + dl * SROW2 + soff);
            const float4* wq = (const float4*)(wt + (size_t)(d0 + dl) * 128 + wvu * 16);
            #pragma unroll
            for (int oi4 = 0; oi4 < 4; oi4++) {
                float4 w4 = wq[oi4];
                int ob4 = oi4 * 16;
                acc[ob4+ 0] = fmaf(w4.x, sv.x, acc[ob4+ 0]);
                acc[ob4+ 1] = fmaf(w4.x, sv.y, acc[ob4+ 1]);
                acc[ob4+ 2] = fmaf(w4.x, sv.z, acc[ob4+ 2]);
                acc[ob4+ 3] = fmaf(w4.x, sv.w, acc[ob4+ 3]);
                acc[ob4+ 4] = fmaf(w4.y, sv.x, acc[ob4+ 4]);
                acc[ob4+ 5] = fmaf(w4.y, sv.y, acc[ob4+ 5]);
                acc[ob4+ 6] = fmaf(w4.y, sv.z, acc[ob4+ 6]);
                acc[ob4+ 7] = fmaf(w4.y, sv.w, acc[ob4+ 7]);
                acc[ob4+ 8] = fmaf(w4.z, sv.x, acc[ob4+ 8]);
                acc[ob4+ 9] = fmaf(w4.z, sv.y, acc[ob4+ 9]);
                acc[ob4+10] = fmaf(w4.z, sv.z, acc[ob4+10]);
                acc[ob4+11] = fmaf(w4.z, sv.w, acc[ob4+11]);
                acc[ob4+12] = fmaf(w4.w, sv.x, acc[ob4+12]);
                acc[ob4+13] = fmaf(w4.w, sv.y, acc[ob4+13]);
                acc[ob4+14] = fmaf(w4.w, sv.z, acc[ob4+14]);
                acc[ob4+15] = fmaf(w4.w, sv.w, acc[ob4+15]);
            }
        }
        __syncthreads();
    }
    size_t base = (size_t)b * DD * HWC + (size_t)(p0 + lp) * WW + (q0 + q4);
    #pragma unroll
    for (int oi = 0; oi < 16; oi++) {
        int o = wv * 16 + oi;
        float4 v = make_float4(acc[oi*4+0], acc[oi*4+1], acc[oi*4+2], acc[oi*4+3]);
        *(float4*)(y + base + (size_t)o * HWC) = v;
    }
}

// ---------------- Kernel 3a/3b: BN stats (fallback tiers only) ----------------
__global__ __launch_bounds__(256) void k3_partial(
    const float* __restrict__ y, double* __restrict__ part)
{
    int blk = blockIdx.x;
    int o = blk >> 2; int sub = blk & 3; int b = sub >> 1; int half = sub & 1;
    const float4* pl = (const float4*)(y + ((size_t)b * DD + o) * HWC + half * (HWC/2));
    int tid = threadIdx.x;
    double s = 0.0, s2 = 0.0;
    for (int idx = tid; idx < HWC/8; idx += 256) {
        float4 v = pl[idx];
        s  += (double)v.x + (double)v.y + (double)v.z + (double)v.w;
        s2 += (double)v.x*v.x + (double)v.y*v.y + (double)v.z*v.z + (double)v.w*v.w;
    }
    __shared__ double ls[256], ls2[256];
    ls[tid] = s; ls2[tid] = s2;
    __syncthreads();
    for (int off = 128; off > 0; off >>= 1) {
        if (tid < off) { ls[tid] += ls[tid+off]; ls2[tid] += ls2[tid+off]; }
        __syncthreads();
    }
    if (tid == 0) { part[blk*2] = ls[0]; part[blk*2+1] = ls2[0]; }
}

__global__ __launch_bounds__(128) void k3_finalize(
    const double* __restrict__ part, const float* __restrict__ gamma,
    const float* __restrict__ beta, float* __restrict__ stats)
{
    int o = threadIdx.x;
    double s = 0.0, s2 = 0.0;
    #pragma unroll
    for (int j = 0; j < 4; j++) { s += part[(o*4+j)*2]; s2 += part[(o*4+j)*2+1]; }
    double N = (double)(BB * HWC);
    double mean = s / N;
    double var = s2 / N - mean * mean;
    double invs = 1.0 / sqrt(var + 1e-5);
    double g = (double)gamma[o];
    stats[o*2]   = (float)(g * invs);
    stats[o*2+1] = (float)((double)beta[o] - mean * g * invs);
}

// ---------------- Kernel 4: BN + exact GELU ----------------
__global__ __launch_bounds__(256) void k4_bn_gelu(
    float* __restrict__ y, const float* __restrict__ stats)
{
    size_t idx4 = (size_t)blockIdx.x * 256 + threadIdx.x;
    float4* p = (float4*)y;
    float4 v = p[idx4];
    int o = (int)((idx4 * 4) / HWC) % DD;
    float sc = stats[o*2], sh = stats[o*2+1];
    const float inv_sqrt2 = 0.70710678118654752f;
    float g0 = fmaf(v.x, sc, sh);
    float g1 = fmaf(v.y, sc, sh);
    float g2 = fmaf(v.z, sc, sh);
    float g3 = fmaf(v.w, sc, sh);
    v.x = 0.5f * g0 * (1.f + erff(g0 * inv_sqrt2));
    v.y = 0.5f * g1 * (1.f + erff(g1 * inv_sqrt2));
    v.z = 0.5f * g2 * (1.f + erff(g2 * inv_sqrt2));
    v.w = 0.5f * g3 * (1.f + erff(g3 * inv_sqrt2));
    p[idx4] = v;
}

extern "C" void kernel_launch(void* const* d_in, const int* in_sizes, int n_in,
                              void* d_out, int out_size, void* d_ws, size_t ws_size,
                              hipStream_t stream) {
    const float* bev   = (const float*)d_in[0];
    const float* offw  = (const float*)d_in[1];
    const float* offb  = (const float*)d_in[2];
    const float* wtw   = (const float*)d_in[3];
    const float* wtb   = (const float*)d_in[4];
    const float* projw = (const float*)d_in[5];
    const float* gamma = (const float*)d_in[6];
    const float* beta  = (const float*)d_in[7];
    float* out = (float*)d_out;
    float* wsf = (float*)d_ws;

    float* oa    = wsf + OA_OFF;
    float* wtT   = wsf + WTT_OFF;
    float* wp    = wsf + WP_OFF;
    float* stats = wsf + STATS_OFF;
    double* part = (double*)(wsf + PART_OFF);
    float* bevt  = wsf + BEVT_OFF;                 // tier2 f32
    ushort* bevtb = (ushort*)(wsf + BEVT_OFF);     // full3 bf16
    ushort* aggb = (ushort*)(wsf + AGG_OFF);
    ushort* wbf  = (ushort*)(wsf + WBF_OFF);
    ushort* wcb  = (ushort*)(wsf + WCB_OFF);
    float* part2 = wsf + PART2_OFF;                // aliases bevtb (written after last read)

    bool full3 = ws_size >= WS_NEED_FULL3;
    bool big   = ws_size >= WS_NEED_BEVT;

    hipLaunchKernelGGL(k0_prep, dim3(64), dim3(256), 0, stream,
                       projw, offw, wtw, wtT, wp);
    if (full3) {
        hipLaunchKernelGGL(k0b_wbf, dim3(64), dim3(256), 0, stream, projw, wbf);
        hipLaunchKernelGGL(k0c_wcb, dim3(72), dim3(256), 0, stream, offw, wtw, wcb);
        hipLaunchKernelGGL(k2t_bf, dim3(2048), dim3(256), 0, stream, bev, bevtb);
        hipLaunchKernelGGL(k1m_conv_mfma, dim3(2048), dim3(256), 0, stream,
                           bevtb, wcb, offb, wtb, oa);
        hipLaunchKernelGGL(k2a_sample_bf, dim3(2048), dim3(256), 0, stream,
                           bevtb, oa, aggb);
        hipLaunchKernelGGL(k2b_proj, dim3(2048), dim3(256), 0, stream,
                           aggb, wbf, out, part2);
        hipLaunchKernelGGL(k3b_finalize2, dim3(128), dim3(256), 0, stream,
                           part2, gamma, beta, stats);
    } else if (big) {
        hipLaunchKernelGGL(k2t_transpose, dim3(2048), dim3(256), 0, stream, bev, bevt);
        hipLaunchKernelGGL(k1_convs, dim3(BB*HH), dim3(256), 0, stream,
                           bev, wp, offb, wtb, oa);
        hipLaunchKernelGGL(k2_sample_proj_t, dim3(BB*256), dim3(512), 0, stream,
                           bevt, oa, wtT, out);
        hipLaunchKernelGGL(k3_partial, dim3(512), dim3(256), 0, stream, out, part);
        hipLaunchKernelGGL(k3_finalize, dim3(1), dim3(128), 0, stream,
                           part, gamma, beta, stats);
    } else {
        hipLaunchKernelGGL(k1_convs, dim3(BB*HH), dim3(256), 0, stream,
                           bev, wp, offb, wtb, oa);
        hipLaunchKernelGGL(k2_sample_proj, dim3(BB*256), dim3(512), 0, stream,
                           bev, oa, wtT, out);
        hipLaunchKernelGGL(k3_partial, dim3(512), dim3(256), 0, stream, out, part);
        hipLaunchKernelGGL(k3_finalize, dim3(1), dim3(128), 0, stream,
                           part, gamma, beta, stats);
    }
    hipLaunchKernelGGL(k4_bn_gelu, dim3((BB*DD*HWC)/1024), dim3(256), 0, stream,
                       out, stats);
}

// Round 10
// 202.837 us; speedup vs baseline: 10.1243x; 1.0073x over previous
//
#include <hip/hip_runtime.h>
#include <math.h>

#define BB 2
#define DD 128
#define HH 256
#define WW 256
#define KK 4
#define HWC (HH*WW)
#define SROW2 320   // d-slice stride in S (fused fallback kernels)

typedef unsigned int u32;
typedef unsigned short ushort;
typedef __attribute__((ext_vector_type(8))) short bf16x8;
typedef __attribute__((ext_vector_type(4))) float f32x4;

// ws float layout
#define OA_OFF    0
#define WTT_OFF   1572864
#define WP_OFF    1589248
#define STATS_OFF 1603072
#define PART_OFF  1603392
#define BEVT_OFF  1605440       // full3: bevtb bf16 (16.8M ushort = 8.4M floats); tier2: f32 bevt
#define PACC_OFF  18382656
#define AGG_OFF   PACC_OFF      // agg bf16: 16.8M ushort
#define WBF_OFF   26771264      // proj W bf16: 16384 ushort = 8192 floats
#define WCB_OFF   26779456      // conv W bf16 padded: 9*16*128 ushort = 9216 float-slots
// PART2 aliases BEVT region: k2b (writes part2) runs strictly after k2a's last bevtb read.
#define PART2_OFF BEVT_OFF
#define WS_NEED_BEVT  ((size_t)PACC_OFF * 4)
#define WS_NEED_FULL3 ((size_t)(WCB_OFF + 9216) * 4)

__device__ __forceinline__ u32 f2bf(float x) {
    u32 u = __builtin_bit_cast(u32, x);
    return (u + 0x7fffu + ((u >> 16) & 1u)) >> 16;
}
__device__ __forceinline__ u32 pkbf(float a, float b) {
    return f2bf(a) | (f2bf(b) << 16);
}
__device__ __forceinline__ float bflo(u32 d) { return __builtin_bit_cast(float, d << 16); }
__device__ __forceinline__ float bfhi(u32 d) { return __builtin_bit_cast(float, d & 0xffff0000u); }

// ---------------- Kernel 0: weight prep (wtT/wp for fallback tiers) ----------------
__global__ __launch_bounds__(256) void k0_prep(
    const float* __restrict__ projw, const float* __restrict__ offw,
    const float* __restrict__ wtw, float* __restrict__ wtT, float* __restrict__ wp)
{
    int idx = blockIdx.x * 256 + threadIdx.x;
    if (idx < 16384) {
        int d = idx >> 7, o = idx & 127;
        wtT[d * 128 + o] = projw[o * 128 + d];
    }
    if (idx < 13824) {
        int c = idx / 108; int r = idx % 108; int o = r / 9; int t = r % 9;
        wp[idx] = (o < 8) ? offw[(o*128 + c)*9 + t] : wtw[((o-8)*128 + c)*9 + t];
    }
}

// ---------------- Kernel 0b: proj weights -> bf16 [o][d] ----------------
__global__ __launch_bounds__(256) void k0b_wbf(
    const float* __restrict__ projw, ushort* __restrict__ wbf)
{
    int idx = blockIdx.x * 256 + threadIdx.x;
    if (idx < 16384) wbf[idx] = (ushort)f2bf(projw[idx]);
}

// ---------------- Kernel 0c: conv weights -> bf16 wcb[tap][16(o pad)][128(c)] ----------------
__global__ __launch_bounds__(256) void k0c_wcb(
    const float* __restrict__ offw, const float* __restrict__ wtw,
    ushort* __restrict__ wcb)
{
    int idx = blockIdx.x * 256 + threadIdx.x;
    if (idx < 18432) {
        int tap = idx >> 11;          // /2048
        int rem = idx & 2047;
        int oo = rem >> 7, c = rem & 127;
        float v = 0.f;
        if (oo < 8)       v = offw[(oo*128 + c)*9 + tap];
        else if (oo < 12) v = wtw[((oo-8)*128 + c)*9 + tap];
        wcb[idx] = (ushort)f2bf(v);
    }
}

// ---------------- Kernel Tb: NCHW f32 -> NHWC bf16 (bevtb[b][y][x][128]) ----------------
__global__ __launch_bounds__(256) void k2t_bf(
    const float* __restrict__ bev, ushort* __restrict__ bevtb)
{
    __shared__ float T[64 * 128];   // 32 KB, XOR-swizzled
    int tid = threadIdx.x;
    int bidx = blockIdx.x;
    int b = bidx >> 10;
    int rem = bidx & 1023;
    int yrow = rem >> 2;
    int x0 = (rem & 3) << 6;

    const float* src = bev + ((size_t)b * DD) * HWC + (size_t)yrow * WW + x0;
    #pragma unroll 4
    for (int k = 0; k < 32; k++) {
        int flat = k * 256 + tid;
        int d = flat >> 6, xl = flat & 63;
        float v = src[(size_t)d * HWC + xl];
        T[xl * 128 + (((d >> 2) ^ (xl & 31)) << 2) + (d & 3)] = v;
    }
    __syncthreads();
    ushort* dst = bevtb + (((size_t)b * HH + yrow) * WW + x0) * 128;
    #pragma unroll 4
    for (int k = 0; k < 8; k++) {
        int flat = k * 256 + tid;
        int d4 = flat & 31, xl = (flat >> 5) & 63;
        float4 v = *(const float4*)&T[xl * 128 + ((d4 ^ (xl & 31)) << 2)];
        uint2 pk;
        pk.x = pkbf(v.x, v.y);
        pk.y = pkbf(v.z, v.w);
        *(uint2*)(dst + (size_t)xl * 128 + (d4 << 2)) = pk;
    }
}

// ---------------- Kernel 1m: 3x3 convs as implicit-GEMM MFMA ----------------
// R9 post-mortem: serial {load->mfma} chain left 1 outstanding load/wave (VGPR=16!)
// -> latency-bound at 70us.  Fix: prefetch ALL 36 B fragments (9 taps x 4 k) into
// registers up front (36 loads in flight), then run the 36 MFMAs.  OOB lanes load
// pix 0 unconditionally and cndmask to zero (no exec divergence).  VGPR ~160-180
// (3 waves/SIMD) is the intended trade.  XCD swizzle: lin=(wgid&7)*256+wgid>>3 ->
// each XCD owns 64 contiguous i-rows (~4.3MB ~ its L2) -> halo refetch drops.
__global__ __launch_bounds__(256) void k1m_conv_mfma(
    const ushort* __restrict__ bevtb, const ushort* __restrict__ wcb,
    const float* __restrict__ offb, const float* __restrict__ wtb,
    float* __restrict__ oa)
{
    int tid = threadIdx.x;
    int wv = tid >> 6;
    int l = tid & 63;
    int lm = l & 15, lk = l >> 4;
    int wgid = blockIdx.x;
    int lin = (wgid & 7) * 256 + (wgid >> 3);   // bijective XCD-contiguous remap
    int b = lin >> 10;
    int i = (lin >> 2) & 255;
    int jt = lin & 3;
    int j = jt * 64 + wv * 16 + lm;

    const ushort* bb = bevtb + (size_t)b * HWC * 128;

    // ---- prefetch all 36 B fragments ----
    bf16x8 bfr[9][4];
    #pragma unroll
    for (int dy = 0; dy < 3; dy++) {
        int yy = i + dy - 1;
        bool yok = ((unsigned)yy < HH);
        #pragma unroll
        for (int dx = 0; dx < 3; dx++) {
            int xx = j + dx - 1;
            bool ok = yok && ((unsigned)xx < WW);
            int pix = ok ? (yy * WW + xx) : 0;
            const ushort* bp = bb + (size_t)pix * 128 + lk * 8;
            #pragma unroll
            for (int kk = 0; kk < 4; kk++) {
                bf16x8 v = *(const bf16x8*)(bp + kk * 32);
                bfr[dy*3 + dx][kk] = ok ? v : (bf16x8)0;
            }
        }
    }

    // ---- 36 MFMAs; A (wcb, 18KB) is L1/L2-hot ----
    f32x4 acc = (f32x4)(0.f);
    #pragma unroll
    for (int t = 0; t < 9; t++) {
        const ushort* ap = wcb + (size_t)(t * 16 + lm) * 128 + lk * 8;
        #pragma unroll
        for (int kk = 0; kk < 4; kk++) {
            bf16x8 afr = *(const bf16x8*)(ap + kk * 32);
            acc = __builtin_amdgcn_mfma_f32_16x16x32_bf16(afr, bfr[t][kk], acc, 0, 0, 0);
        }
    }

    float v[4];
    #pragma unroll
    for (int r = 0; r < 4; r++) v[r] = acc[r];

    if (lk < 2) {
        #pragma unroll
        for (int r = 0; r < 4; r++) v[r] += offb[lk*4 + r];   // OFFSET_SCALE = 1.0
    } else if (lk == 2) {
        float l4[4];
        #pragma unroll
        for (int r = 0; r < 4; r++) l4[r] = v[r] + wtb[r];
        float m = fmaxf(fmaxf(l4[0], l4[1]), fmaxf(l4[2], l4[3]));
        float e[4]; float se = 0.f;
        #pragma unroll
        for (int r = 0; r < 4; r++) { e[r] = expf(l4[r] - m); se += e[r]; }
        float inv = 1.f / se;
        #pragma unroll
        for (int r = 0; r < 4; r++) v[r] = e[r] * inv;
    }
    if (lk < 3) {
        size_t basep = (size_t)b * 12 * HWC + (size_t)i * WW + j;
        #pragma unroll
        for (int r = 0; r < 4; r++)
            oa[basep + (size_t)(lk*4 + r) * HWC] = v[r];
    }
}

// ---------------- Kernel 1 (tier2 fallback): full 128-channel conv ----------------
__global__ __launch_bounds__(256) void k1_convs(
    const float* __restrict__ bev, const float* __restrict__ wp,
    const float* __restrict__ offb, const float* __restrict__ wtb,
    float* __restrict__ oa)
{
    __shared__ float rows[2][3][260];
    int tid = threadIdx.x;
    int p = blockIdx.x;
    int b = p / HH; int i = p % HH; int j = tid;
    const float* bb = bev + (size_t)b * DD * HWC;

    if (tid < 12) { int bf = tid / 6, r = tid % 6; rows[bf][r >> 1][(r & 1) ? 257 : 0] = 0.f; }
    #pragma unroll
    for (int l = 0; l < 3; l++) {
        int yy = i + l - 1;
        rows[0][l][1 + tid] = ((unsigned)yy < HH) ? bb[yy * WW + tid] : 0.f;
    }
    __syncthreads();

    float acc[12];
    #pragma unroll
    for (int o = 0; o < 12; o++) acc[o] = 0.f;

    for (int c = 0; c < 128; c++) {
        int cb = c & 1, nb = cb ^ 1;
        float rv[3];
        if (c < 127) {
            const float* pln = bb + (size_t)(c + 1) * HWC;
            #pragma unroll
            for (int l = 0; l < 3; l++) {
                int yy = i + l - 1;
                rv[l] = ((unsigned)yy < HH) ? pln[yy * WW + tid] : 0.f;
            }
        }
        float v[9];
        #pragma unroll
        for (int dy = 0; dy < 3; dy++)
            #pragma unroll
            for (int dx = 0; dx < 3; dx++)
                v[dy*3 + dx] = rows[cb][dy][tid + dx];
        const float* wc = wp + c * 108;
        #pragma unroll
        for (int o = 0; o < 12; o++) {
            float s = acc[o];
            #pragma unroll
            for (int t = 0; t < 9; t++) s = fmaf(wc[o*9 + t], v[t], s);
            acc[o] = s;
        }
        if (c < 127) {
            #pragma unroll
            for (int l = 0; l < 3; l++) rows[nb][l][1 + tid] = rv[l];
        }
        __syncthreads();
    }

    float outv[12];
    #pragma unroll
    for (int o = 0; o < 8; o++) outv[o] = acc[o] + offb[o];
    float l4[4];
    #pragma unroll
    for (int k = 0; k < 4; k++) l4[k] = acc[8+k] + wtb[k];
    float m = fmaxf(fmaxf(l4[0], l4[1]), fmaxf(l4[2], l4[3]));
    float e[4]; float se = 0.f;
    #pragma unroll
    for (int k = 0; k < 4; k++) { e[k] = expf(l4[k] - m); se += e[k]; }
    float inv = 1.f / se;
    #pragma unroll
    for (int k = 0; k < 4; k++) outv[8+k] = e[k] * inv;

    size_t basep = (size_t)b * 12 * HWC + (size_t)i * WW + j;
    #pragma unroll
    for (int o = 0; o < 12; o++) oa[basep + (size_t)o * HWC] = outv[o];
}

// ---------------- Kernel T (tier2): NCHW -> NHWC f32 transpose ----------------
__global__ __launch_bounds__(256) void k2t_transpose(
    const float* __restrict__ bev, float* __restrict__ bevt)
{
    __shared__ float T[64 * 128];
    int tid = threadIdx.x;
    int bidx = blockIdx.x;
    int b = bidx >> 10;
    int rem = bidx & 1023;
    int yrow = rem >> 2;
    int x0 = (rem & 3) << 6;

    const float* src = bev + ((size_t)b * DD) * HWC + (size_t)yrow * WW + x0;
    #pragma unroll 4
    for (int k = 0; k < 32; k++) {
        int flat = k * 256 + tid;
        int d = flat >> 6, xl = flat & 63;
        float v = src[(size_t)d * HWC + xl];
        T[xl * 128 + (((d >> 2) ^ (xl & 31)) << 2) + (d & 3)] = v;
    }
    __syncthreads();
    float* dst = bevt + (((size_t)b * HH + yrow) * WW + x0) * 128;
    #pragma unroll 4
    for (int k = 0; k < 8; k++) {
        int flat = k * 256 + tid;
        int d4 = flat & 31, xl = (flat >> 5) & 63;
        float4 v = *(const float4*)&T[xl * 128 + ((d4 ^ (xl & 31)) << 2)];
        *(float4*)(dst + (size_t)xl * 128 + (d4 << 2)) = v;
    }
}

// ---------------- Kernel 2a (bf16): deformable sample + K-aggregate ----------------
__global__ __launch_bounds__(256) void k2a_sample_bf(
    const ushort* __restrict__ bevtb, const float* __restrict__ oa,
    ushort* __restrict__ aggb)
{
    int tid = threadIdx.x;
    int q4 = tid & 3;
    int pl = (tid >> 2) & 15;
    int ql = tid >> 6;
    int bidx = blockIdx.x;
    int b = bidx >> 10;
    int rem = bidx & 1023;
    int pt = rem >> 6;
    int qt = rem & 63;
    int p = pt * 16 + pl;
    int q = qt * 4 + ql;

    // offsets / attention (transpose quirk: x <- p+dx, y <- q+dy)
    const float* ob = oa + (size_t)b * 12 * HWC + (size_t)p * WW + q;
    unsigned pa[8]; float cw[16];
    #pragma unroll
    for (int k = 0; k < 4; k++) {
        float dx = ob[(size_t)(2*k)   * HWC];
        float dy = ob[(size_t)(2*k+1) * HWC];
        float a  = ob[(size_t)(8+k)   * HWC];
        float x  = fminf(fmaxf((float)p + dx, 0.f), (float)(WW-1));
        float yv = fminf(fmaxf((float)q + dy, 0.f), (float)(HH-1));
        float x0f = floorf(x); float y0f = floorf(yv);
        int x0 = (int)x0f; int y0 = (int)y0f;
        int x1 = min(x0 + 1, WW - 1); int y1 = min(y0 + 1, HH - 1);
        float wx = x - x0f; float wy = yv - y0f;
        pa[k*2+0] = (unsigned)(y0*WW + x0) | ((unsigned)(y0*WW + x1) << 16);
        pa[k*2+1] = (unsigned)(y1*WW + x0) | ((unsigned)(y1*WW + x1) << 16);
        cw[k*4+0] = a * (1.f - wx) * (1.f - wy);
        cw[k*4+1] = a * wx * (1.f - wy);
        cw[k*4+2] = a * (1.f - wx) * wy;
        cw[k*4+3] = a * wx * wy;
    }

    const ushort* bt = bevtb + (size_t)b * HWC * 128 + q4 * 8;

    float s[4][8];
    #pragma unroll
    for (int c = 0; c < 4; c++)
        #pragma unroll
        for (int e = 0; e < 8; e++) s[c][e] = 0.f;

    #pragma unroll
    for (int t = 0; t < 16; t++) {
        unsigned a01 = pa[t >> 1];
        unsigned pix = (t & 1) ? (a01 >> 16) : (a01 & 0xffffu);
        const ushort* tp = bt + ((size_t)pix << 7);
        float w = cw[t];
        #pragma unroll
        for (int c = 0; c < 4; c++) {
            uint4 v = *(const uint4*)(tp + c * 32);
            s[c][0] = fmaf(w, bflo(v.x), s[c][0]);
            s[c][1] = fmaf(w, bfhi(v.x), s[c][1]);
            s[c][2] = fmaf(w, bflo(v.y), s[c][2]);
            s[c][3] = fmaf(w, bfhi(v.y), s[c][3]);
            s[c][4] = fmaf(w, bflo(v.z), s[c][4]);
            s[c][5] = fmaf(w, bfhi(v.z), s[c][5]);
            s[c][6] = fmaf(w, bflo(v.w), s[c][6]);
            s[c][7] = fmaf(w, bfhi(v.w), s[c][7]);
        }
    }

    ushort* outp = aggb + ((size_t)b * HWC + (size_t)p * WW + q) * 128 + q4 * 8;
    #pragma unroll
    for (int c = 0; c < 4; c++) {
        uint4 pk;
        pk.x = pkbf(s[c][0], s[c][1]);
        pk.y = pkbf(s[c][2], s[c][3]);
        pk.z = pkbf(s[c][4], s[c][5]);
        pk.w = pkbf(s[c][6], s[c][7]);
        *(uint4*)(outp + c * 32) = pk;
    }
}

// ---------------- Kernel 2b: 1x1 proj as bf16 MFMA GEMM + fused BN partial stats ----------------
__global__ __launch_bounds__(256) void k2b_proj(
    const ushort* __restrict__ aggb, const ushort* __restrict__ wbf,
    float* __restrict__ y, float* __restrict__ part2)
{
    int tid = threadIdx.x;
    int wv = tid >> 6;
    int l = tid & 63;
    int lm = l & 15, lk = l >> 4;
    int bidx = blockIdx.x;
    int b = bidx >> 10;
    int pix0 = (bidx & 1023) << 6;
    int o0 = wv << 5;

    bf16x8 a[2][4];
    const ushort* wbase = wbf + (size_t)(o0 + lm) * 128 + lk * 8;
    #pragma unroll
    for (int ot = 0; ot < 2; ot++)
        #pragma unroll
        for (int kk = 0; kk < 4; kk++)
            a[ot][kk] = *(const bf16x8*)(wbase + ot * 16 * 128 + kk * 32);

    f32x4 acc[2][4];
    #pragma unroll
    for (int ot = 0; ot < 2; ot++)
        #pragma unroll
        for (int nt = 0; nt < 4; nt++)
            acc[ot][nt] = (f32x4)(0.f);

    const ushort* bbase = aggb + ((size_t)b * HWC + pix0 + lm) * 128 + lk * 8;
    #pragma unroll
    for (int nt = 0; nt < 4; nt++) {
        bf16x8 bfr[4];
        #pragma unroll
        for (int kk = 0; kk < 4; kk++)
            bfr[kk] = *(const bf16x8*)(bbase + nt * 16 * 128 + kk * 32);
        #pragma unroll
        for (int ot = 0; ot < 2; ot++)
            #pragma unroll
            for (int kk = 0; kk < 4; kk++)
                acc[ot][nt] = __builtin_amdgcn_mfma_f32_16x16x32_bf16(
                    a[ot][kk], bfr[kk], acc[ot][nt], 0, 0, 0);
    }

    #pragma unroll
    for (int ot = 0; ot < 2; ot++)
        #pragma unroll
        for (int nt = 0; nt < 4; nt++)
            #pragma unroll
            for (int r = 0; r < 4; r++)
                y[((size_t)b * DD + o0 + ot * 16 + lk * 4 + r) * HWC + pix0 + nt * 16 + lm]
                    = acc[ot][nt][r];

    float sm[2][4], sq[2][4];
    #pragma unroll
    for (int ot = 0; ot < 2; ot++)
        #pragma unroll
        for (int r = 0; r < 4; r++) { sm[ot][r] = 0.f; sq[ot][r] = 0.f; }
    #pragma unroll
    for (int ot = 0; ot < 2; ot++)
        #pragma unroll
        for (int nt = 0; nt < 4; nt++)
            #pragma unroll
            for (int r = 0; r < 4; r++) {
                float v = acc[ot][nt][r];
                sm[ot][r] += v;
                sq[ot][r] = fmaf(v, v, sq[ot][r]);
            }
    #pragma unroll
    for (int m = 1; m < 16; m <<= 1) {
        #pragma unroll
        for (int ot = 0; ot < 2; ot++)
            #pragma unroll
            for (int r = 0; r < 4; r++) {
                sm[ot][r] += __shfl_xor(sm[ot][r], m);
                sq[ot][r] += __shfl_xor(sq[ot][r], m);
            }
    }
    if (lm == 0) {
        #pragma unroll
        for (int ot = 0; ot < 2; ot++)
            #pragma unroll
            for (int r = 0; r < 4; r++) {
                int o = o0 + ot * 16 + lk * 4 + r;
                part2[(size_t)o * 2048 + bidx] = sm[ot][r];
                part2[(size_t)128 * 2048 + (size_t)o * 2048 + bidx] = sq[ot][r];
            }
    }
}

// ---------------- Kernel 3b': finalize BN from k2b block partials ----------------
__global__ __launch_bounds__(256) void k3b_finalize2(
    const float* __restrict__ part2, const float* __restrict__ gamma,
    const float* __restrict__ beta, float* __restrict__ stats)
{
    int o = blockIdx.x; int tid = threadIdx.x;
    const float* ps = part2 + (size_t)o * 2048;
    const float* pq = part2 + (size_t)128 * 2048 + (size_t)o * 2048;
    double s = 0.0, s2 = 0.0;
    for (int i = tid; i < 2048; i += 256) { s += (double)ps[i]; s2 += (double)pq[i]; }
    __shared__ double ls[256], ls2[256];
    ls[tid] = s; ls2[tid] = s2;
    __syncthreads();
    for (int off = 128; off > 0; off >>= 1) {
        if (tid < off) { ls[tid] += ls[tid+off]; ls2[tid] += ls2[tid+off]; }
        __syncthreads();
    }
    if (tid == 0) {
        double N = (double)(BB * HWC);
        double mean = ls[0] / N;
        double var = ls2[0] / N - mean * mean;
        double invs = 1.0 / sqrt(var + 1e-5);
        double g = (double)gamma[o];
        stats[o*2]   = (float)(g * invs);
        stats[o*2+1] = (float)((double)beta[o] - mean * g * invs);
    }
}

// ---------------- Kernel 2 fused fallback (tier2, NHWC f32) ----------------
__global__ __launch_bounds__(512, 2) void k2_sample_proj_t(
    const float* __restrict__ bevt, const float* __restrict__ oa,
    const float* __restrict__ wt, float* __restrict__ y)
{
    __shared__ float S[2][16 * SROW2];

    int tid = threadIdx.x;
    int bidx = blockIdx.x;
    int b  = bidx >> 8;
    int p0 = ((bidx >> 4) & 15) * 16;
    int q0 = (bidx & 15) * 16;

    int gpix = tid >> 1;
    int gp = gpix & 15;
    int gq = gpix >> 4;
    int dgrp = tid & 1;
    int swr = gp * 20 + gq;

    int wv = tid >> 6;
    int wvu = __builtin_amdgcn_readfirstlane(wv);
    int lane = tid & 63;
    int lp = lane >> 2;
    int q4 = (lane & 3) << 2;
    int soff = lp * 20 + q4;

    const float* ob = oa + (size_t)b * 12 * HWC + (size_t)(p0 + gp) * WW + (q0 + gq);
    unsigned pa[8]; float cw[16];
    #pragma unroll
    for (int k = 0; k < 4; k++) {
        float dx = ob[(size_t)(2*k)   * HWC];
        float dy = ob[(size_t)(2*k+1) * HWC];
        float a  = ob[(size_t)(8+k)   * HWC];
        float x  = fminf(fmaxf((float)(p0 + gp) + dx, 0.f), (float)(WW-1));
        float yv = fminf(fmaxf((float)(q0 + gq) + dy, 0.f), (float)(HH-1));
        float x0f = floorf(x); float y0f = floorf(yv);
        int x0 = (int)x0f; int y0 = (int)y0f;
        int x1 = min(x0 + 1, WW - 1); int y1 = min(y0 + 1, HH - 1);
        float wx = x - x0f; float wy = yv - y0f;
        pa[k*2+0] = (unsigned)(y0*WW + x0) | ((unsigned)(y0*WW + x1) << 16);
        pa[k*2+1] = (unsigned)(y1*WW + x0) | ((unsigned)(y1*WW + x1) << 16);
        cw[k*4+0] = a * (1.f - wx) * (1.f - wy);
        cw[k*4+1] = a * wx * (1.f - wy);
        cw[k*4+2] = a * (1.f - wx) * wy;
        cw[k*4+3] = a * wx * wy;
    }

    const float* bt = bevt + (size_t)b * HWC * 128 + dgrp * 8;

    float acc[64];
    #pragma unroll
    for (int t = 0; t < 64; t++) acc[t] = 0.f;

    {
        float4 s0 = make_float4(0,0,0,0), s1 = make_float4(0,0,0,0);
        #pragma unroll
        for (int t = 0; t < 16; t++) {
            unsigned pix = (t & 1) ? (pa[t >> 1] >> 16) : (pa[t >> 1] & 0xffffu);
            const float4* tp = (const float4*)(bt + ((size_t)pix << 7));
            float4 va = tp[0], vb = tp[1];
            float c = cw[t];
            s0.x = fmaf(c, va.x, s0.x); s0.y = fmaf(c, va.y, s0.y);
            s0.z = fmaf(c, va.z, s0.z); s0.w = fmaf(c, va.w, s0.w);
            s1.x = fmaf(c, vb.x, s1.x); s1.y = fmaf(c, vb.y, s1.y);
            s1.z = fmaf(c, vb.z, s1.z); s1.w = fmaf(c, vb.w, s1.w);
        }
        int r = dgrp * 8;
        S[0][(r+0)*SROW2 + swr] = s0.x; S[0][(r+1)*SROW2 + swr] = s0.y;
        S[0][(r+2)*SROW2 + swr] = s0.z; S[0][(r+3)*SROW2 + swr] = s0.w;
        S[0][(r+4)*SROW2 + swr] = s1.x; S[0][(r+5)*SROW2 + swr] = s1.y;
        S[0][(r+6)*SROW2 + swr] = s1.z; S[0][(r+7)*SROW2 + swr] = s1.w;
    }
    __syncthreads();

    for (int c = 0; c < 8; c++) {
        int cur = c & 1;
        const float* Sc = &S[cur][0];
        float* Sn = &S[cur ^ 1][0];
        int d0 = c * 16;
        int dn = d0 + 16;
        bool more = (c < 7);

        float4 g0 = make_float4(0,0,0,0), g1 = make_float4(0,0,0,0);
        float4 pf0, pf1;
        if (more) {
            unsigned pix = pa[0] & 0xffffu;
            const float4* tp = (const float4*)(bt + ((size_t)pix << 7) + dn);
            pf0 = tp[0]; pf1 = tp[1];
        }

        #pragma unroll
        for (int dl = 0; dl < 16; dl++) {
            float4 cur0 = pf0, cur1 = pf1;
            if (more && dl < 15) {
                int t = dl + 1;
                unsigned pix = (t & 1) ? (pa[t >> 1] >> 16) : (pa[t >> 1] & 0xffffu);
                const float4* tp = (const float4*)(bt + ((size_t)pix << 7) + dn);
                pf0 = tp[0]; pf1 = tp[1];
            }

            float4 sv = *(const float4*)(Sc + dl * SROW2 + soff);
            const float4* wq = (const float4*)(wt + (size_t)(d0 + dl) * 128 + wvu * 16);
            #pragma unroll
            for (int oi4 = 0; oi4 < 4; oi4++) {
                float4 w4 = wq[oi4];
                int ob4 = oi4 * 16;
                acc[ob4+ 0] = fmaf(w4.x, sv.x, acc[ob4+ 0]);
                acc[ob4+ 1] = fmaf(w4.x, sv.y, acc[ob4+ 1]);
                acc[ob4+ 2] = fmaf(w4.x, sv.z, acc[ob4+ 2]);
                acc[ob4+ 3] = fmaf(w4.x, sv.w, acc[ob4+ 3]);
                acc[ob4+ 4] = fmaf(w4.y, sv.x, acc[ob4+ 4]);
                acc[ob4+ 5] = fmaf(w4.y, sv.y, acc[ob4+ 5]);
                acc[ob4+ 6] = fmaf(w4.y, sv.z, acc[ob4+ 6]);
                acc[ob4+ 7] = fmaf(w4.y, sv.w, acc[ob4+ 7]);
                acc[ob4+ 8] = fmaf(w4.z, sv.x, acc[ob4+ 8]);
                acc[ob4+ 9] = fmaf(w4.z, sv.y, acc[ob4+ 9]);
                acc[ob4+10] = fmaf(w4.z, sv.z, acc[ob4+10]);
                acc[ob4+11] = fmaf(w4.z, sv.w, acc[ob4+11]);
                acc[ob4+12] = fmaf(w4.w, sv.x, acc[ob4+12]);
                acc[ob4+13] = fmaf(w4.w, sv.y, acc[ob4+13]);
                acc[ob4+14] = fmaf(w4.w, sv.z, acc[ob4+14]);
                acc[ob4+15] = fmaf(w4.w, sv.w, acc[ob4+15]);
            }

            if (more) {
                float cwt = cw[dl];
                g0.x = fmaf(cwt, cur0.x, g0.x); g0.y = fmaf(cwt, cur0.y, g0.y);
                g0.z = fmaf(cwt, cur0.z, g0.z); g0.w = fmaf(cwt, cur0.w, g0.w);
                g1.x = fmaf(cwt, cur1.x, g1.x); g1.y = fmaf(cwt, cur1.y, g1.y);
                g1.z = fmaf(cwt, cur1.z, g1.z); g1.w = fmaf(cwt, cur1.w, g1.w);
            }
        }

        if (more) {
            int r = dgrp * 8;
            Sn[(r+0)*SROW2 + swr] = g0.x; Sn[(r+1)*SROW2 + swr] = g0.y;
            Sn[(r+2)*SROW2 + swr] = g0.z; Sn[(r+3)*SROW2 + swr] = g0.w;
            Sn[(r+4)*SROW2 + swr] = g1.x; Sn[(r+5)*SROW2 + swr] = g1.y;
            Sn[(r+6)*SROW2 + swr] = g1.z; Sn[(r+7)*SROW2 + swr] = g1.w;
        }
        __syncthreads();
    }

    size_t base = (size_t)b * DD * HWC + (size_t)(p0 + lp) * WW + (q0 + q4);
    #pragma unroll
    for (int oi = 0; oi < 16; oi++) {
        int o = wv * 16 + oi;
        float4 v = make_float4(acc[oi*4+0], acc[oi*4+1], acc[oi*4+2], acc[oi*4+3]);
        *(float4*)(y + base + (size_t)o * HWC) = v;
    }
}

// ---------------- Kernel 2 fallback (tier3, NCHW) ----------------
__global__ __launch_bounds__(512, 2) void k2_sample_proj(
    const float* __restrict__ bev, const float* __restrict__ oa,
    const float* __restrict__ wt, float* __restrict__ y)
{
    __shared__ float S[2][16 * SROW2];
    int tid = threadIdx.x;
    int bidx = blockIdx.x;
    int b  = bidx >> 8;
    int p0 = ((bidx >> 4) & 15) * 16;
    int q0 = (bidx & 15) * 16;
    int pix = tid & 255;
    int gq = pix >> 4;
    int gp = pix & 15;
    int dgrp = tid >> 8;
    int swr = gp * 20 + gq;
    int wv = tid >> 6;
    int wvu = __builtin_amdgcn_readfirstlane(wv);
    int lane = tid & 63;
    int lp = lane >> 2;
    int q4 = (lane & 3) << 2;
    int soff = lp * 20 + q4;

    const float* ob = oa + (size_t)b * 12 * HWC + (size_t)(p0 + gp) * WW + (q0 + gq);
    unsigned pa[8]; float cw[16];
    #pragma unroll
    for (int k = 0; k < 4; k++) {
        float dx = ob[(size_t)(2*k)   * HWC];
        float dy = ob[(size_t)(2*k+1) * HWC];
        float a  = ob[(size_t)(8+k)   * HWC];
        float x  = fminf(fmaxf((float)(p0 + gp) + dx, 0.f), (float)(WW-1));
        float yv = fminf(fmaxf((float)(q0 + gq) + dy, 0.f), (float)(HH-1));
        float x0f = floorf(x); float y0f = floorf(yv);
        int x0 = (int)x0f; int y0 = (int)y0f;
        int x1 = min(x0 + 1, WW - 1); int y1 = min(y0 + 1, HH - 1);
        float wx = x - x0f; float wy = yv - y0f;
        pa[k*2+0] = (unsigned)(y0*WW + x0) | ((unsigned)(y0*WW + x1) << 16);
        pa[k*2+1] = (unsigned)(y1*WW + x0) | ((unsigned)(y1*WW + x1) << 16);
        cw[k*4+0] = a * (1.f - wx) * (1.f - wy);
        cw[k*4+1] = a * wx * (1.f - wy);
        cw[k*4+2] = a * (1.f - wx) * wy;
        cw[k*4+3] = a * wx * wy;
    }
    const float* bb = bev + (size_t)b * DD * HWC;
    float acc[64];
    #pragma unroll
    for (int t = 0; t < 64; t++) acc[t] = 0.f;
    #pragma unroll
    for (int dd = 0; dd < 8; dd++) {
        const float* pl = bb + (size_t)(dgrp*8 + dd) * HWC;
        float s = 0.f;
        #pragma unroll
        for (int t = 0; t < 8; t++) {
            unsigned a01 = pa[t];
            s = fmaf(cw[2*t],   pl[a01 & 0xffffu], s);
            s = fmaf(cw[2*t+1], pl[a01 >> 16], s);
        }
        S[0][(dgrp*8 + dd) * SROW2 + swr] = s;
    }
    __syncthreads();
    for (int c = 0; c < 8; c++) {
        int cur = c & 1;
        const float* Sc = &S[cur][0];
        float* Sn = &S[cur ^ 1][0];
        int d0 = c * 16;
        int d0n = d0 + 16;
        bool more = (c < 7);
        #pragma unroll
        for (int dl = 0; dl < 16; dl++) {
            if (dl < 8) {
                if (more) {
                    const float* pl = bb + (size_t)(d0n + dgrp*8 + dl) * HWC;
                    float s = 0.f;
                    #pragma unroll
                    for (int t = 0; t < 8; t++) {
                        unsigned a01 = pa[t];
                        s = fmaf(cw[2*t],   pl[a01 & 0xffffu], s);
                        s = fmaf(cw[2*t+1], pl[a01 >> 16], s);
                    }
                    Sn[(dgrp*8 + dl) * SROW2 + swr] = s;
                }
            }
            float4 sv = *(const float4*)(Sc + dl * SROW2 + soff);
            const float4* wq = (const float4*)(wt + (size_t)(d0 + dl) * 128 + wvu * 16);
            #pragma unroll
            for (int oi4 = 0; oi4 < 4; oi4++) {
                float4 w4 = wq[oi4];
                int ob4 = oi4 * 16;
                acc[ob4+ 0] = fmaf(w4.x, sv.x, acc[ob4+ 0]);
                acc[ob4+ 1] = fmaf(w4.x, sv.y, acc[ob4+ 1]);
                acc[ob4+ 2] = fmaf(w4.x, sv.z, acc[ob4+ 2]);
                acc[ob4+ 3] = fmaf(w4.x, sv.w, acc[ob4+ 3]);
                acc[ob4+ 4] = fmaf(w4.y, sv.x, acc[ob4+ 4]);
                acc[ob4+ 5] = fmaf(w4.y, sv.y, acc[ob4+ 5]);
                acc[ob4+ 6] = fmaf(w4.y, sv.z, acc[ob4+ 6]);
                acc[ob4+ 7] = fmaf(w4.y, sv.w, acc[ob4+ 7]);
                acc[ob4+ 8] = fmaf(w4.z, sv.x, acc[ob4+ 8]);
                acc[ob4+ 9] = fmaf(w4.z, sv.y, acc[ob4+ 9]);
                acc[ob4+10] = fmaf(w4.z, sv.z, acc[ob4+10]);
                acc[ob4+11] = fmaf(w4.z, sv.w, acc[ob4+11]);
                acc[ob4+12] = fmaf(w4.w, sv.x, acc[ob4+12]);
                acc[ob4+13] = fmaf(w4.w, sv.y, acc[ob4+13]);
                acc[ob4+14] = fmaf(w4.w, sv.z, acc[ob4+14]);
                acc[ob4+15] = fmaf(w4.w, sv.w, acc[ob4+15]);
            }
        }
        __syncthreads();
    }
    size_t base = (size_t)b * DD * HWC + (size_t)(p0 + lp) * WW + (q0 + q4);
    #pragma unroll
    for (int oi = 0; oi < 16; oi++) {
        int o = wv * 16 + oi;
        float4 v = make_float4(acc[oi*4+0], acc[oi*4+1], acc[oi*4+2], acc[oi*4+3]);
        *(float4*)(y + base + (size_t)o * HWC) = v;
    }
}

// ---------------- Kernel 3a/3b: BN stats (fallback tiers only) ----------------
__global__ __launch_bounds__(256) void k3_partial(
    const float* __restrict__ y, double* __restrict__ part)
{
    int blk = blockIdx.x;
    int o = blk >> 2; int sub = blk & 3; int b = sub >> 1; int half = sub & 1;
    const float4* pl = (const float4*)(y + ((size_t)b * DD + o) * HWC + half * (HWC/2));
    int tid = threadIdx.x;
    double s = 0.0, s2 = 0.0;
    for (int idx = tid; idx < HWC/8; idx += 256) {
        float4 v = pl[idx];
        s  += (double)v.x + (double)v.y + (double)v.z + (double)v.w;
        s2 += (double)v.x*v.x + (double)v.y*v.y + (double)v.z*v.z + (double)v.w*v.w;
    }
    __shared__ double ls[256], ls2[256];
    ls[tid] = s; ls2[tid] = s2;
    __syncthreads();
    for (int off = 128; off > 0; off >>= 1) {
        if (tid < off) { ls[tid] += ls[tid+off]; ls2[tid] += ls2[tid+off]; }
        __syncthreads();
    }
    if (tid == 0) { part[blk*2] = ls[0]; part[blk*2+1] = ls2[0]; }
}

__global__ __launch_bounds__(128) void k3_finalize(
    const double* __restrict__ part, const float* __restrict__ gamma,
    const float* __restrict__ beta, float* __restrict__ stats)
{
    int o = threadIdx.x;
    double s = 0.0, s2 = 0.0;
    #pragma unroll
    for (int j = 0; j < 4; j++) { s += part[(o*4+j)*2]; s2 += part[(o*4+j)*2+1]; }
    double N = (double)(BB * HWC);
    double mean = s / N;
    double var = s2 / N - mean * mean;
    double invs = 1.0 / sqrt(var + 1e-5);
    double g = (double)gamma[o];
    stats[o*2]   = (float)(g * invs);
    stats[o*2+1] = (float)((double)beta[o] - mean * g * invs);
}

// ---------------- Kernel 4: BN + exact GELU ----------------
__global__ __launch_bounds__(256) void k4_bn_gelu(
    float* __restrict__ y, const float* __restrict__ stats)
{
    size_t idx4 = (size_t)blockIdx.x * 256 + threadIdx.x;
    float4* p = (float4*)y;
    float4 v = p[idx4];
    int o = (int)((idx4 * 4) / HWC) % DD;
    float sc = stats[o*2], sh = stats[o*2+1];
    const float inv_sqrt2 = 0.70710678118654752f;
    float g0 = fmaf(v.x, sc, sh);
    float g1 = fmaf(v.y, sc, sh);
    float g2 = fmaf(v.z, sc, sh);
    float g3 = fmaf(v.w, sc, sh);
    v.x = 0.5f * g0 * (1.f + erff(g0 * inv_sqrt2));
    v.y = 0.5f * g1 * (1.f + erff(g1 * inv_sqrt2));
    v.z = 0.5f * g2 * (1.f + erff(g2 * inv_sqrt2));
    v.w = 0.5f * g3 * (1.f + erff(g3 * inv_sqrt2));
    p[idx4] = v;
}

extern "C" void kernel_launch(void* const* d_in, const int* in_sizes, int n_in,
                              void* d_out, int out_size, void* d_ws, size_t ws_size,
                              hipStream_t stream) {
    const float* bev   = (const float*)d_in[0];
    const float* offw  = (const float*)d_in[1];
    const float* offb  = (const float*)d_in[2];
    const float* wtw   = (const float*)d_in[3];
    const float* wtb   = (const float*)d_in[4];
    const float* projw = (const float*)d_in[5];
    const float* gamma = (const float*)d_in[6];
    const float* beta  = (const float*)d_in[7];
    float* out = (float*)d_out;
    float* wsf = (float*)d_ws;

    float* oa    = wsf + OA_OFF;
    float* wtT   = wsf + WTT_OFF;
    float* wp    = wsf + WP_OFF;
    float* stats = wsf + STATS_OFF;
    double* part = (double*)(wsf + PART_OFF);
    float* bevt  = wsf + BEVT_OFF;                 // tier2 f32
    ushort* bevtb = (ushort*)(wsf + BEVT_OFF);     // full3 bf16
    ushort* aggb = (ushort*)(wsf + AGG_OFF);
    ushort* wbf  = (ushort*)(wsf + WBF_OFF);
    ushort* wcb  = (ushort*)(wsf + WCB_OFF);
    float* part2 = wsf + PART2_OFF;                // aliases bevtb (written after last read)

    bool full3 = ws_size >= WS_NEED_FULL3;
    bool big   = ws_size >= WS_NEED_BEVT;

    hipLaunchKernelGGL(k0_prep, dim3(64), dim3(256), 0, stream,
                       projw, offw, wtw, wtT, wp);
    if (full3) {
        hipLaunchKernelGGL(k0b_wbf, dim3(64), dim3(256), 0, stream, projw, wbf);
        hipLaunchKernelGGL(k0c_wcb, dim3(72), dim3(256), 0, stream, offw, wtw, wcb);
        hipLaunchKernelGGL(k2t_bf, dim3(2048), dim3(256), 0, stream, bev, bevtb);
        hipLaunchKernelGGL(k1m_conv_mfma, dim3(2048), dim3(256), 0, stream,
                           bevtb, wcb, offb, wtb, oa);
        hipLaunchKernelGGL(k2a_sample_bf, dim3(2048), dim3(256), 0, stream,
                           bevtb, oa, aggb);
        hipLaunchKernelGGL(k2b_proj, dim3(2048), dim3(256), 0, stream,
                           aggb, wbf, out, part2);
        hipLaunchKernelGGL(k3b_finalize2, dim3(128), dim3(256), 0, stream,
                           part2, gamma, beta, stats);
    } else if (big) {
        hipLaunchKernelGGL(k2t_transpose, dim3(2048), dim3(256), 0, stream, bev, bevt);
        hipLaunchKernelGGL(k1_convs, dim3(BB*HH), dim3(256), 0, stream,
                           bev, wp, offb, wtb, oa);
        hipLaunchKernelGGL(k2_sample_proj_t, dim3(BB*256), dim3(512), 0, stream,
                           bevt, oa, wtT, out);
        hipLaunchKernelGGL(k3_partial, dim3(512), dim3(256), 0, stream, out, part);
        hipLaunchKernelGGL(k3_finalize, dim3(1), dim3(128), 0, stream,
                           part, gamma, beta, stats);
    } else {
        hipLaunchKernelGGL(k1_convs, dim3(BB*HH), dim3(256), 0, stream,
                           bev, wp, offb, wtb, oa);
        hipLaunchKernelGGL(k2_sample_proj, dim3(BB*256), dim3(512), 0, stream,
                           bev, oa, wtT, out);
        hipLaunchKernelGGL(k3_partial, dim3(512), dim3(256), 0, stream, out, part);
        hipLaunchKernelGGL(k3_finalize, dim3(1), dim3(128), 0, stream,
                           part, gamma, beta, stats);
    }
    hipLaunchKernelGGL(k4_bn_gelu, dim3((BB*DD*HWC)/1024), dim3(256), 0, stream,
                       out, stats);
}

// Round 11
// 186.452 us; speedup vs baseline: 11.0140x; 1.0879x over previous
//
#include <hip/hip_runtime.h>
#include <math.h>

#define BB 2
#define DD 128
#define HH 256
#define WW 256
#define KK 4
#define HWC (HH*WW)
#define SROW2 320   // d-slice stride in S (fused fallback kernels)

typedef unsigned int u32;
typedef unsigned short ushort;
typedef __attribute__((ext_vector_type(8))) short bf16x8;
typedef __attribute__((ext_vector_type(4))) float f32x4;

// ws float layout
#define OA_OFF    0
#define WTT_OFF   1572864
#define WP_OFF    1589248
#define STATS_OFF 1603072
#define PART_OFF  1603392
#define BEVT_OFF  1605440       // full3: bevtb bf16 (16.8M ushort); tier2: f32 bevt
#define PACC_OFF  18382656
#define AGG_OFF   PACC_OFF      // agg bf16: 16.8M ushort
#define WBF_OFF   26771264      // proj W bf16
#define WCB_OFF   26779456      // conv W bf16 padded: 9*16*128 ushort
#define PART2_OFF BEVT_OFF      // aliases bevtb (written after last read)
#define WS_NEED_BEVT  ((size_t)PACC_OFF * 4)
#define WS_NEED_FULL3 ((size_t)(WCB_OFF + 9216) * 4)

__device__ __forceinline__ u32 f2bf(float x) {
    u32 u = __builtin_bit_cast(u32, x);
    return (u + 0x7fffu + ((u >> 16) & 1u)) >> 16;
}
__device__ __forceinline__ u32 pkbf(float a, float b) {
    return f2bf(a) | (f2bf(b) << 16);
}
__device__ __forceinline__ float bflo(u32 d) { return __builtin_bit_cast(float, d << 16); }
__device__ __forceinline__ float bfhi(u32 d) { return __builtin_bit_cast(float, d & 0xffff0000u); }

// ---------------- Kernel 0: weight prep (fallback tiers) ----------------
__global__ __launch_bounds__(256) void k0_prep(
    const float* __restrict__ projw, const float* __restrict__ offw,
    const float* __restrict__ wtw, float* __restrict__ wtT, float* __restrict__ wp)
{
    int idx = blockIdx.x * 256 + threadIdx.x;
    if (idx < 16384) {
        int d = idx >> 7, o = idx & 127;
        wtT[d * 128 + o] = projw[o * 128 + d];
    }
    if (idx < 13824) {
        int c = idx / 108; int r = idx % 108; int o = r / 9; int t = r % 9;
        wp[idx] = (o < 8) ? offw[(o*128 + c)*9 + t] : wtw[((o-8)*128 + c)*9 + t];
    }
}

// ---------------- Kernel 0b: proj weights -> bf16 [o][d] ----------------
__global__ __launch_bounds__(256) void k0b_wbf(
    const float* __restrict__ projw, ushort* __restrict__ wbf)
{
    int idx = blockIdx.x * 256 + threadIdx.x;
    if (idx < 16384) wbf[idx] = (ushort)f2bf(projw[idx]);
}

// ---------------- Kernel 0c: conv weights -> bf16 wcb[tap][16(o pad)][128(c)] ----------------
__global__ __launch_bounds__(256) void k0c_wcb(
    const float* __restrict__ offw, const float* __restrict__ wtw,
    ushort* __restrict__ wcb)
{
    int idx = blockIdx.x * 256 + threadIdx.x;
    if (idx < 18432) {
        int tap = idx >> 11;
        int rem = idx & 2047;
        int oo = rem >> 7, c = rem & 127;
        float v = 0.f;
        if (oo < 8)       v = offw[(oo*128 + c)*9 + tap];
        else if (oo < 12) v = wtw[((oo-8)*128 + c)*9 + tap];
        wcb[idx] = (ushort)f2bf(v);
    }
}

// ---------------- Kernel Tb: NCHW f32 -> NHWC bf16 ----------------
__global__ __launch_bounds__(256) void k2t_bf(
    const float* __restrict__ bev, ushort* __restrict__ bevtb)
{
    __shared__ float T[64 * 128];
    int tid = threadIdx.x;
    int bidx = blockIdx.x;
    int b = bidx >> 10;
    int rem = bidx & 1023;
    int yrow = rem >> 2;
    int x0 = (rem & 3) << 6;

    const float* src = bev + ((size_t)b * DD) * HWC + (size_t)yrow * WW + x0;
    #pragma unroll 4
    for (int k = 0; k < 32; k++) {
        int flat = k * 256 + tid;
        int d = flat >> 6, xl = flat & 63;
        float v = src[(size_t)d * HWC + xl];
        T[xl * 128 + (((d >> 2) ^ (xl & 31)) << 2) + (d & 3)] = v;
    }
    __syncthreads();
    ushort* dst = bevtb + (((size_t)b * HH + yrow) * WW + x0) * 128;
    #pragma unroll 4
    for (int k = 0; k < 8; k++) {
        int flat = k * 256 + tid;
        int d4 = flat & 31, xl = (flat >> 5) & 63;
        float4 v = *(const float4*)&T[xl * 128 + ((d4 ^ (xl & 31)) << 2)];
        uint2 pk;
        pk.x = pkbf(v.x, v.y);
        pk.y = pkbf(v.z, v.w);
        *(uint2*)(dst + (size_t)xl * 128 + (d4 << 2)) = pk;
    }
}

// ---------------- Kernel 1m: 3x3 convs as implicit-GEMM MFMA, LDS-staged ----------------
// R10 post-mortem: compiler sinks reg-prefetch back into a serial load->mfma chain
// (VGPR=32) -> 36 L2 round-trips/wave, 68us at 2.5% MfmaUtil. Fix: stage the block's
// 3 rows x 66 px x 256B of bevtb into LDS with ~13 INDEPENDENT streaming loads/thread
// (full MLP), then MFMA B-frags via ds_read_b128.  Quarter-slot XOR layout
// slot=(kk*4+lk)^(pl&15): for fixed (kk,lk) the 16 pixel-lanes hit 16 distinct 16B
// slots -> 2-way banks (free).  Writes use the same XOR (reg-staged, both sides swz).
__global__ __launch_bounds__(256) void k1m_conv_mfma(
    const ushort* __restrict__ bevtb, const ushort* __restrict__ wcb,
    const float* __restrict__ offb, const float* __restrict__ wtb,
    float* __restrict__ oa)
{
    __shared__ uint4 lds4[3168];   // 3 rows x 66 px x 16 slots x 16B = 50688 B

    int tid = threadIdx.x;
    int wv = tid >> 6;
    int l = tid & 63;
    int lm = l & 15, lk = l >> 4;
    int wgid = blockIdx.x;
    int lin = (wgid & 7) * 256 + (wgid >> 3);   // bijective XCD-contiguous remap
    int b = lin >> 10;
    int i = (lin >> 2) & 255;
    int jt = lin & 3;
    int x0 = jt * 64;

    // ---- stage 3 rows (y = i-1..i+1), pixels x0-1 .. x0+64, zero-filled OOB ----
    const ushort* bb = bevtb + (size_t)b * HWC * 128;
    for (int z = tid; z < 3168; z += 256) {
        int row = z / 1056;
        int rem = z - row * 1056;
        int pl = rem >> 4;
        int q  = rem & 15;
        int yy = i - 1 + row;
        int x  = x0 - 1 + pl;
        bool ok = ((unsigned)yy < HH) && ((unsigned)x < WW);
        uint4 v = make_uint4(0u, 0u, 0u, 0u);
        if (ok) v = *(const uint4*)(bb + ((size_t)(yy * WW + x) << 7) + q * 8);
        lds4[row * 1056 + pl * 16 + (q ^ (pl & 15))] = v;
    }
    __syncthreads();

    // ---- 36 MFMAs; B from LDS, A (wcb, 18KB) L1-hot ----
    f32x4 acc = (f32x4)(0.f);
    #pragma unroll
    for (int dy = 0; dy < 3; dy++) {
        #pragma unroll
        for (int dx = 0; dx < 3; dx++) {
            int pl = wv * 16 + lm + dx;          // LDS pixel index for this lane
            const uint4* bp = &lds4[dy * 1056 + pl * 16];
            int sx = pl & 15;
            const ushort* ap = wcb + (size_t)((dy*3 + dx) * 16 + lm) * 128 + lk * 8;
            #pragma unroll
            for (int kk = 0; kk < 4; kk++) {
                bf16x8 bfr = *(const bf16x8*)&bp[(kk*4 + lk) ^ sx];
                bf16x8 afr = *(const bf16x8*)(ap + kk * 32);
                acc = __builtin_amdgcn_mfma_f32_16x16x32_bf16(afr, bfr, acc, 0, 0, 0);
            }
        }
    }

    float v[4];
    #pragma unroll
    for (int r = 0; r < 4; r++) v[r] = acc[r];

    int j = x0 + wv * 16 + lm;
    if (lk < 2) {
        #pragma unroll
        for (int r = 0; r < 4; r++) v[r] += offb[lk*4 + r];   // OFFSET_SCALE = 1.0
    } else if (lk == 2) {
        float l4[4];
        #pragma unroll
        for (int r = 0; r < 4; r++) l4[r] = v[r] + wtb[r];
        float m = fmaxf(fmaxf(l4[0], l4[1]), fmaxf(l4[2], l4[3]));
        float e[4]; float se = 0.f;
        #pragma unroll
        for (int r = 0; r < 4; r++) { e[r] = expf(l4[r] - m); se += e[r]; }
        float inv = 1.f / se;
        #pragma unroll
        for (int r = 0; r < 4; r++) v[r] = e[r] * inv;
    }
    if (lk < 3) {
        size_t basep = (size_t)b * 12 * HWC + (size_t)i * WW + j;
        #pragma unroll
        for (int r = 0; r < 4; r++)
            oa[basep + (size_t)(lk*4 + r) * HWC] = v[r];
    }
}

// ---------------- Kernel 1 (tier2 fallback): full 128-channel conv ----------------
__global__ __launch_bounds__(256) void k1_convs(
    const float* __restrict__ bev, const float* __restrict__ wp,
    const float* __restrict__ offb, const float* __restrict__ wtb,
    float* __restrict__ oa)
{
    __shared__ float rows[2][3][260];
    int tid = threadIdx.x;
    int p = blockIdx.x;
    int b = p / HH; int i = p % HH; int j = tid;
    const float* bb = bev + (size_t)b * DD * HWC;

    if (tid < 12) { int bf = tid / 6, r = tid % 6; rows[bf][r >> 1][(r & 1) ? 257 : 0] = 0.f; }
    #pragma unroll
    for (int l = 0; l < 3; l++) {
        int yy = i + l - 1;
        rows[0][l][1 + tid] = ((unsigned)yy < HH) ? bb[yy * WW + tid] : 0.f;
    }
    __syncthreads();

    float acc[12];
    #pragma unroll
    for (int o = 0; o < 12; o++) acc[o] = 0.f;

    for (int c = 0; c < 128; c++) {
        int cb = c & 1, nb = cb ^ 1;
        float rv[3];
        if (c < 127) {
            const float* pln = bb + (size_t)(c + 1) * HWC;
            #pragma unroll
            for (int l = 0; l < 3; l++) {
                int yy = i + l - 1;
                rv[l] = ((unsigned)yy < HH) ? pln[yy * WW + tid] : 0.f;
            }
        }
        float v[9];
        #pragma unroll
        for (int dy = 0; dy < 3; dy++)
            #pragma unroll
            for (int dx = 0; dx < 3; dx++)
                v[dy*3 + dx] = rows[cb][dy][tid + dx];
        const float* wc = wp + c * 108;
        #pragma unroll
        for (int o = 0; o < 12; o++) {
            float s = acc[o];
            #pragma unroll
            for (int t = 0; t < 9; t++) s = fmaf(wc[o*9 + t], v[t], s);
            acc[o] = s;
        }
        if (c < 127) {
            #pragma unroll
            for (int l = 0; l < 3; l++) rows[nb][l][1 + tid] = rv[l];
        }
        __syncthreads();
    }

    float outv[12];
    #pragma unroll
    for (int o = 0; o < 8; o++) outv[o] = acc[o] + offb[o];
    float l4[4];
    #pragma unroll
    for (int k = 0; k < 4; k++) l4[k] = acc[8+k] + wtb[k];
    float m = fmaxf(fmaxf(l4[0], l4[1]), fmaxf(l4[2], l4[3]));
    float e[4]; float se = 0.f;
    #pragma unroll
    for (int k = 0; k < 4; k++) { e[k] = expf(l4[k] - m); se += e[k]; }
    float inv = 1.f / se;
    #pragma unroll
    for (int k = 0; k < 4; k++) outv[8+k] = e[k] * inv;

    size_t basep = (size_t)b * 12 * HWC + (size_t)i * WW + j;
    #pragma unroll
    for (int o = 0; o < 12; o++) oa[basep + (size_t)o * HWC] = outv[o];
}

// ---------------- Kernel T (tier2): NCHW -> NHWC f32 transpose ----------------
__global__ __launch_bounds__(256) void k2t_transpose(
    const float* __restrict__ bev, float* __restrict__ bevt)
{
    __shared__ float T[64 * 128];
    int tid = threadIdx.x;
    int bidx = blockIdx.x;
    int b = bidx >> 10;
    int rem = bidx & 1023;
    int yrow = rem >> 2;
    int x0 = (rem & 3) << 6;

    const float* src = bev + ((size_t)b * DD) * HWC + (size_t)yrow * WW + x0;
    #pragma unroll 4
    for (int k = 0; k < 32; k++) {
        int flat = k * 256 + tid;
        int d = flat >> 6, xl = flat & 63;
        float v = src[(size_t)d * HWC + xl];
        T[xl * 128 + (((d >> 2) ^ (xl & 31)) << 2) + (d & 3)] = v;
    }
    __syncthreads();
    float* dst = bevt + (((size_t)b * HH + yrow) * WW + x0) * 128;
    #pragma unroll 4
    for (int k = 0; k < 8; k++) {
        int flat = k * 256 + tid;
        int d4 = flat & 31, xl = (flat >> 5) & 63;
        float4 v = *(const float4*)&T[xl * 128 + ((d4 ^ (xl & 31)) << 2)];
        *(float4*)(dst + (size_t)xl * 128 + (d4 << 2)) = v;
    }
}

// ---------------- Kernel 2a (bf16): deformable sample + K-aggregate ----------------
__global__ __launch_bounds__(256) void k2a_sample_bf(
    const ushort* __restrict__ bevtb, const float* __restrict__ oa,
    ushort* __restrict__ aggb)
{
    int tid = threadIdx.x;
    int q4 = tid & 3;
    int pl = (tid >> 2) & 15;
    int ql = tid >> 6;
    int bidx = blockIdx.x;
    int b = bidx >> 10;
    int rem = bidx & 1023;
    int pt = rem >> 6;
    int qt = rem & 63;
    int p = pt * 16 + pl;
    int q = qt * 4 + ql;

    // offsets / attention (transpose quirk: x <- p+dx, y <- q+dy)
    const float* ob = oa + (size_t)b * 12 * HWC + (size_t)p * WW + q;
    unsigned pa[8]; float cw[16];
    #pragma unroll
    for (int k = 0; k < 4; k++) {
        float dx = ob[(size_t)(2*k)   * HWC];
        float dy = ob[(size_t)(2*k+1) * HWC];
        float a  = ob[(size_t)(8+k)   * HWC];
        float x  = fminf(fmaxf((float)p + dx, 0.f), (float)(WW-1));
        float yv = fminf(fmaxf((float)q + dy, 0.f), (float)(HH-1));
        float x0f = floorf(x); float y0f = floorf(yv);
        int x0 = (int)x0f; int y0 = (int)y0f;
        int x1 = min(x0 + 1, WW - 1); int y1 = min(y0 + 1, HH - 1);
        float wx = x - x0f; float wy = yv - y0f;
        pa[k*2+0] = (unsigned)(y0*WW + x0) | ((unsigned)(y0*WW + x1) << 16);
        pa[k*2+1] = (unsigned)(y1*WW + x0) | ((unsigned)(y1*WW + x1) << 16);
        cw[k*4+0] = a * (1.f - wx) * (1.f - wy);
        cw[k*4+1] = a * wx * (1.f - wy);
        cw[k*4+2] = a * (1.f - wx) * wy;
        cw[k*4+3] = a * wx * wy;
    }

    const ushort* bt = bevtb + (size_t)b * HWC * 128 + q4 * 8;

    float s[4][8];
    #pragma unroll
    for (int c = 0; c < 4; c++)
        #pragma unroll
        for (int e = 0; e < 8; e++) s[c][e] = 0.f;

    #pragma unroll
    for (int t = 0; t < 16; t++) {
        unsigned a01 = pa[t >> 1];
        unsigned pix = (t & 1) ? (a01 >> 16) : (a01 & 0xffffu);
        const ushort* tp = bt + ((size_t)pix << 7);
        float w = cw[t];
        #pragma unroll
        for (int c = 0; c < 4; c++) {
            uint4 v = *(const uint4*)(tp + c * 32);
            s[c][0] = fmaf(w, bflo(v.x), s[c][0]);
            s[c][1] = fmaf(w, bfhi(v.x), s[c][1]);
            s[c][2] = fmaf(w, bflo(v.y), s[c][2]);
            s[c][3] = fmaf(w, bfhi(v.y), s[c][3]);
            s[c][4] = fmaf(w, bflo(v.z), s[c][4]);
            s[c][5] = fmaf(w, bfhi(v.z), s[c][5]);
            s[c][6] = fmaf(w, bflo(v.w), s[c][6]);
            s[c][7] = fmaf(w, bfhi(v.w), s[c][7]);
        }
    }

    ushort* outp = aggb + ((size_t)b * HWC + (size_t)p * WW + q) * 128 + q4 * 8;
    #pragma unroll
    for (int c = 0; c < 4; c++) {
        uint4 pk;
        pk.x = pkbf(s[c][0], s[c][1]);
        pk.y = pkbf(s[c][2], s[c][3]);
        pk.z = pkbf(s[c][4], s[c][5]);
        pk.w = pkbf(s[c][6], s[c][7]);
        *(uint4*)(outp + c * 32) = pk;
    }
}

// ---------------- Kernel 2b: 1x1 proj MFMA GEMM + fused BN partial stats ----------------
__global__ __launch_bounds__(256) void k2b_proj(
    const ushort* __restrict__ aggb, const ushort* __restrict__ wbf,
    float* __restrict__ y, float* __restrict__ part2)
{
    int tid = threadIdx.x;
    int wv = tid >> 6;
    int l = tid & 63;
    int lm = l & 15, lk = l >> 4;
    int bidx = blockIdx.x;
    int b = bidx >> 10;
    int pix0 = (bidx & 1023) << 6;
    int o0 = wv << 5;

    bf16x8 a[2][4];
    const ushort* wbase = wbf + (size_t)(o0 + lm) * 128 + lk * 8;
    #pragma unroll
    for (int ot = 0; ot < 2; ot++)
        #pragma unroll
        for (int kk = 0; kk < 4; kk++)
            a[ot][kk] = *(const bf16x8*)(wbase + ot * 16 * 128 + kk * 32);

    f32x4 acc[2][4];
    #pragma unroll
    for (int ot = 0; ot < 2; ot++)
        #pragma unroll
        for (int nt = 0; nt < 4; nt++)
            acc[ot][nt] = (f32x4)(0.f);

    const ushort* bbase = aggb + ((size_t)b * HWC + pix0 + lm) * 128 + lk * 8;
    #pragma unroll
    for (int nt = 0; nt < 4; nt++) {
        bf16x8 bfr[4];
        #pragma unroll
        for (int kk = 0; kk < 4; kk++)
            bfr[kk] = *(const bf16x8*)(bbase + nt * 16 * 128 + kk * 32);
        #pragma unroll
        for (int ot = 0; ot < 2; ot++)
            #pragma unroll
            for (int kk = 0; kk < 4; kk++)
                acc[ot][nt] = __builtin_amdgcn_mfma_f32_16x16x32_bf16(
                    a[ot][kk], bfr[kk], acc[ot][nt], 0, 0, 0);
    }

    #pragma unroll
    for (int ot = 0; ot < 2; ot++)
        #pragma unroll
        for (int nt = 0; nt < 4; nt++)
            #pragma unroll
            for (int r = 0; r < 4; r++)
                y[((size_t)b * DD + o0 + ot * 16 + lk * 4 + r) * HWC + pix0 + nt * 16 + lm]
                    = acc[ot][nt][r];

    float sm[2][4], sq[2][4];
    #pragma unroll
    for (int ot = 0; ot < 2; ot++)
        #pragma unroll
        for (int r = 0; r < 4; r++) { sm[ot][r] = 0.f; sq[ot][r] = 0.f; }
    #pragma unroll
    for (int ot = 0; ot < 2; ot++)
        #pragma unroll
        for (int nt = 0; nt < 4; nt++)
            #pragma unroll
            for (int r = 0; r < 4; r++) {
                float v = acc[ot][nt][r];
                sm[ot][r] += v;
                sq[ot][r] = fmaf(v, v, sq[ot][r]);
            }
    #pragma unroll
    for (int m = 1; m < 16; m <<= 1) {
        #pragma unroll
        for (int ot = 0; ot < 2; ot++)
            #pragma unroll
            for (int r = 0; r < 4; r++) {
                sm[ot][r] += __shfl_xor(sm[ot][r], m);
                sq[ot][r] += __shfl_xor(sq[ot][r], m);
            }
    }
    if (lm == 0) {
        #pragma unroll
        for (int ot = 0; ot < 2; ot++)
            #pragma unroll
            for (int r = 0; r < 4; r++) {
                int o = o0 + ot * 16 + lk * 4 + r;
                part2[(size_t)o * 2048 + bidx] = sm[ot][r];
                part2[(size_t)128 * 2048 + (size_t)o * 2048 + bidx] = sq[ot][r];
            }
    }
}

// ---------------- Kernel 3b': finalize BN from k2b block partials ----------------
__global__ __launch_bounds__(256) void k3b_finalize2(
    const float* __restrict__ part2, const float* __restrict__ gamma,
    const float* __restrict__ beta, float* __restrict__ stats)
{
    int o = blockIdx.x; int tid = threadIdx.x;
    const float* ps = part2 + (size_t)o * 2048;
    const float* pq = part2 + (size_t)128 * 2048 + (size_t)o * 2048;
    double s = 0.0, s2 = 0.0;
    for (int i = tid; i < 2048; i += 256) { s += (double)ps[i]; s2 += (double)pq[i]; }
    __shared__ double ls[256], ls2[256];
    ls[tid] = s; ls2[tid] = s2;
    __syncthreads();
    for (int off = 128; off > 0; off >>= 1) {
        if (tid < off) { ls[tid] += ls[tid+off]; ls2[tid] += ls2[tid+off]; }
        __syncthreads();
    }
    if (tid == 0) {
        double N = (double)(BB * HWC);
        double mean = ls[0] / N;
        double var = ls2[0] / N - mean * mean;
        double invs = 1.0 / sqrt(var + 1e-5);
        double g = (double)gamma[o];
        stats[o*2]   = (float)(g * invs);
        stats[o*2+1] = (float)((double)beta[o] - mean * g * invs);
    }
}

// ---------------- Kernel 2 fused fallback (tier2, NHWC f32) ----------------
__global__ __launch_bounds__(512, 2) void k2_sample_proj_t(
    const float* __restrict__ bevt, const float* __restrict__ oa,
    const float* __restrict__ wt, float* __restrict__ y)
{
    __shared__ float S[2][16 * SROW2];

    int tid = threadIdx.x;
    int bidx = blockIdx.x;
    int b  = bidx >> 8;
    int p0 = ((bidx >> 4) & 15) * 16;
    int q0 = (bidx & 15) * 16;

    int gpix = tid >> 1;
    int gp = gpix & 15;
    int gq = gpix >> 4;
    int dgrp = tid & 1;
    int swr = gp * 20 + gq;

    int wv = tid >> 6;
    int wvu = __builtin_amdgcn_readfirstlane(wv);
    int lane = tid & 63;
    int lp = lane >> 2;
    int q4 = (lane & 3) << 2;
    int soff = lp * 20 + q4;

    const float* ob = oa + (size_t)b * 12 * HWC + (size_t)(p0 + gp) * WW + (q0 + gq);
    unsigned pa[8]; float cw[16];
    #pragma unroll
    for (int k = 0; k < 4; k++) {
        float dx = ob[(size_t)(2*k)   * HWC];
        float dy = ob[(size_t)(2*k+1) * HWC];
        float a  = ob[(size_t)(8+k)   * HWC];
        float x  = fminf(fmaxf((float)(p0 + gp) + dx, 0.f), (float)(WW-1));
        float yv = fminf(fmaxf((float)(q0 + gq) + dy, 0.f), (float)(HH-1));
        float x0f = floorf(x); float y0f = floorf(yv);
        int x0 = (int)x0f; int y0 = (int)y0f;
        int x1 = min(x0 + 1, WW - 1); int y1 = min(y0 + 1, HH - 1);
        float wx = x - x0f; float wy = yv - y0f;
        pa[k*2+0] = (unsigned)(y0*WW + x0) | ((unsigned)(y0*WW + x1) << 16);
        pa[k*2+1] = (unsigned)(y1*WW + x0) | ((unsigned)(y1*WW + x1) << 16);
        cw[k*4+0] = a * (1.f - wx) * (1.f - wy);
        cw[k*4+1] = a * wx * (1.f - wy);
        cw[k*4+2] = a * (1.f - wx) * wy;
        cw[k*4+3] = a * wx * wy;
    }

    const float* bt = bevt + (size_t)b * HWC * 128 + dgrp * 8;

    float acc[64];
    #pragma unroll
    for (int t = 0; t < 64; t++) acc[t] = 0.f;

    {
        float4 s0 = make_float4(0,0,0,0), s1 = make_float4(0,0,0,0);
        #pragma unroll
        for (int t = 0; t < 16; t++) {
            unsigned pix = (t & 1) ? (pa[t >> 1] >> 16) : (pa[t >> 1] & 0xffffu);
            const float4* tp = (const float4*)(bt + ((size_t)pix << 7));
            float4 va = tp[0], vb = tp[1];
            float c = cw[t];
            s0.x = fmaf(c, va.x, s0.x); s0.y = fmaf(c, va.y, s0.y);
            s0.z = fmaf(c, va.z, s0.z); s0.w = fmaf(c, va.w, s0.w);
            s1.x = fmaf(c, vb.x, s1.x); s1.y = fmaf(c, vb.y, s1.y);
            s1.z = fmaf(c, vb.z, s1.z); s1.w = fmaf(c, vb.w, s1.w);
        }
        int r = dgrp * 8;
        S[0][(r+0)*SROW2 + swr] = s0.x; S[0][(r+1)*SROW2 + swr] = s0.y;
        S[0][(r+2)*SROW2 + swr] = s0.z; S[0][(r+3)*SROW2 + swr] = s0.w;
        S[0][(r+4)*SROW2 + swr] = s1.x; S[0][(r+5)*SROW2 + swr] = s1.y;
        S[0][(r+6)*SROW2 + swr] = s1.z; S[0][(r+7)*SROW2 + swr] = s1.w;
    }
    __syncthreads();

    for (int c = 0; c < 8; c++) {
        int cur = c & 1;
        const float* Sc = &S[cur][0];
        float* Sn = &S[cur ^ 1][0];
        int d0 = c * 16;
        int dn = d0 + 16;
        bool more = (c < 7);

        float4 g0 = make_float4(0,0,0,0), g1 = make_float4(0,0,0,0);
        float4 pf0, pf1;
        if (more) {
            unsigned pix = pa[0] & 0xffffu;
            const float4* tp = (const float4*)(bt + ((size_t)pix << 7) + dn);
            pf0 = tp[0]; pf1 = tp[1];
        }

        #pragma unroll
        for (int dl = 0; dl < 16; dl++) {
            float4 cur0 = pf0, cur1 = pf1;
            if (more && dl < 15) {
                int t = dl + 1;
                unsigned pix = (t & 1) ? (pa[t >> 1] >> 16) : (pa[t >> 1] & 0xffffu);
                const float4* tp = (const float4*)(bt + ((size_t)pix << 7) + dn);
                pf0 = tp[0]; pf1 = tp[1];
            }

            float4 sv = *(const float4*)(Sc + dl * SROW2 + soff);
            const float4* wq = (const float4*)(wt + (size_t)(d0 + dl) * 128 + wvu * 16);
            #pragma unroll
            for (int oi4 = 0; oi4 < 4; oi4++) {
                float4 w4 = wq[oi4];
                int ob4 = oi4 * 16;
                acc[ob4+ 0] = fmaf(w4.x, sv.x, acc[ob4+ 0]);
                acc[ob4+ 1] = fmaf(w4.x, sv.y, acc[ob4+ 1]);
                acc[ob4+ 2] = fmaf(w4.x, sv.z, acc[ob4+ 2]);
                acc[ob4+ 3] = fmaf(w4.x, sv.w, acc[ob4+ 3]);
                acc[ob4+ 4] = fmaf(w4.y, sv.x, acc[ob4+ 4]);
                acc[ob4+ 5] = fmaf(w4.y, sv.y, acc[ob4+ 5]);
                acc[ob4+ 6] = fmaf(w4.y, sv.z, acc[ob4+ 6]);
                acc[ob4+ 7] = fmaf(w4.y, sv.w, acc[ob4+ 7]);
                acc[ob4+ 8] = fmaf(w4.z, sv.x, acc[ob4+ 8]);
                acc[ob4+ 9] = fmaf(w4.z, sv.y, acc[ob4+ 9]);
                acc[ob4+10] = fmaf(w4.z, sv.z, acc[ob4+10]);
                acc[ob4+11] = fmaf(w4.z, sv.w, acc[ob4+11]);
                acc[ob4+12] = fmaf(w4.w, sv.x, acc[ob4+12]);
                acc[ob4+13] = fmaf(w4.w, sv.y, acc[ob4+13]);
                acc[ob4+14] = fmaf(w4.w, sv.z, acc[ob4+14]);
                acc[ob4+15] = fmaf(w4.w, sv.w, acc[ob4+15]);
            }

            if (more) {
                float cwt = cw[dl];
                g0.x = fmaf(cwt, cur0.x, g0.x); g0.y = fmaf(cwt, cur0.y, g0.y);
                g0.z = fmaf(cwt, cur0.z, g0.z); g0.w = fmaf(cwt, cur0.w, g0.w);
                g1.x = fmaf(cwt, cur1.x, g1.x); g1.y = fmaf(cwt, cur1.y, g1.y);
                g1.z = fmaf(cwt, cur1.z, g1.z); g1.w = fmaf(cwt, cur1.w, g1.w);
            }
        }

        if (more) {
            int r = dgrp * 8;
            Sn[(r+0)*SROW2 + swr] = g0.x; Sn[(r+1)*SROW2 + swr] = g0.y;
            Sn[(r+2)*SROW2 + swr] = g0.z; Sn[(r+3)*SROW2 + swr] = g0.w;
            Sn[(r+4)*SROW2 + swr] = g1.x; Sn[(r+5)*SROW2 + swr] = g1.y;
            Sn[(r+6)*SROW2 + swr] = g1.z; Sn[(r+7)*SROW2 + swr] = g1.w;
        }
        __syncthreads();
    }

    size_t base = (size_t)b * DD * HWC + (size_t)(p0 + lp) * WW + (q0 + q4);
    #pragma unroll
    for (int oi = 0; oi < 16; oi++) {
        int o = wv * 16 + oi;
        float4 v = make_float4(acc[oi*4+0], acc[oi*4+1], acc[oi*4+2], acc[oi*4+3]);
        *(float4*)(y + base + (size_t)o * HWC) = v;
    }
}

// ---------------- Kernel 2 fallback (tier3, NCHW) ----------------
__global__ __launch_bounds__(512, 2) void k2_sample_proj(
    const float* __restrict__ bev, const float* __restrict__ oa,
    const float* __restrict__ wt, float* __restrict__ y)
{
    __shared__ float S[2][16 * SROW2];
    int tid = threadIdx.x;
    int bidx = blockIdx.x;
    int b  = bidx >> 8;
    int p0 = ((bidx >> 4) & 15) * 16;
    int q0 = (bidx & 15) * 16;
    int pix = tid & 255;
    int gq = pix >> 4;
    int gp = pix & 15;
    int dgrp = tid >> 8;
    int swr = gp * 20 + gq;
    int wv = tid >> 6;
    int wvu = __builtin_amdgcn_readfirstlane(wv);
    int lane = tid & 63;
    int lp = lane >> 2;
    int q4 = (lane & 3) << 2;
    int soff = lp * 20 + q4;

    const float* ob = oa + (size_t)b * 12 * HWC + (size_t)(p0 + gp) * WW + (q0 + gq);
    unsigned pa[8]; float cw[16];
    #pragma unroll
    for (int k = 0; k < 4; k++) {
        float dx = ob[(size_t)(2*k)   * HWC];
        float dy = ob[(size_t)(2*k+1) * HWC];
        float a  = ob[(size_t)(8+k)   * HWC];
        float x  = fminf(fmaxf((float)(p0 + gp) + dx, 0.f), (float)(WW-1));
        float yv = fminf(fmaxf((float)(q0 + gq) + dy, 0.f), (float)(HH-1));
        float x0f = floorf(x); float y0f = floorf(yv);
        int x0 = (int)x0f; int y0 = (int)y0f;
        int x1 = min(x0 + 1, WW - 1); int y1 = min(y0 + 1, HH - 1);
        float wx = x - x0f; float wy = yv - y0f;
        pa[k*2+0] = (unsigned)(y0*WW + x0) | ((unsigned)(y0*WW + x1) << 16);
        pa[k*2+1] = (unsigned)(y1*WW + x0) | ((unsigned)(y1*WW + x1) << 16);
        cw[k*4+0] = a * (1.f - wx) * (1.f - wy);
        cw[k*4+1] = a * wx * (1.f - wy);
        cw[k*4+2] = a * (1.f - wx) * wy;
        cw[k*4+3] = a * wx * wy;
    }
    const float* bb = bev + (size_t)b * DD * HWC;
    float acc[64];
    #pragma unroll
    for (int t = 0; t < 64; t++) acc[t] = 0.f;
    #pragma unroll
    for (int dd = 0; dd < 8; dd++) {
        const float* pl = bb + (size_t)(dgrp*8 + dd) * HWC;
        float s = 0.f;
        #pragma unroll
        for (int t = 0; t < 8; t++) {
            unsigned a01 = pa[t];
            s = fmaf(cw[2*t],   pl[a01 & 0xffffu], s);
            s = fmaf(cw[2*t+1], pl[a01 >> 16], s);
        }
        S[0][(dgrp*8 + dd) * SROW2 + swr] = s;
    }
    __syncthreads();
    for (int c = 0; c < 8; c++) {
        int cur = c & 1;
        const float* Sc = &S[cur][0];
        float* Sn = &S[cur ^ 1][0];
        int d0 = c * 16;
        int d0n = d0 + 16;
        bool more = (c < 7);
        #pragma unroll
        for (int dl = 0; dl < 16; dl++) {
            if (dl < 8) {
                if (more) {
                    const float* pl = bb + (size_t)(d0n + dgrp*8 + dl) * HWC;
                    float s = 0.f;
                    #pragma unroll
                    for (int t = 0; t < 8; t++) {
                        unsigned a01 = pa[t];
                        s = fmaf(cw[2*t],   pl[a01 & 0xffffu], s);
                        s = fmaf(cw[2*t+1], pl[a01 >> 16], s);
                    }
                    Sn[(dgrp*8 + dl) * SROW2 + swr] = s;
                }
            }
            float4 sv = *(const float4*)(Sc + dl * SROW2 + soff);
            const float4* wq = (const float4*)(wt + (size_t)(d0 + dl) * 128 + wvu * 16);
            #pragma unroll
            for (int oi4 = 0; oi4 < 4; oi4++) {
                float4 w4 = wq[oi4];
                int ob4 = oi4 * 16;
                acc[ob4+ 0] = fmaf(w4.x, sv.x, acc[ob4+ 0]);
                acc[ob4+ 1] = fmaf(w4.x, sv.y, acc[ob4+ 1]);
                acc[ob4+ 2] = fmaf(w4.x, sv.z, acc[ob4+ 2]);
                acc[ob4+ 3] = fmaf(w4.x, sv.w, acc[ob4+ 3]);
                acc[ob4+ 4] = fmaf(w4.y, sv.x, acc[ob4+ 4]);
                acc[ob4+ 5] = fmaf(w4.y, sv.y, acc[ob4+ 5]);
                acc[ob4+ 6] = fmaf(w4.y, sv.z, acc[ob4+ 6]);
                acc[ob4+ 7] = fmaf(w4.y, sv.w, acc[ob4+ 7]);
                acc[ob4+ 8] = fmaf(w4.z, sv.x, acc[ob4+ 8]);
                acc[ob4+ 9] = fmaf(w4.z, sv.y, acc[ob4+ 9]);
                acc[ob4+10] = fmaf(w4.z, sv.z, acc[ob4+10]);
                acc[ob4+11] = fmaf(w4.z, sv.w, acc[ob4+11]);
                acc[ob4+12] = fmaf(w4.w, sv.x, acc[ob4+12]);
                acc[ob4+13] = fmaf(w4.w, sv.y, acc[ob4+13]);
                acc[ob4+14] = fmaf(w4.w, sv.z, acc[ob4+14]);
                acc[ob4+15] = fmaf(w4.w, sv.w, acc[ob4+15]);
            }
        }
        __syncthreads();
    }
    size_t base = (size_t)b * DD * HWC + (size_t)(p0 + lp) * WW + (q0 + q4);
    #pragma unroll
    for (int oi = 0; oi < 16; oi++) {
        int o = wv * 16 + oi;
        float4 v = make_float4(acc[oi*4+0], acc[oi*4+1], acc[oi*4+2], acc[oi*4+3]);
        *(float4*)(y + base + (size_t)o * HWC) = v;
    }
}

// ---------------- Kernel 3a/3b: BN stats (fallback tiers only) ----------------
__global__ __launch_bounds__(256) void k3_partial(
    const float* __restrict__ y, double* __restrict__ part)
{
    int blk = blockIdx.x;
    int o = blk >> 2; int sub = blk & 3; int b = sub >> 1; int half = sub & 1;
    const float4* pl = (const float4*)(y + ((size_t)b * DD + o) * HWC + half * (HWC/2));
    int tid = threadIdx.x;
    double s = 0.0, s2 = 0.0;
    for (int idx = tid; idx < HWC/8; idx += 256) {
        float4 v = pl[idx];
        s  += (double)v.x + (double)v.y + (double)v.z + (double)v.w;
        s2 += (double)v.x*v.x + (double)v.y*v.y + (double)v.z*v.z + (double)v.w*v.w;
    }
    __shared__ double ls[256], ls2[256];
    ls[tid] = s; ls2[tid] = s2;
    __syncthreads();
    for (int off = 128; off > 0; off >>= 1) {
        if (tid < off) { ls[tid] += ls[tid+off]; ls2[tid] += ls2[tid+off]; }
        __syncthreads();
    }
    if (tid == 0) { part[blk*2] = ls[0]; part[blk*2+1] = ls2[0]; }
}

__global__ __launch_bounds__(128) void k3_finalize(
    const double* __restrict__ part, const float* __restrict__ gamma,
    const float* __restrict__ beta, float* __restrict__ stats)
{
    int o = threadIdx.x;
    double s = 0.0, s2 = 0.0;
    #pragma unroll
    for (int j = 0; j < 4; j++) { s += part[(o*4+j)*2]; s2 += part[(o*4+j)*2+1]; }
    double N = (double)(BB * HWC);
    double mean = s / N;
    double var = s2 / N - mean * mean;
    double invs = 1.0 / sqrt(var + 1e-5);
    double g = (double)gamma[o];
    stats[o*2]   = (float)(g * invs);
    stats[o*2+1] = (float)((double)beta[o] - mean * g * invs);
}

// ---------------- Kernel 4: BN + exact GELU ----------------
__global__ __launch_bounds__(256) void k4_bn_gelu(
    float* __restrict__ y, const float* __restrict__ stats)
{
    size_t idx4 = (size_t)blockIdx.x * 256 + threadIdx.x;
    float4* p = (float4*)y;
    float4 v = p[idx4];
    int o = (int)((idx4 * 4) / HWC) % DD;
    float sc = stats[o*2], sh = stats[o*2+1];
    const float inv_sqrt2 = 0.70710678118654752f;
    float g0 = fmaf(v.x, sc, sh);
    float g1 = fmaf(v.y, sc, sh);
    float g2 = fmaf(v.z, sc, sh);
    float g3 = fmaf(v.w, sc, sh);
    v.x = 0.5f * g0 * (1.f + erff(g0 * inv_sqrt2));
    v.y = 0.5f * g1 * (1.f + erff(g1 * inv_sqrt2));
    v.z = 0.5f * g2 * (1.f + erff(g2 * inv_sqrt2));
    v.w = 0.5f * g3 * (1.f + erff(g3 * inv_sqrt2));
    p[idx4] = v;
}

extern "C" void kernel_launch(void* const* d_in, const int* in_sizes, int n_in,
                              void* d_out, int out_size, void* d_ws, size_t ws_size,
                              hipStream_t stream) {
    const float* bev   = (const float*)d_in[0];
    const float* offw  = (const float*)d_in[1];
    const float* offb  = (const float*)d_in[2];
    const float* wtw   = (const float*)d_in[3];
    const float* wtb   = (const float*)d_in[4];
    const float* projw = (const float*)d_in[5];
    const float* gamma = (const float*)d_in[6];
    const float* beta  = (const float*)d_in[7];
    float* out = (float*)d_out;
    float* wsf = (float*)d_ws;

    float* oa    = wsf + OA_OFF;
    float* wtT   = wsf + WTT_OFF;
    float* wp    = wsf + WP_OFF;
    float* stats = wsf + STATS_OFF;
    double* part = (double*)(wsf + PART_OFF);
    float* bevt  = wsf + BEVT_OFF;                 // tier2 f32
    ushort* bevtb = (ushort*)(wsf + BEVT_OFF);     // full3 bf16
    ushort* aggb = (ushort*)(wsf + AGG_OFF);
    ushort* wbf  = (ushort*)(wsf + WBF_OFF);
    ushort* wcb  = (ushort*)(wsf + WCB_OFF);
    float* part2 = wsf + PART2_OFF;                // aliases bevtb (written after last read)

    bool full3 = ws_size >= WS_NEED_FULL3;
    bool big   = ws_size >= WS_NEED_BEVT;

    hipLaunchKernelGGL(k0_prep, dim3(64), dim3(256), 0, stream,
                       projw, offw, wtw, wtT, wp);
    if (full3) {
        hipLaunchKernelGGL(k0b_wbf, dim3(64), dim3(256), 0, stream, projw, wbf);
        hipLaunchKernelGGL(k0c_wcb, dim3(72), dim3(256), 0, stream, offw, wtw, wcb);
        hipLaunchKernelGGL(k2t_bf, dim3(2048), dim3(256), 0, stream, bev, bevtb);
        hipLaunchKernelGGL(k1m_conv_mfma, dim3(2048), dim3(256), 0, stream,
                           bevtb, wcb, offb, wtb, oa);
        hipLaunchKernelGGL(k2a_sample_bf, dim3(2048), dim3(256), 0, stream,
                           bevtb, oa, aggb);
        hipLaunchKernelGGL(k2b_proj, dim3(2048), dim3(256), 0, stream,
                           aggb, wbf, out, part2);
        hipLaunchKernelGGL(k3b_finalize2, dim3(128), dim3(256), 0, stream,
                           part2, gamma, beta, stats);
    } else if (big) {
        hipLaunchKernelGGL(k2t_transpose, dim3(2048), dim3(256), 0, stream, bev, bevt);
        hipLaunchKernelGGL(k1_convs, dim3(BB*HH), dim3(256), 0, stream,
                           bev, wp, offb, wtb, oa);
        hipLaunchKernelGGL(k2_sample_proj_t, dim3(BB*256), dim3(512), 0, stream,
                           bevt, oa, wtT, out);
        hipLaunchKernelGGL(k3_partial, dim3(512), dim3(256), 0, stream, out, part);
        hipLaunchKernelGGL(k3_finalize, dim3(1), dim3(128), 0, stream,
                           part, gamma, beta, stats);
    } else {
        hipLaunchKernelGGL(k1_convs, dim3(BB*HH), dim3(256), 0, stream,
                           bev, wp, offb, wtb, oa);
        hipLaunchKernelGGL(k2_sample_proj, dim3(BB*256), dim3(512), 0, stream,
                           bev, oa, wtT, out);
        hipLaunchKernelGGL(k3_partial, dim3(512), dim3(256), 0, stream, out, part);
        hipLaunchKernelGGL(k3_finalize, dim3(1), dim3(128), 0, stream,
                           part, gamma, beta, stats);
    }
    hipLaunchKernelGGL(k4_bn_gelu, dim3((BB*DD*HWC)/1024), dim3(256), 0, stream,
                       out, stats);
}

// Round 12
// 156.887 us; speedup vs baseline: 13.0896x; 1.1885x over previous
//
#include <hip/hip_runtime.h>
#include <math.h>

#define BB 2
#define DD 128
#define HH 256
#define WW 256
#define KK 4
#define HWC (HH*WW)
#define SROW2 320   // d-slice stride in S (fused fallback kernels)

typedef unsigned int u32;
typedef unsigned short ushort;
typedef __attribute__((ext_vector_type(8))) short bf16x8;
typedef __attribute__((ext_vector_type(4))) float f32x4;

// ws float layout
#define OA_OFF    0
#define WTT_OFF   1572864
#define WP_OFF    1589248
#define STATS_OFF 1603072
#define PART_OFF  1603392
#define BEVT_OFF  1605440       // full3: bevtb bf16 (16.8M ushort); tier2: f32 bevt
#define PACC_OFF  18382656
#define PART2_OFF PACC_OFF      // full3: k2f block stats (2*128*2048 f32) - NOT aliasing bevtb
#define WBF_OFF   26771264      // proj W bf16
#define WCB_OFF   26779456      // conv W bf16 padded: 9*16*128 ushort
#define WS_NEED_BEVT  ((size_t)PACC_OFF * 4)
#define WS_NEED_FULL3 ((size_t)(WCB_OFF + 9216) * 4)

__device__ __forceinline__ u32 f2bf(float x) {
    u32 u = __builtin_bit_cast(u32, x);
    return (u + 0x7fffu + ((u >> 16) & 1u)) >> 16;
}
__device__ __forceinline__ u32 pkbf(float a, float b) {
    return f2bf(a) | (f2bf(b) << 16);
}
__device__ __forceinline__ float bflo(u32 d) { return __builtin_bit_cast(float, d << 16); }
__device__ __forceinline__ float bfhi(u32 d) { return __builtin_bit_cast(float, d & 0xffff0000u); }

// ---------------- Kernel 0: weight prep (fallback tiers only) ----------------
__global__ __launch_bounds__(256) void k0_prep(
    const float* __restrict__ projw, const float* __restrict__ offw,
    const float* __restrict__ wtw, float* __restrict__ wtT, float* __restrict__ wp)
{
    int idx = blockIdx.x * 256 + threadIdx.x;
    if (idx < 16384) {
        int d = idx >> 7, o = idx & 127;
        wtT[d * 128 + o] = projw[o * 128 + d];
    }
    if (idx < 13824) {
        int c = idx / 108; int r = idx % 108; int o = r / 9; int t = r % 9;
        wp[idx] = (o < 8) ? offw[(o*128 + c)*9 + t] : wtw[((o-8)*128 + c)*9 + t];
    }
}

// ---------------- Kernel 0bc: bf16 weight prep (proj + conv), merged ----------------
__global__ __launch_bounds__(256) void k0bc(
    const float* __restrict__ projw, const float* __restrict__ offw,
    const float* __restrict__ wtw, ushort* __restrict__ wbf,
    ushort* __restrict__ wcb)
{
    int idx = blockIdx.x * 256 + threadIdx.x;
    if (idx < 16384) wbf[idx] = (ushort)f2bf(projw[idx]);
    if (idx < 18432) {
        int tap = idx >> 11;
        int rem = idx & 2047;
        int oo = rem >> 7, c = rem & 127;
        float v = 0.f;
        if (oo < 8)       v = offw[(oo*128 + c)*9 + tap];
        else if (oo < 12) v = wtw[((oo-8)*128 + c)*9 + tap];
        wcb[idx] = (ushort)f2bf(v);
    }
}

// ---------------- Kernel Tb: NCHW f32 -> NHWC bf16 ----------------
__global__ __launch_bounds__(256) void k2t_bf(
    const float* __restrict__ bev, ushort* __restrict__ bevtb)
{
    __shared__ float T[64 * 128];
    int tid = threadIdx.x;
    int bidx = blockIdx.x;
    int b = bidx >> 10;
    int rem = bidx & 1023;
    int yrow = rem >> 2;
    int x0 = (rem & 3) << 6;

    const float* src = bev + ((size_t)b * DD) * HWC + (size_t)yrow * WW + x0;
    #pragma unroll 4
    for (int k = 0; k < 32; k++) {
        int flat = k * 256 + tid;
        int d = flat >> 6, xl = flat & 63;
        float v = src[(size_t)d * HWC + xl];
        T[xl * 128 + (((d >> 2) ^ (xl & 31)) << 2) + (d & 3)] = v;
    }
    __syncthreads();
    ushort* dst = bevtb + (((size_t)b * HH + yrow) * WW + x0) * 128;
    #pragma unroll 4
    for (int k = 0; k < 8; k++) {
        int flat = k * 256 + tid;
        int d4 = flat & 31, xl = (flat >> 5) & 63;
        float4 v = *(const float4*)&T[xl * 128 + ((d4 ^ (xl & 31)) << 2)];
        uint2 pk;
        pk.x = pkbf(v.x, v.y);
        pk.y = pkbf(v.z, v.w);
        *(uint2*)(dst + (size_t)xl * 128 + (d4 << 2)) = pk;
    }
}

// ---------------- Kernel 1m: 3x3 convs as implicit-GEMM MFMA, LDS-staged ----------------
__global__ __launch_bounds__(256) void k1m_conv_mfma(
    const ushort* __restrict__ bevtb, const ushort* __restrict__ wcb,
    const float* __restrict__ offb, const float* __restrict__ wtb,
    float* __restrict__ oa)
{
    __shared__ uint4 lds4[3168];   // 3 rows x 66 px x 16 slots x 16B = 50688 B

    int tid = threadIdx.x;
    int wv = tid >> 6;
    int l = tid & 63;
    int lm = l & 15, lk = l >> 4;
    int wgid = blockIdx.x;
    int lin = (wgid & 7) * 256 + (wgid >> 3);   // bijective XCD-contiguous remap
    int b = lin >> 10;
    int i = (lin >> 2) & 255;
    int jt = lin & 3;
    int x0 = jt * 64;

    const ushort* bb = bevtb + (size_t)b * HWC * 128;
    for (int z = tid; z < 3168; z += 256) {
        int row = z / 1056;
        int rem = z - row * 1056;
        int pl = rem >> 4;
        int q  = rem & 15;
        int yy = i - 1 + row;
        int x  = x0 - 1 + pl;
        bool ok = ((unsigned)yy < HH) && ((unsigned)x < WW);
        uint4 v = make_uint4(0u, 0u, 0u, 0u);
        if (ok) v = *(const uint4*)(bb + ((size_t)(yy * WW + x) << 7) + q * 8);
        lds4[row * 1056 + pl * 16 + (q ^ (pl & 15))] = v;
    }
    __syncthreads();

    f32x4 acc = (f32x4)(0.f);
    #pragma unroll
    for (int dy = 0; dy < 3; dy++) {
        #pragma unroll
        for (int dx = 0; dx < 3; dx++) {
            int pl = wv * 16 + lm + dx;
            const uint4* bp = &lds4[dy * 1056 + pl * 16];
            int sx = pl & 15;
            const ushort* ap = wcb + (size_t)((dy*3 + dx) * 16 + lm) * 128 + lk * 8;
            #pragma unroll
            for (int kk = 0; kk < 4; kk++) {
                bf16x8 bfr = *(const bf16x8*)&bp[(kk*4 + lk) ^ sx];
                bf16x8 afr = *(const bf16x8*)(ap + kk * 32);
                acc = __builtin_amdgcn_mfma_f32_16x16x32_bf16(afr, bfr, acc, 0, 0, 0);
            }
        }
    }

    float v[4];
    #pragma unroll
    for (int r = 0; r < 4; r++) v[r] = acc[r];

    int j = x0 + wv * 16 + lm;
    if (lk < 2) {
        #pragma unroll
        for (int r = 0; r < 4; r++) v[r] += offb[lk*4 + r];   // OFFSET_SCALE = 1.0
    } else if (lk == 2) {
        float l4[4];
        #pragma unroll
        for (int r = 0; r < 4; r++) l4[r] = v[r] + wtb[r];
        float m = fmaxf(fmaxf(l4[0], l4[1]), fmaxf(l4[2], l4[3]));
        float e[4]; float se = 0.f;
        #pragma unroll
        for (int r = 0; r < 4; r++) { e[r] = expf(l4[r] - m); se += e[r]; }
        float inv = 1.f / se;
        #pragma unroll
        for (int r = 0; r < 4; r++) v[r] = e[r] * inv;
    }
    if (lk < 3) {
        size_t basep = (size_t)b * 12 * HWC + (size_t)i * WW + j;
        #pragma unroll
        for (int r = 0; r < 4; r++)
            oa[basep + (size_t)(lk*4 + r) * HWC] = v[r];
    }
}

// ---------------- Kernel 2f: FUSED deformable sample + 1x1 MFMA proj + BN stats ----------------
// Block = 64 consecutive linear pixels (p constant, q span 64) -> tight gather footprint.
// Phase 1 (gather): thread = (pixel, d-quarter), k2a's proven identity; packed bf16
// result staged to 16KB swizzled LDS P[pix][slot^(pix&15)] (k1m's scheme: 2-way banks
// both sides).  Phase 2 (GEMM): k2b's proven identity, B-frags via ds_read_b128 from
// LDS; y write + in-register BN partial stats.  Kills the 35MB agg write + 33.5MB
// re-read of the split version.  part2 lives in the PACC region (NOT bevtb - the
// fused kernel reads bevtb, so the old alias would race).
__global__ __launch_bounds__(256) void k2f_sample_proj(
    const ushort* __restrict__ bevtb, const float* __restrict__ oa,
    const ushort* __restrict__ wbf, float* __restrict__ y,
    float* __restrict__ part2)
{
    __shared__ uint4 P[64 * 16];   // 16 KB

    int tid = threadIdx.x;
    int wgid = blockIdx.x;
    int lin = (wgid & 7) * 256 + (wgid >> 3);   // bijective XCD-contiguous remap
    int b = lin >> 10;
    int pix0 = (lin & 1023) << 6;

    // ---- gather phase ----
    int q4 = tid & 3;
    int pixl = tid >> 2;
    int pix = pix0 + pixl;
    int p = pix >> 8;
    int q = pix & 255;

    const float* ob = oa + (size_t)b * 12 * HWC + (size_t)p * WW + q;
    unsigned pa[8]; float cw[16];
    #pragma unroll
    for (int k = 0; k < 4; k++) {
        float dx = ob[(size_t)(2*k)   * HWC];
        float dy = ob[(size_t)(2*k+1) * HWC];
        float a  = ob[(size_t)(8+k)   * HWC];
        float x  = fminf(fmaxf((float)p + dx, 0.f), (float)(WW-1));
        float yv = fminf(fmaxf((float)q + dy, 0.f), (float)(HH-1));
        float x0f = floorf(x); float y0f = floorf(yv);
        int x0 = (int)x0f; int y0 = (int)y0f;
        int x1 = min(x0 + 1, WW - 1); int y1 = min(y0 + 1, HH - 1);
        float wx = x - x0f; float wy = yv - y0f;
        pa[k*2+0] = (unsigned)(y0*WW + x0) | ((unsigned)(y0*WW + x1) << 16);
        pa[k*2+1] = (unsigned)(y1*WW + x0) | ((unsigned)(y1*WW + x1) << 16);
        cw[k*4+0] = a * (1.f - wx) * (1.f - wy);
        cw[k*4+1] = a * wx * (1.f - wy);
        cw[k*4+2] = a * (1.f - wx) * wy;
        cw[k*4+3] = a * wx * wy;
    }

    const ushort* bt = bevtb + (size_t)b * HWC * 128 + q4 * 8;

    float s[4][8];
    #pragma unroll
    for (int c = 0; c < 4; c++)
        #pragma unroll
        for (int e = 0; e < 8; e++) s[c][e] = 0.f;

    #pragma unroll
    for (int t = 0; t < 16; t++) {
        unsigned a01 = pa[t >> 1];
        unsigned gp = (t & 1) ? (a01 >> 16) : (a01 & 0xffffu);
        const ushort* tp = bt + ((size_t)gp << 7);
        float w = cw[t];
        #pragma unroll
        for (int c = 0; c < 4; c++) {
            uint4 v = *(const uint4*)(tp + c * 32);
            s[c][0] = fmaf(w, bflo(v.x), s[c][0]);
            s[c][1] = fmaf(w, bfhi(v.x), s[c][1]);
            s[c][2] = fmaf(w, bflo(v.y), s[c][2]);
            s[c][3] = fmaf(w, bfhi(v.y), s[c][3]);
            s[c][4] = fmaf(w, bflo(v.z), s[c][4]);
            s[c][5] = fmaf(w, bfhi(v.z), s[c][5]);
            s[c][6] = fmaf(w, bflo(v.w), s[c][6]);
            s[c][7] = fmaf(w, bfhi(v.w), s[c][7]);
        }
    }

    int sxr = pixl & 15;
    #pragma unroll
    for (int c = 0; c < 4; c++) {
        uint4 pk;
        pk.x = pkbf(s[c][0], s[c][1]);
        pk.y = pkbf(s[c][2], s[c][3]);
        pk.z = pkbf(s[c][4], s[c][5]);
        pk.w = pkbf(s[c][6], s[c][7]);
        P[pixl * 16 + ((c * 4 + q4) ^ sxr)] = pk;
    }
    __syncthreads();

    // ---- GEMM phase ----
    int wv = tid >> 6;
    int l = tid & 63;
    int lm = l & 15, lk = l >> 4;
    int o0 = wv << 5;

    bf16x8 a[2][4];
    const ushort* wbase = wbf + (size_t)(o0 + lm) * 128 + lk * 8;
    #pragma unroll
    for (int ot = 0; ot < 2; ot++)
        #pragma unroll
        for (int kk = 0; kk < 4; kk++)
            a[ot][kk] = *(const bf16x8*)(wbase + ot * 16 * 128 + kk * 32);

    f32x4 acc[2][4];
    #pragma unroll
    for (int ot = 0; ot < 2; ot++)
        #pragma unroll
        for (int nt = 0; nt < 4; nt++)
            acc[ot][nt] = (f32x4)(0.f);

    #pragma unroll
    for (int nt = 0; nt < 4; nt++) {
        int row = nt * 16 + lm;
        bf16x8 bfr[4];
        #pragma unroll
        for (int kk = 0; kk < 4; kk++)
            bfr[kk] = *(const bf16x8*)&P[row * 16 + ((kk * 4 + lk) ^ lm)];
        #pragma unroll
        for (int ot = 0; ot < 2; ot++)
            #pragma unroll
            for (int kk = 0; kk < 4; kk++)
                acc[ot][nt] = __builtin_amdgcn_mfma_f32_16x16x32_bf16(
                    a[ot][kk], bfr[kk], acc[ot][nt], 0, 0, 0);
    }

    #pragma unroll
    for (int ot = 0; ot < 2; ot++)
        #pragma unroll
        for (int nt = 0; nt < 4; nt++)
            #pragma unroll
            for (int r = 0; r < 4; r++)
                y[((size_t)b * DD + o0 + ot * 16 + lk * 4 + r) * HWC + pix0 + nt * 16 + lm]
                    = acc[ot][nt][r];

    // ---- fused BN partial stats over this block's 64 pixels ----
    float sm[2][4], sq[2][4];
    #pragma unroll
    for (int ot = 0; ot < 2; ot++)
        #pragma unroll
        for (int r = 0; r < 4; r++) { sm[ot][r] = 0.f; sq[ot][r] = 0.f; }
    #pragma unroll
    for (int ot = 0; ot < 2; ot++)
        #pragma unroll
        for (int nt = 0; nt < 4; nt++)
            #pragma unroll
            for (int r = 0; r < 4; r++) {
                float v = acc[ot][nt][r];
                sm[ot][r] += v;
                sq[ot][r] = fmaf(v, v, sq[ot][r]);
            }
    #pragma unroll
    for (int m = 1; m < 16; m <<= 1) {
        #pragma unroll
        for (int ot = 0; ot < 2; ot++)
            #pragma unroll
            for (int r = 0; r < 4; r++) {
                sm[ot][r] += __shfl_xor(sm[ot][r], m);
                sq[ot][r] += __shfl_xor(sq[ot][r], m);
            }
    }
    if (lm == 0) {
        #pragma unroll
        for (int ot = 0; ot < 2; ot++)
            #pragma unroll
            for (int r = 0; r < 4; r++) {
                int o = o0 + ot * 16 + lk * 4 + r;
                part2[(size_t)o * 2048 + wgid] = sm[ot][r];
                part2[(size_t)128 * 2048 + (size_t)o * 2048 + wgid] = sq[ot][r];
            }
    }
}

// ---------------- Kernel 3b': finalize BN from k2f block partials ----------------
__global__ __launch_bounds__(256) void k3b_finalize2(
    const float* __restrict__ part2, const float* __restrict__ gamma,
    const float* __restrict__ beta, float* __restrict__ stats)
{
    int o = blockIdx.x; int tid = threadIdx.x;
    const float* ps = part2 + (size_t)o * 2048;
    const float* pq = part2 + (size_t)128 * 2048 + (size_t)o * 2048;
    double s = 0.0, s2 = 0.0;
    for (int i = tid; i < 2048; i += 256) { s += (double)ps[i]; s2 += (double)pq[i]; }
    __shared__ double ls[256], ls2[256];
    ls[tid] = s; ls2[tid] = s2;
    __syncthreads();
    for (int off = 128; off > 0; off >>= 1) {
        if (tid < off) { ls[tid] += ls[tid+off]; ls2[tid] += ls2[tid+off]; }
        __syncthreads();
    }
    if (tid == 0) {
        double N = (double)(BB * HWC);
        double mean = ls[0] / N;
        double var = ls2[0] / N - mean * mean;
        double invs = 1.0 / sqrt(var + 1e-5);
        double g = (double)gamma[o];
        stats[o*2]   = (float)(g * invs);
        stats[o*2+1] = (float)((double)beta[o] - mean * g * invs);
    }
}

// ---------------- Kernel 1 (tier2 fallback): full 128-channel conv ----------------
__global__ __launch_bounds__(256) void k1_convs(
    const float* __restrict__ bev, const float* __restrict__ wp,
    const float* __restrict__ offb, const float* __restrict__ wtb,
    float* __restrict__ oa)
{
    __shared__ float rows[2][3][260];
    int tid = threadIdx.x;
    int p = blockIdx.x;
    int b = p / HH; int i = p % HH; int j = tid;
    const float* bb = bev + (size_t)b * DD * HWC;

    if (tid < 12) { int bf = tid / 6, r = tid % 6; rows[bf][r >> 1][(r & 1) ? 257 : 0] = 0.f; }
    #pragma unroll
    for (int l = 0; l < 3; l++) {
        int yy = i + l - 1;
        rows[0][l][1 + tid] = ((unsigned)yy < HH) ? bb[yy * WW + tid] : 0.f;
    }
    __syncthreads();

    float acc[12];
    #pragma unroll
    for (int o = 0; o < 12; o++) acc[o] = 0.f;

    for (int c = 0; c < 128; c++) {
        int cb = c & 1, nb = cb ^ 1;
        float rv[3];
        if (c < 127) {
            const float* pln = bb + (size_t)(c + 1) * HWC;
            #pragma unroll
            for (int l = 0; l < 3; l++) {
                int yy = i + l - 1;
                rv[l] = ((unsigned)yy < HH) ? pln[yy * WW + tid] : 0.f;
            }
        }
        float v[9];
        #pragma unroll
        for (int dy = 0; dy < 3; dy++)
            #pragma unroll
            for (int dx = 0; dx < 3; dx++)
                v[dy*3 + dx] = rows[cb][dy][tid + dx];
        const float* wc = wp + c * 108;
        #pragma unroll
        for (int o = 0; o < 12; o++) {
            float s = acc[o];
            #pragma unroll
            for (int t = 0; t < 9; t++) s = fmaf(wc[o*9 + t], v[t], s);
            acc[o] = s;
        }
        if (c < 127) {
            #pragma unroll
            for (int l = 0; l < 3; l++) rows[nb][l][1 + tid] = rv[l];
        }
        __syncthreads();
    }

    float outv[12];
    #pragma unroll
    for (int o = 0; o < 8; o++) outv[o] = acc[o] + offb[o];
    float l4[4];
    #pragma unroll
    for (int k = 0; k < 4; k++) l4[k] = acc[8+k] + wtb[k];
    float m = fmaxf(fmaxf(l4[0], l4[1]), fmaxf(l4[2], l4[3]));
    float e[4]; float se = 0.f;
    #pragma unroll
    for (int k = 0; k < 4; k++) { e[k] = expf(l4[k] - m); se += e[k]; }
    float inv = 1.f / se;
    #pragma unroll
    for (int k = 0; k < 4; k++) outv[8+k] = e[k] * inv;

    size_t basep = (size_t)b * 12 * HWC + (size_t)i * WW + j;
    #pragma unroll
    for (int o = 0; o < 12; o++) oa[basep + (size_t)o * HWC] = outv[o];
}

// ---------------- Kernel T (tier2): NCHW -> NHWC f32 transpose ----------------
__global__ __launch_bounds__(256) void k2t_transpose(
    const float* __restrict__ bev, float* __restrict__ bevt)
{
    __shared__ float T[64 * 128];
    int tid = threadIdx.x;
    int bidx = blockIdx.x;
    int b = bidx >> 10;
    int rem = bidx & 1023;
    int yrow = rem >> 2;
    int x0 = (rem & 3) << 6;

    const float* src = bev + ((size_t)b * DD) * HWC + (size_t)yrow * WW + x0;
    #pragma unroll 4
    for (int k = 0; k < 32; k++) {
        int flat = k * 256 + tid;
        int d = flat >> 6, xl = flat & 63;
        float v = src[(size_t)d * HWC + xl];
        T[xl * 128 + (((d >> 2) ^ (xl & 31)) << 2) + (d & 3)] = v;
    }
    __syncthreads();
    float* dst = bevt + (((size_t)b * HH + yrow) * WW + x0) * 128;
    #pragma unroll 4
    for (int k = 0; k < 8; k++) {
        int flat = k * 256 + tid;
        int d4 = flat & 31, xl = (flat >> 5) & 63;
        float4 v = *(const float4*)&T[xl * 128 + ((d4 ^ (xl & 31)) << 2)];
        *(float4*)(dst + (size_t)xl * 128 + (d4 << 2)) = v;
    }
}

// ---------------- Kernel 2 fused fallback (tier2, NHWC f32) ----------------
__global__ __launch_bounds__(512, 2) void k2_sample_proj_t(
    const float* __restrict__ bevt, const float* __restrict__ oa,
    const float* __restrict__ wt, float* __restrict__ y)
{
    __shared__ float S[2][16 * SROW2];

    int tid = threadIdx.x;
    int bidx = blockIdx.x;
    int b  = bidx >> 8;
    int p0 = ((bidx >> 4) & 15) * 16;
    int q0 = (bidx & 15) * 16;

    int gpix = tid >> 1;
    int gp = gpix & 15;
    int gq = gpix >> 4;
    int dgrp = tid & 1;
    int swr = gp * 20 + gq;

    int wv = tid >> 6;
    int wvu = __builtin_amdgcn_readfirstlane(wv);
    int lane = tid & 63;
    int lp = lane >> 2;
    int q4 = (lane & 3) << 2;
    int soff = lp * 20 + q4;

    const float* ob = oa + (size_t)b * 12 * HWC + (size_t)(p0 + gp) * WW + (q0 + gq);
    unsigned pa[8]; float cw[16];
    #pragma unroll
    for (int k = 0; k < 4; k++) {
        float dx = ob[(size_t)(2*k)   * HWC];
        float dy = ob[(size_t)(2*k+1) * HWC];
        float a  = ob[(size_t)(8+k)   * HWC];
        float x  = fminf(fmaxf((float)(p0 + gp) + dx, 0.f), (float)(WW-1));
        float yv = fminf(fmaxf((float)(q0 + gq) + dy, 0.f), (float)(HH-1));
        float x0f = floorf(x); float y0f = floorf(yv);
        int x0 = (int)x0f; int y0 = (int)y0f;
        int x1 = min(x0 + 1, WW - 1); int y1 = min(y0 + 1, HH - 1);
        float wx = x - x0f; float wy = yv - y0f;
        pa[k*2+0] = (unsigned)(y0*WW + x0) | ((unsigned)(y0*WW + x1) << 16);
        pa[k*2+1] = (unsigned)(y1*WW + x0) | ((unsigned)(y1*WW + x1) << 16);
        cw[k*4+0] = a * (1.f - wx) * (1.f - wy);
        cw[k*4+1] = a * wx * (1.f - wy);
        cw[k*4+2] = a * (1.f - wx) * wy;
        cw[k*4+3] = a * wx * wy;
    }

    const float* bt = bevt + (size_t)b * HWC * 128 + dgrp * 8;

    float acc[64];
    #pragma unroll
    for (int t = 0; t < 64; t++) acc[t] = 0.f;

    {
        float4 s0 = make_float4(0,0,0,0), s1 = make_float4(0,0,0,0);
        #pragma unroll
        for (int t = 0; t < 16; t++) {
            unsigned pix = (t & 1) ? (pa[t >> 1] >> 16) : (pa[t >> 1] & 0xffffu);
            const float4* tp = (const float4*)(bt + ((size_t)pix << 7));
            float4 va = tp[0], vb = tp[1];
            float c = cw[t];
            s0.x = fmaf(c, va.x, s0.x); s0.y = fmaf(c, va.y, s0.y);
            s0.z = fmaf(c, va.z, s0.z); s0.w = fmaf(c, va.w, s0.w);
            s1.x = fmaf(c, vb.x, s1.x); s1.y = fmaf(c, vb.y, s1.y);
            s1.z = fmaf(c, vb.z, s1.z); s1.w = fmaf(c, vb.w, s1.w);
        }
        int r = dgrp * 8;
        S[0][(r+0)*SROW2 + swr] = s0.x; S[0][(r+1)*SROW2 + swr] = s0.y;
        S[0][(r+2)*SROW2 + swr] = s0.z; S[0][(r+3)*SROW2 + swr] = s0.w;
        S[0][(r+4)*SROW2 + swr] = s1.x; S[0][(r+5)*SROW2 + swr] = s1.y;
        S[0][(r+6)*SROW2 + swr] = s1.z; S[0][(r+7)*SROW2 + swr] = s1.w;
    }
    __syncthreads();

    for (int c = 0; c < 8; c++) {
        int cur = c & 1;
        const float* Sc = &S[cur][0];
        float* Sn = &S[cur ^ 1][0];
        int d0 = c * 16;
        int dn = d0 + 16;
        bool more = (c < 7);

        float4 g0 = make_float4(0,0,0,0), g1 = make_float4(0,0,0,0);
        float4 pf0, pf1;
        if (more) {
            unsigned pix = pa[0] & 0xffffu;
            const float4* tp = (const float4*)(bt + ((size_t)pix << 7) + dn);
            pf0 = tp[0]; pf1 = tp[1];
        }

        #pragma unroll
        for (int dl = 0; dl < 16; dl++) {
            float4 cur0 = pf0, cur1 = pf1;
            if (more && dl < 15) {
                int t = dl + 1;
                unsigned pix = (t & 1) ? (pa[t >> 1] >> 16) : (pa[t >> 1] & 0xffffu);
                const float4* tp = (const float4*)(bt + ((size_t)pix << 7) + dn);
                pf0 = tp[0]; pf1 = tp[1];
            }

            float4 sv = *(const float4*)(Sc + dl * SROW2 + soff);
            const float4* wq = (const float4*)(wt + (size_t)(d0 + dl) * 128 + wvu * 16);
            #pragma unroll
            for (int oi4 = 0; oi4 < 4; oi4++) {
                float4 w4 = wq[oi4];
                int ob4 = oi4 * 16;
                acc[ob4+ 0] = fmaf(w4.x, sv.x, acc[ob4+ 0]);
                acc[ob4+ 1] = fmaf(w4.x, sv.y, acc[ob4+ 1]);
                acc[ob4+ 2] = fmaf(w4.x, sv.z, acc[ob4+ 2]);
                acc[ob4+ 3] = fmaf(w4.x, sv.w, acc[ob4+ 3]);
                acc[ob4+ 4] = fmaf(w4.y, sv.x, acc[ob4+ 4]);
                acc[ob4+ 5] = fmaf(w4.y, sv.y, acc[ob4+ 5]);
                acc[ob4+ 6] = fmaf(w4.y, sv.z, acc[ob4+ 6]);
                acc[ob4+ 7] = fmaf(w4.y, sv.w, acc[ob4+ 7]);
                acc[ob4+ 8] = fmaf(w4.z, sv.x, acc[ob4+ 8]);
                acc[ob4+ 9] = fmaf(w4.z, sv.y, acc[ob4+ 9]);
                acc[ob4+10] = fmaf(w4.z, sv.z, acc[ob4+10]);
                acc[ob4+11] = fmaf(w4.z, sv.w, acc[ob4+11]);
                acc[ob4+12] = fmaf(w4.w, sv.x, acc[ob4+12]);
                acc[ob4+13] = fmaf(w4.w, sv.y, acc[ob4+13]);
                acc[ob4+14] = fmaf(w4.w, sv.z, acc[ob4+14]);
                acc[ob4+15] = fmaf(w4.w, sv.w, acc[ob4+15]);
            }

            if (more) {
                float cwt = cw[dl];
                g0.x = fmaf(cwt, cur0.x, g0.x); g0.y = fmaf(cwt, cur0.y, g0.y);
                g0.z = fmaf(cwt, cur0.z, g0.z); g0.w = fmaf(cwt, cur0.w, g0.w);
                g1.x = fmaf(cwt, cur1.x, g1.x); g1.y = fmaf(cwt, cur1.y, g1.y);
                g1.z = fmaf(cwt, cur1.z, g1.z); g1.w = fmaf(cwt, cur1.w, g1.w);
            }
        }

        if (more) {
            int r = dgrp * 8;
            Sn[(r+0)*SROW2 + swr] = g0.x; Sn[(r+1)*SROW2 + swr] = g0.y;
            Sn[(r+2)*SROW2 + swr] = g0.z; Sn[(r+3)*SROW2 + swr] = g0.w;
            Sn[(r+4)*SROW2 + swr] = g1.x; Sn[(r+5)*SROW2 + swr] = g1.y;
            Sn[(r+6)*SROW2 + swr] = g1.z; Sn[(r+7)*SROW2 + swr] = g1.w;
        }
        __syncthreads();
    }

    size_t base = (size_t)b * DD * HWC + (size_t)(p0 + lp) * WW + (q0 + q4);
    #pragma unroll
    for (int oi = 0; oi < 16; oi++) {
        int o = wv * 16 + oi;
        float4 v = make_float4(acc[oi*4+0], acc[oi*4+1], acc[oi*4+2], acc[oi*4+3]);
        *(float4*)(y + base + (size_t)o * HWC) = v;
    }
}

// ---------------- Kernel 2 fallback (tier3, NCHW) ----------------
__global__ __launch_bounds__(512, 2) void k2_sample_proj(
    const float* __restrict__ bev, const float* __restrict__ oa,
    const float* __restrict__ wt, float* __restrict__ y)
{
    __shared__ float S[2][16 * SROW2];
    int tid = threadIdx.x;
    int bidx = blockIdx.x;
    int b  = bidx >> 8;
    int p0 = ((bidx >> 4) & 15) * 16;
    int q0 = (bidx & 15) * 16;
    int pix = tid & 255;
    int gq = pix >> 4;
    int gp = pix & 15;
    int dgrp = tid >> 8;
    int swr = gp * 20 + gq;
    int wv = tid >> 6;
    int wvu = __builtin_amdgcn_readfirstlane(wv);
    int lane = tid & 63;
    int lp = lane >> 2;
    int q4 = (lane & 3) << 2;
    int soff = lp * 20 + q4;

    const float* ob = oa + (size_t)b * 12 * HWC + (size_t)(p0 + gp) * WW + (q0 + gq);
    unsigned pa[8]; float cw[16];
    #pragma unroll
    for (int k = 0; k < 4; k++) {
        float dx = ob[(size_t)(2*k)   * HWC];
        float dy = ob[(size_t)(2*k+1) * HWC];
        float a  = ob[(size_t)(8+k)   * HWC];
        float x  = fminf(fmaxf((float)(p0 + gp) + dx, 0.f), (float)(WW-1));
        float yv = fminf(fmaxf((float)(q0 + gq) + dy, 0.f), (float)(HH-1));
        float x0f = floorf(x); float y0f = floorf(yv);
        int x0 = (int)x0f; int y0 = (int)y0f;
        int x1 = min(x0 + 1, WW - 1); int y1 = min(y0 + 1, HH - 1);
        float wx = x - x0f; float wy = yv - y0f;
        pa[k*2+0] = (unsigned)(y0*WW + x0) | ((unsigned)(y0*WW + x1) << 16);
        pa[k*2+1] = (unsigned)(y1*WW + x0) | ((unsigned)(y1*WW + x1) << 16);
        cw[k*4+0] = a * (1.f - wx) * (1.f - wy);
        cw[k*4+1] = a * wx * (1.f - wy);
        cw[k*4+2] = a * (1.f - wx) * wy;
        cw[k*4+3] = a * wx * wy;
    }
    const float* bb = bev + (size_t)b * DD * HWC;
    float acc[64];
    #pragma unroll
    for (int t = 0; t < 64; t++) acc[t] = 0.f;
    #pragma unroll
    for (int dd = 0; dd < 8; dd++) {
        const float* pl = bb + (size_t)(dgrp*8 + dd) * HWC;
        float s = 0.f;
        #pragma unroll
        for (int t = 0; t < 8; t++) {
            unsigned a01 = pa[t];
            s = fmaf(cw[2*t],   pl[a01 & 0xffffu], s);
            s = fmaf(cw[2*t+1], pl[a01 >> 16], s);
        }
        S[0][(dgrp*8 + dd) * SROW2 + swr] = s;
    }
    __syncthreads();
    for (int c = 0; c < 8; c++) {
        int cur = c & 1;
        const float* Sc = &S[cur][0];
        float* Sn = &S[cur ^ 1][0];
        int d0 = c * 16;
        int d0n = d0 + 16;
        bool more = (c < 7);
        #pragma unroll
        for (int dl = 0; dl < 16; dl++) {
            if (dl < 8) {
                if (more) {
                    const float* pl = bb + (size_t)(d0n + dgrp*8 + dl) * HWC;
                    float s = 0.f;
                    #pragma unroll
                    for (int t = 0; t < 8; t++) {
                        unsigned a01 = pa[t];
                        s = fmaf(cw[2*t],   pl[a01 & 0xffffu], s);
                        s = fmaf(cw[2*t+1], pl[a01 >> 16], s);
                    }
                    Sn[(dgrp*8 + dl) * SROW2 + swr] = s;
                }
            }
            float4 sv = *(const float4*)(Sc + dl * SROW2 + soff);
            const float4* wq = (const float4*)(wt + (size_t)(d0 + dl) * 128 + wvu * 16);
            #pragma unroll
            for (int oi4 = 0; oi4 < 4; oi4++) {
                float4 w4 = wq[oi4];
                int ob4 = oi4 * 16;
                acc[ob4+ 0] = fmaf(w4.x, sv.x, acc[ob4+ 0]);
                acc[ob4+ 1] = fmaf(w4.x, sv.y, acc[ob4+ 1]);
                acc[ob4+ 2] = fmaf(w4.x, sv.z, acc[ob4+ 2]);
                acc[ob4+ 3] = fmaf(w4.x, sv.w, acc[ob4+ 3]);
                acc[ob4+ 4] = fmaf(w4.y, sv.x, acc[ob4+ 4]);
                acc[ob4+ 5] = fmaf(w4.y, sv.y, acc[ob4+ 5]);
                acc[ob4+ 6] = fmaf(w4.y, sv.z, acc[ob4+ 6]);
                acc[ob4+ 7] = fmaf(w4.y, sv.w, acc[ob4+ 7]);
                acc[ob4+ 8] = fmaf(w4.z, sv.x, acc[ob4+ 8]);
                acc[ob4+ 9] = fmaf(w4.z, sv.y, acc[ob4+ 9]);
                acc[ob4+10] = fmaf(w4.z, sv.z, acc[ob4+10]);
                acc[ob4+11] = fmaf(w4.z, sv.w, acc[ob4+11]);
                acc[ob4+12] = fmaf(w4.w, sv.x, acc[ob4+12]);
                acc[ob4+13] = fmaf(w4.w, sv.y, acc[ob4+13]);
                acc[ob4+14] = fmaf(w4.w, sv.z, acc[ob4+14]);
                acc[ob4+15] = fmaf(w4.w, sv.w, acc[ob4+15]);
            }
        }
        __syncthreads();
    }
    size_t base = (size_t)b * DD * HWC + (size_t)(p0 + lp) * WW + (q0 + q4);
    #pragma unroll
    for (int oi = 0; oi < 16; oi++) {
        int o = wv * 16 + oi;
        float4 v = make_float4(acc[oi*4+0], acc[oi*4+1], acc[oi*4+2], acc[oi*4+3]);
        *(float4*)(y + base + (size_t)o * HWC) = v;
    }
}

// ---------------- Kernel 3a/3b: BN stats (fallback tiers only) ----------------
__global__ __launch_bounds__(256) void k3_partial(
    const float* __restrict__ y, double* __restrict__ part)
{
    int blk = blockIdx.x;
    int o = blk >> 2; int sub = blk & 3; int b = sub >> 1; int half = sub & 1;
    const float4* pl = (const float4*)(y + ((size_t)b * DD + o) * HWC + half * (HWC/2));
    int tid = threadIdx.x;
    double s = 0.0, s2 = 0.0;
    for (int idx = tid; idx < HWC/8; idx += 256) {
        float4 v = pl[idx];
        s  += (double)v.x + (double)v.y + (double)v.z + (double)v.w;
        s2 += (double)v.x*v.x + (double)v.y*v.y + (double)v.z*v.z + (double)v.w*v.w;
    }
    __shared__ double ls[256], ls2[256];
    ls[tid] = s; ls2[tid] = s2;
    __syncthreads();
    for (int off = 128; off > 0; off >>= 1) {
        if (tid < off) { ls[tid] += ls[tid+off]; ls2[tid] += ls2[tid+off]; }
        __syncthreads();
    }
    if (tid == 0) { part[blk*2] = ls[0]; part[blk*2+1] = ls2[0]; }
}

__global__ __launch_bounds__(128) void k3_finalize(
    const double* __restrict__ part, const float* __restrict__ gamma,
    const float* __restrict__ beta, float* __restrict__ stats)
{
    int o = threadIdx.x;
    double s = 0.0, s2 = 0.0;
    #pragma unroll
    for (int j = 0; j < 4; j++) { s += part[(o*4+j)*2]; s2 += part[(o*4+j)*2+1]; }
    double N = (double)(BB * HWC);
    double mean = s / N;
    double var = s2 / N - mean * mean;
    double invs = 1.0 / sqrt(var + 1e-5);
    double g = (double)gamma[o];
    stats[o*2]   = (float)(g * invs);
    stats[o*2+1] = (float)((double)beta[o] - mean * g * invs);
}

// ---------------- Kernel 4: BN + exact GELU ----------------
__global__ __launch_bounds__(256) void k4_bn_gelu(
    float* __restrict__ y, const float* __restrict__ stats)
{
    size_t idx4 = (size_t)blockIdx.x * 256 + threadIdx.x;
    float4* p = (float4*)y;
    float4 v = p[idx4];
    int o = (int)((idx4 * 4) / HWC) % DD;
    float sc = stats[o*2], sh = stats[o*2+1];
    const float inv_sqrt2 = 0.70710678118654752f;
    float g0 = fmaf(v.x, sc, sh);
    float g1 = fmaf(v.y, sc, sh);
    float g2 = fmaf(v.z, sc, sh);
    float g3 = fmaf(v.w, sc, sh);
    v.x = 0.5f * g0 * (1.f + erff(g0 * inv_sqrt2));
    v.y = 0.5f * g1 * (1.f + erff(g1 * inv_sqrt2));
    v.z = 0.5f * g2 * (1.f + erff(g2 * inv_sqrt2));
    v.w = 0.5f * g3 * (1.f + erff(g3 * inv_sqrt2));
    p[idx4] = v;
}

extern "C" void kernel_launch(void* const* d_in, const int* in_sizes, int n_in,
                              void* d_out, int out_size, void* d_ws, size_t ws_size,
                              hipStream_t stream) {
    const float* bev   = (const float*)d_in[0];
    const float* offw  = (const float*)d_in[1];
    const float* offb  = (const float*)d_in[2];
    const float* wtw   = (const float*)d_in[3];
    const float* wtb   = (const float*)d_in[4];
    const float* projw = (const float*)d_in[5];
    const float* gamma = (const float*)d_in[6];
    const float* beta  = (const float*)d_in[7];
    float* out = (float*)d_out;
    float* wsf = (float*)d_ws;

    float* oa    = wsf + OA_OFF;
    float* wtT   = wsf + WTT_OFF;
    float* wp    = wsf + WP_OFF;
    float* stats = wsf + STATS_OFF;
    double* part = (double*)(wsf + PART_OFF);
    float* bevt  = wsf + BEVT_OFF;                 // tier2 f32
    ushort* bevtb = (ushort*)(wsf + BEVT_OFF);     // full3 bf16
    ushort* wbf  = (ushort*)(wsf + WBF_OFF);
    ushort* wcb  = (ushort*)(wsf + WCB_OFF);
    float* part2 = wsf + PART2_OFF;                // PACC region (no bevtb alias)

    bool full3 = ws_size >= WS_NEED_FULL3;
    bool big   = ws_size >= WS_NEED_BEVT;

    if (full3) {
        hipLaunchKernelGGL(k0bc, dim3(72), dim3(256), 0, stream,
                           projw, offw, wtw, wbf, wcb);
        hipLaunchKernelGGL(k2t_bf, dim3(2048), dim3(256), 0, stream, bev, bevtb);
        hipLaunchKernelGGL(k1m_conv_mfma, dim3(2048), dim3(256), 0, stream,
                           bevtb, wcb, offb, wtb, oa);
        hipLaunchKernelGGL(k2f_sample_proj, dim3(2048), dim3(256), 0, stream,
                           bevtb, oa, wbf, out, part2);
        hipLaunchKernelGGL(k3b_finalize2, dim3(128), dim3(256), 0, stream,
                           part2, gamma, beta, stats);
    } else if (big) {
        hipLaunchKernelGGL(k0_prep, dim3(64), dim3(256), 0, stream,
                           projw, offw, wtw, wtT, wp);
        hipLaunchKernelGGL(k2t_transpose, dim3(2048), dim3(256), 0, stream, bev, bevt);
        hipLaunchKernelGGL(k1_convs, dim3(BB*HH), dim3(256), 0, stream,
                           bev, wp, offb, wtb, oa);
        hipLaunchKernelGGL(k2_sample_proj_t, dim3(BB*256), dim3(512), 0, stream,
                           bevt, oa, wtT, out);
        hipLaunchKernelGGL(k3_partial, dim3(512), dim3(256), 0, stream, out, part);
        hipLaunchKernelGGL(k3_finalize, dim3(1), dim3(128), 0, stream,
                           part, gamma, beta, stats);
    } else {
        hipLaunchKernelGGL(k0_prep, dim3(64), dim3(256), 0, stream,
                           projw, offw, wtw, wtT, wp);
        hipLaunchKernelGGL(k1_convs, dim3(BB*HH), dim3(256), 0, stream,
                           bev, wp, offb, wtb, oa);
        hipLaunchKernelGGL(k2_sample_proj, dim3(BB*256), dim3(512), 0, stream,
                           bev, oa, wtT, out);
        hipLaunchKernelGGL(k3_partial, dim3(512), dim3(256), 0, stream, out, part);
        hipLaunchKernelGGL(k3_finalize, dim3(1), dim3(128), 0, stream,
                           part, gamma, beta, stats);
    }
    hipLaunchKernelGGL(k4_bn_gelu, dim3((BB*DD*HWC)/1024), dim3(256), 0, stream,
                       out, stats);
}